// Round 1
// 4192.443 us; speedup vs baseline: 1.5091x; 1.5091x over previous
//
#include <hip/hip_runtime.h>
#include <hip/hip_bf16.h>

typedef unsigned short u16;
typedef unsigned int u32;
typedef _Float16 h16x2 __attribute__((ext_vector_type(2)));
typedef _Float16 f16x8 __attribute__((ext_vector_type(8)));
typedef float f32x4 __attribute__((ext_vector_type(4)));

constexpr int B_ = 64, T_ = 256, V_ = 65, E_ = 384, H_ = 6, L_ = 6, D_ = 64, F_ = 1536;
constexpr int BT = B_ * T_;
constexpr int XN = BT * E_;

__device__ __forceinline__ float ldw(const void* p, long long i, int f32) {
    return f32 ? ((const float*)p)[i]
               : __bfloat162float(((const __hip_bfloat16*)p)[i]);
}
__device__ __forceinline__ float b2f(u16 u) { union { u32 i; float f; } x; x.i = (u32)u << 16; return x.f; }
__device__ __forceinline__ u16 f2b(float f) {
    __hip_bfloat16 h = __float2bfloat16(f);
    union { __hip_bfloat16 h; u16 u; } x; x.h = h; return x.u;
}
__device__ __forceinline__ float blo(u32 u) { union { u32 i; float f; } x; x.i = u << 16; return x.f; }
__device__ __forceinline__ float bhi(u32 u) { union { u32 i; float f; } x; x.i = u & 0xffff0000u; return x.f; }

// pack two floats into an f16x2 (u32)
__device__ __forceinline__ u32 pack_h2(float a, float b) {
    union { h16x2 h; u32 u; } x;
    x.h[0] = (_Float16)a; x.h[1] = (_Float16)b;
    return x.u;
}
// 2-wide f16 dot with fp32 accumulate: c += a.x*b.x + a.y*b.y
__device__ __forceinline__ float dot2(u32 a, u32 b, float c) {
    union { u32 u; h16x2 h; } xa, xb; xa.u = a; xb.u = b;
#if __has_builtin(__builtin_amdgcn_fdot2)
    return __builtin_amdgcn_fdot2(xa.h, xb.h, c, false);
#else
    return c + (float)xa.h[0] * (float)xb.h[0] + (float)xa.h[1] * (float)xb.h[1];
#endif
}

__global__ void init_k(int* flag, float* lossacc) {
    if (threadIdx.x == 0) { *flag = 0; *lossacc = 0.f; }
}

__global__ void detect_k(const void* tok, int n, int* flag) {
    int i = blockIdx.x * blockDim.x + threadIdx.x;
    if (i < n) {
        float v = __bfloat162float(((const __hip_bfloat16*)tok)[i]);
        if (!(fabsf(v) < 1e4f)) *flag = 1;
    }
}

// ---------------- embedding (verbatim) ----------------
__global__ void embed_k(const int* __restrict__ idx, const void* __restrict__ tok,
                        const void* __restrict__ pos, const int* __restrict__ flag,
                        __hip_bfloat16* __restrict__ x) {
    int i = blockIdx.x * blockDim.x + threadIdx.x;
    if (i >= XN) return;
    int f = *flag;
    int row = i / E_, e = i - row * E_;
    int t = row % T_;
    x[i] = __float2bfloat16(ldw(tok, (long long)idx[row] * E_ + e, f) +
                            ldw(pos, (long long)t * E_ + e, f));
}

// ---------------- layernorm (verbatim) ----------------
__global__ void ln_k(const __hip_bfloat16* __restrict__ x,
                     const void* __restrict__ g, long long goff,
                     const void* __restrict__ b, long long boff,
                     const int* __restrict__ flag,
                     __hip_bfloat16* __restrict__ out) {
    int f = *flag;
    int row = blockIdx.x;
    int lane = threadIdx.x;
    const __hip_bfloat16* xr = x + (size_t)row * E_;
    float vals[6];
    float s = 0.f, ss = 0.f;
    #pragma unroll
    for (int i = 0; i < 6; i++) {
        float v = __bfloat162float(xr[lane + 64 * i]);
        vals[i] = v; s += v; ss += v * v;
    }
    #pragma unroll
    for (int off = 32; off; off >>= 1) {
        s  += __shfl_down(s,  off, 64);
        ss += __shfl_down(ss, off, 64);
    }
    s = __shfl(s, 0, 64); ss = __shfl(ss, 0, 64);
    float mu = s * (1.f / E_);
    float var = ss * (1.f / E_) - mu * mu;
    float rs = rsqrtf(var + 1e-5f);
    __hip_bfloat16* orow = out + (size_t)row * E_;
    #pragma unroll
    for (int i = 0; i < 6; i++) {
        int e = lane + 64 * i;
        float r = (vals[i] - mu) * rs * ldw(g, goff + e, f) + ldw(b, boff + e, f);
        orow[e] = __float2bfloat16(r);
    }
}

// ---------------- legacy 64x64 dot2 GEMM (kept for lm head, N=65) ----------------
__global__ __launch_bounds__(256) void gemm64_k(
        const __hip_bfloat16* __restrict__ A,
        const void* __restrict__ W, long long woff,
        const void* __restrict__ bias, long long boff, int has_bias,
        const int* __restrict__ flag,
        void* __restrict__ Cv, int c_f32,
        int M, int N, int K, int residual, int relu) {
    __shared__ __align__(16) u32 As2[16][68];   // [kpair][row]
    __shared__ __align__(16) u32 Ws2[16][68];   // [kpair][col]
    int f = *flag;
    int tid = threadIdx.x;
    int row0 = blockIdx.y * 64;
    int col0 = blockIdx.x * 64;
    int tr = tid >> 4;            // 0..15 compute row group
    int tc = tid & 15;            // 0..15 compute col group
    int lr_ = tid >> 2;           // 0..63 A-load row
    int lkp4 = (tid & 3) * 4;     // A-load kpair base (4 pairs = 8 k)
    int wkp = tid >> 4;           // 0..15 W-load kpair
    int wc4 = (tid & 15) * 4;     // W-load col offset
    float acc[4][4];
    #pragma unroll
    for (int i = 0; i < 4; i++)
        #pragma unroll
        for (int j = 0; j < 4; j++) acc[i][j] = 0.f;

    for (int kt = 0; kt < K; kt += 32) {   // K multiple of 32 (384, 1536)
        uint4 a8 = *(const uint4*)((const u16*)A + (size_t)(row0 + lr_) * K + kt + lkp4 * 2);
        As2[lkp4 + 0][lr_] = pack_h2(blo(a8.x), bhi(a8.x));
        As2[lkp4 + 1][lr_] = pack_h2(blo(a8.y), bhi(a8.y));
        As2[lkp4 + 2][lr_] = pack_h2(blo(a8.z), bhi(a8.z));
        As2[lkp4 + 3][lr_] = pack_h2(blo(a8.w), bhi(a8.w));
        #pragma unroll
        for (int j = 0; j < 4; j++) {
            int c = col0 + wc4 + j;
            float w0 = (c < N) ? ldw(W, woff + (long long)(kt + 2 * wkp) * N + c, f) : 0.f;
            float w1 = (c < N) ? ldw(W, woff + (long long)(kt + 2 * wkp + 1) * N + c, f) : 0.f;
            Ws2[wkp][wc4 + j] = pack_h2(w0, w1);
        }
        __syncthreads();
        #pragma unroll
        for (int kp = 0; kp < 16; kp++) {
            uint4 a4 = *(const uint4*)&As2[kp][tr * 4];
            uint4 w4 = *(const uint4*)&Ws2[kp][tc * 4];
            u32 av[4] = {a4.x, a4.y, a4.z, a4.w};
            u32 wv[4] = {w4.x, w4.y, w4.z, w4.w};
            #pragma unroll
            for (int i = 0; i < 4; i++)
                #pragma unroll
                for (int j = 0; j < 4; j++)
                    acc[i][j] = dot2(av[i], wv[j], acc[i][j]);
        }
        __syncthreads();
    }
    #pragma unroll
    for (int i = 0; i < 4; i++) {
        int row = row0 + tr * 4 + i;
        #pragma unroll
        for (int j = 0; j < 4; j++) {
            int col = col0 + tc * 4 + j;
            if (col < N) {
                float r = acc[i][j];
                if (has_bias) r += ldw(bias, boff + col, f);
                size_t o = (size_t)row * N + col;
                if (c_f32) {
                    ((float*)Cv)[o] = r;
                } else {
                    __hip_bfloat16* C = (__hip_bfloat16*)Cv;
                    if (residual) r += __bfloat162float(C[o]);
                    if (relu) r = fmaxf(r, 0.f);
                    C[o] = __float2bfloat16(r);
                }
            }
        }
    }
}

// ---------------- MFMA GEMM: 128x128 tile, BK=64, 4 waves, f16 in / f32 acc ----------------
// Requires M%128==0, N%128==0, K%64==0 (holds for all big GEMMs here).
// A: bf16 [M][K] row-major.  W: bf16-or-f32 [K][N] row-major (flag selects).
// LDS: As4/Ws4 hold f16 pairs, rows of 128B (8 x 16B slots), slot XOR-swizzled by (row&7)
// so all ds_write_b128 / ds_read_b128 phases are 2-way (free) instead of 8-way.
// Fragment layout (m97-verified): A lane: row=lane&15, k=(lane>>4)*8+i (contiguous 8);
// C/D: col=lane&15, row=(lane>>4)*4+reg.
__global__ __launch_bounds__(256, 2) void gemm_mfma_k(
        const __hip_bfloat16* __restrict__ A,
        const void* __restrict__ W, long long woff,
        const void* __restrict__ bias, long long boff, int has_bias,
        const int* __restrict__ flag,
        __hip_bfloat16* __restrict__ C,
        int N, int K, int residual, int relu) {
    __shared__ __align__(16) u32 As4[128][32];   // [row][32 u32] = 64 f16 of k
    __shared__ __align__(16) u32 Ws4[128][32];   // [col][32 u32] = 64 f16 of k (W transposed)
    const int f = *flag;
    const int tid = threadIdx.x;
    const int lane = tid & 63;
    const int wv = tid >> 6;          // wave 0..3
    const int wr = wv >> 1, wc = wv & 1;
    const int row0 = blockIdx.y << 7;
    const int col0 = blockIdx.x << 7;
    const int l15 = lane & 15, l4 = lane >> 4;

    f32x4 acc[4][4];
    #pragma unroll
    for (int m = 0; m < 4; m++)
        #pragma unroll
        for (int n = 0; n < 4; n++)
            acc[m][n] = f32x4{0.f, 0.f, 0.f, 0.f};

    const int arow = tid >> 3;        // 0..31 (A stage: +p*32)
    const int aslot = tid & 7;        // 16B slot within a 128B k-row
    const u16* Ab = (const u16*)A + (size_t)row0 * K;
    const int wcol0 = tid & 63;       // W stage col base
    const int ksbase = (tid >> 6) << 1;

    for (int kt = 0; kt < K; kt += 64) {
        // ---- stage A tile [128][64] (bf16 -> f16), coalesced 16B per lane ----
        #pragma unroll
        for (int p = 0; p < 4; p++) {
            int r = arow + (p << 5);
            uint4 a8 = *(const uint4*)(Ab + (size_t)r * K + kt + aslot * 8);
            uint4 o;
            o.x = pack_h2(blo(a8.x), bhi(a8.x));
            o.y = pack_h2(blo(a8.y), bhi(a8.y));
            o.z = pack_h2(blo(a8.z), bhi(a8.z));
            o.w = pack_h2(blo(a8.w), bhi(a8.w));
            *(uint4*)&As4[r][(aslot ^ (r & 7)) << 2] = o;
        }
        // ---- stage W^T tile [128 cols][64 k] (dual dtype -> f16) ----
        // global loads coalesced along N (64 consecutive cols per lane group)
        #pragma unroll
        for (int p = 0; p < 4; p++) {
            int c = wcol0 + ((p & 1) << 6);       // 0..127
            int ks = ksbase + (p >> 1);           // 0..7 (8 k per slot)
            uint4 o;
            if (f) {
                const float* Wf = (const float*)W + woff + (size_t)(kt + ks * 8) * N + col0 + c;
                o.x = pack_h2(Wf[0],     Wf[(size_t)N]);
                o.y = pack_h2(Wf[2 * (size_t)N], Wf[3 * (size_t)N]);
                o.z = pack_h2(Wf[4 * (size_t)N], Wf[5 * (size_t)N]);
                o.w = pack_h2(Wf[6 * (size_t)N], Wf[7 * (size_t)N]);
            } else {
                const u16* Wb = (const u16*)W + woff + (size_t)(kt + ks * 8) * N + col0 + c;
                o.x = pack_h2(b2f(Wb[0]),     b2f(Wb[(size_t)N]));
                o.y = pack_h2(b2f(Wb[2 * (size_t)N]), b2f(Wb[3 * (size_t)N]));
                o.z = pack_h2(b2f(Wb[4 * (size_t)N]), b2f(Wb[5 * (size_t)N]));
                o.w = pack_h2(b2f(Wb[6 * (size_t)N]), b2f(Wb[7 * (size_t)N]));
            }
            *(uint4*)&Ws4[c][(ks ^ (c & 7)) << 2] = o;
        }
        __syncthreads();
        // ---- compute: 2 k-halves x 4x4 fragments ----
        #pragma unroll
        for (int kh = 0; kh < 2; kh++) {
            f16x8 af[4], wf[4];
            int s = (kh << 2) + l4;   // 16B slot = k/8
            #pragma unroll
            for (int m = 0; m < 4; m++) {
                int r = (wr << 6) + (m << 4) + l15;
                af[m] = *(const f16x8*)&As4[r][(s ^ (r & 7)) << 2];
            }
            #pragma unroll
            for (int n = 0; n < 4; n++) {
                int c = (wc << 6) + (n << 4) + l15;
                wf[n] = *(const f16x8*)&Ws4[c][(s ^ (c & 7)) << 2];
            }
            #pragma unroll
            for (int m = 0; m < 4; m++)
                #pragma unroll
                for (int n = 0; n < 4; n++)
                    acc[m][n] = __builtin_amdgcn_mfma_f32_16x16x32_f16(af[m], wf[n], acc[m][n], 0, 0, 0);
        }
        __syncthreads();
    }

    // ---- epilogue: bias / residual / relu, bf16 out ----
    float bv[4];
    #pragma unroll
    for (int n = 0; n < 4; n++)
        bv[n] = has_bias ? ldw(bias, boff + col0 + (wc << 6) + (n << 4) + l15, f) : 0.f;
    #pragma unroll
    for (int m = 0; m < 4; m++) {
        #pragma unroll
        for (int i = 0; i < 4; i++) {
            int row = row0 + (wr << 6) + (m << 4) + (l4 << 2) + i;
            __hip_bfloat16* Cr = C + (size_t)row * N + col0 + (wc << 6) + l15;
            #pragma unroll
            for (int n = 0; n < 4; n++) {
                float r = acc[m][n][i] + bv[n];
                if (residual) r += __bfloat162float(Cr[n << 4]);
                if (relu) r = fmaxf(r, 0.f);
                Cr[n << 4] = __float2bfloat16(r);
            }
        }
    }
}

// ---------------- attention: two-phase, fully LDS-resident, f16 dot2 (verbatim) ----------------
__global__ __launch_bounds__(256) void attn_fast_k(
        const __hip_bfloat16* __restrict__ q, const __hip_bfloat16* __restrict__ k,
        const __hip_bfloat16* __restrict__ v, __hip_bfloat16* __restrict__ att) {
    __shared__ u32 KV[8192];      // 32 KB: phase1 Ktp[dp*256+key] (f16 d-pair); phase2 V2[kp*64+d] (f16 k-pair)
    __shared__ u16 P[64 * 256];   // 32 KB: probs f16 [qlocal][key]
    int tid = threadIdx.x;
    int chunk = blockIdx.x & 3;
    int bh = blockIdx.x >> 2;
    int b = bh / H_, h = bh % H_;
    const u16* qbase = (const u16*)q + ((size_t)b * T_) * E_ + h * D_;
    const u16* kbase = (const u16*)k + ((size_t)b * T_) * E_ + h * D_;
    const u16* vbase = (const u16*)v + ((size_t)b * T_) * E_ + h * D_;
    u16* abase = (u16*)att + ((size_t)b * T_) * E_ + h * D_;

    const int kmax = (chunk + 1) * 64;   // causal: keys beyond kmax never used
    {   // stage K^T as f16 d-pairs
        int r = tid & 31, c = tid >> 5;
        for (int rr = r; rr < kmax; rr += 32) {
            uint4 u = ((const uint4*)(kbase + (size_t)rr * E_))[c];
            KV[(c * 4 + 0) * 256 + rr] = pack_h2(blo(u.x), bhi(u.x));
            KV[(c * 4 + 1) * 256 + rr] = pack_h2(blo(u.y), bhi(u.y));
            KV[(c * 4 + 2) * 256 + rr] = pack_h2(blo(u.z), bhi(u.z));
            KV[(c * 4 + 3) * 256 + rr] = pack_h2(blo(u.w), bhi(u.w));
        }
    }
    __syncthreads();

    int w = tid >> 6, lane = tid & 63;

    // ---- phase 1: scores + softmax -> P ----
    for (int j16 = 0; j16 < 16; j16++) {
        int qi = chunk * 64 + j16 * 4 + w;
        int ql = j16 * 4 + w;
        u32 qbf = ((const u32*)(qbase + (size_t)qi * E_))[lane & 31];
        u32 qf = pack_h2(blo(qbf), bhi(qbf));
        float s0 = 0.f, s1 = 0.f, s2 = 0.f, s3 = 0.f;
        int nc = (qi >> 6) + 1;
        for (int dp = 0; dp < 32; dp++) {
            u32 q2 = __shfl(qf, dp, 64);
            s0 = dot2(q2, KV[dp * 256 + lane], s0);
            if (nc > 1) s1 = dot2(q2, KV[dp * 256 + lane + 64], s1);
            if (nc > 2) s2 = dot2(q2, KV[dp * 256 + lane + 128], s2);
            if (nc > 3) s3 = dot2(q2, KV[dp * 256 + lane + 192], s3);
        }
        float sc[4] = {s0 * 0.125f, s1 * 0.125f, s2 * 0.125f, s3 * 0.125f};
        #pragma unroll
        for (int c = 0; c < 4; c++)
            if (c >= nc || lane + 64 * c > qi) sc[c] = -1e30f;
        float m = fmaxf(fmaxf(sc[0], sc[1]), fmaxf(sc[2], sc[3]));
        #pragma unroll
        for (int off = 32; off; off >>= 1) m = fmaxf(m, __shfl_xor(m, off, 64));
        float pr[4]; float sum = 0.f;
        #pragma unroll
        for (int c = 0; c < 4; c++) {
            pr[c] = (sc[c] > -1e29f) ? __expf(sc[c] - m) : 0.f;
            sum += pr[c];
        }
        #pragma unroll
        for (int off = 32; off; off >>= 1) sum += __shfl_xor(sum, off, 64);
        float inv = 1.f / sum;
        #pragma unroll
        for (int c = 0; c < 4; c++) {
            union { _Float16 h; u16 u; } x;
            x.h = (_Float16)(pr[c] * inv);
            P[ql * 256 + lane + 64 * c] = x.u;
        }
    }
    __syncthreads();

    {   // restage V into KV as f16 k-pairs: V2[kp*64+d] = {V[2kp][d], V[2kp+1][d]}
        int d = tid & 63, q4 = tid >> 6;
        for (int kp = q4; kp < kmax / 2; kp += 4) {
            float v0 = b2f(vbase[(size_t)(2 * kp) * E_ + d]);
            float v1 = b2f(vbase[(size_t)(2 * kp + 1) * E_ + d]);
            KV[kp * 64 + d] = pack_h2(v0, v1);
        }
    }
    __syncthreads();

    // ---- phase 2: O = P @ V, all LDS ----
    for (int j16 = 0; j16 < 16; j16++) {
        int qi = chunk * 64 + j16 * 4 + w;
        int ql = j16 * 4 + w;
        const u32* prow = (const u32*)&P[ql * 256];
        float o0 = 0.f, o1 = 0.f, o2 = 0.f, o3 = 0.f;
        int nkp = (qi >> 1) + 1;
        int kp = 0;
        for (; kp + 4 <= nkp; kp += 4) {
            o0 = dot2(prow[kp + 0], KV[(kp + 0) * 64 + lane], o0);
            o1 = dot2(prow[kp + 1], KV[(kp + 1) * 64 + lane], o1);
            o2 = dot2(prow[kp + 2], KV[(kp + 2) * 64 + lane], o2);
            o3 = dot2(prow[kp + 3], KV[(kp + 3) * 64 + lane], o3);
        }
        for (; kp < nkp; kp++) o0 = dot2(prow[kp], KV[kp * 64 + lane], o0);
        abase[(size_t)qi * E_ + lane] = f2b((o0 + o1) + (o2 + o3));
    }
}

// ---------------- loss tail (verbatim) ----------------
__global__ void outcvt_k(const float* __restrict__ logits, const int* __restrict__ flag,
                         void* __restrict__ out) {
    int i = blockIdx.x * blockDim.x + threadIdx.x;
    if (i >= BT * V_) return;
    if (*flag) ((float*)out)[i] = logits[i];
    else ((__hip_bfloat16*)out)[i] = __float2bfloat16(logits[i]);
}

__global__ void rowloss_k(const float* __restrict__ logits, const int* __restrict__ tgt,
                          float* __restrict__ accum) {
    int row = blockIdx.x;
    int l = threadIdx.x;
    const float* lr = logits + (size_t)row * V_;
    float v0 = lr[l];
    float v64 = (l == 0) ? lr[64] : -1e30f;
    float m = fmaxf(v0, v64);
    #pragma unroll
    for (int off = 32; off; off >>= 1) m = fmaxf(m, __shfl_xor(m, off, 64));
    float se = __expf(v0 - m) + ((l == 0) ? __expf(v64 - m) : 0.f);
    #pragma unroll
    for (int off = 32; off; off >>= 1) se += __shfl_xor(se, off, 64);
    if (l == 0) {
        float lp = lr[tgt[row]] - m - __logf(se);
        atomicAdd(accum, -lp);
    }
}

__global__ void final_k(const float* __restrict__ accum, const int* __restrict__ flag,
                        void* __restrict__ out) {
    if (threadIdx.x == 0) {
        float v = *accum * (1.f / BT);
        if (*flag) ((float*)out)[(size_t)BT * V_] = v;
        else ((__hip_bfloat16*)out)[(size_t)BT * V_] = __float2bfloat16(v);
    }
}

extern "C" void kernel_launch(void* const* d_in, const int* in_sizes, int n_in,
                              void* d_out, int out_size, void* d_ws, size_t ws_size,
                              hipStream_t stream) {
    const int* idx     = (const int*)d_in[0];
    const int* targets = (const int*)d_in[1];
    const void* tok  = d_in[2];
    const void* pos  = d_in[3];
    const void* Wq   = d_in[4];
    const void* Wk   = d_in[5];
    const void* Wv   = d_in[6];
    const void* Wo   = d_in[7];
    const void* bo   = d_in[8];
    const void* W1   = d_in[9];
    const void* b1   = d_in[10];
    const void* W2   = d_in[11];
    const void* b2   = d_in[12];
    const void* ln1g = d_in[13];
    const void* ln1b = d_in[14];
    const void* ln2g = d_in[15];
    const void* ln2b = d_in[16];
    const void* lnfg = d_in[17];
    const void* lnfb = d_in[18];
    const void* Wlm  = d_in[19];
    const void* blm  = d_in[20];

    // ---- workspace layout IDENTICAL to passing rounds ----
    char* wsb = (char*)d_ws;
    int*   flag    = (int*)wsb;
    float* lossacc = (float*)(wsb + 8);
    float* logits  = (float*)(wsb + 256);
    __hip_bfloat16* xb = (__hip_bfloat16*)(wsb + 256 + sizeof(float) * (size_t)BT * V_);
    __hip_bfloat16* hb = xb + (size_t)XN;
    __hip_bfloat16* qb = hb + (size_t)XN;
    __hip_bfloat16* kb = qb + (size_t)XN;
    __hip_bfloat16* vb = kb + (size_t)XN;
    __hip_bfloat16* ab = vb + (size_t)XN;
    __hip_bfloat16* ffnb = qb;

    dim3 grdV(2, 256);
    dim3 grdEm(E_ / 128, BT / 128);   // (3, 128)
    dim3 grdFm(F_ / 128, BT / 128);   // (12, 128)
    const long long EE = (long long)E_ * E_;

    init_k<<<1, 64, 0, stream>>>(flag, lossacc);
    detect_k<<<(V_ * E_ + 255) / 256, 256, 0, stream>>>(tok, V_ * E_, flag);
    embed_k<<<(XN + 255) / 256, 256, 0, stream>>>(idx, tok, pos, flag, xb);

    for (int l = 0; l < L_; l++) {
        ln_k<<<BT, 64, 0, stream>>>(xb, ln1g, (long long)l * E_, ln1b, (long long)l * E_, flag, hb);
        gemm_mfma_k<<<grdEm, 256, 0, stream>>>(hb, Wq, l * EE, nullptr, 0, 0, flag, qb, E_, E_, 0, 0);
        gemm_mfma_k<<<grdEm, 256, 0, stream>>>(hb, Wk, l * EE, nullptr, 0, 0, flag, kb, E_, E_, 0, 0);
        gemm_mfma_k<<<grdEm, 256, 0, stream>>>(hb, Wv, l * EE, nullptr, 0, 0, flag, vb, E_, E_, 0, 0);
        attn_fast_k<<<B_ * H_ * 4, 256, 0, stream>>>(qb, kb, vb, ab);
        gemm_mfma_k<<<grdEm, 256, 0, stream>>>(ab, Wo, l * EE, bo, (long long)l * E_, 1, flag, xb, E_, E_, 1, 0);
        ln_k<<<BT, 64, 0, stream>>>(xb, ln2g, (long long)l * E_, ln2b, (long long)l * E_, flag, hb);
        gemm_mfma_k<<<grdFm, 256, 0, stream>>>(hb, W1, (long long)l * E_ * F_, b1, (long long)l * F_, 1, flag, ffnb, F_, E_, 0, 1);
        gemm_mfma_k<<<grdEm, 256, 0, stream>>>(ffnb, W2, (long long)l * F_ * E_, b2, (long long)l * E_, 1, flag, xb, E_, F_, 1, 0);
    }

    ln_k<<<BT, 64, 0, stream>>>(xb, lnfg, 0, lnfb, 0, flag, hb);
    gemm64_k<<<grdV, 256, 0, stream>>>(hb, Wlm, 0, blm, 0, 1, flag, logits, 1, BT, V_, E_, 0, 0);

    outcvt_k<<<(BT * V_ + 255) / 256, 256, 0, stream>>>(logits, flag, d_out);
    rowloss_k<<<BT, 64, 0, stream>>>(logits, targets, lossacc);
    final_k<<<1, 64, 0, stream>>>(lossacc, flag, d_out);
}

// Round 2
// 2370.203 us; speedup vs baseline: 2.6693x; 1.7688x over previous
//
#include <hip/hip_runtime.h>
#include <hip/hip_bf16.h>

typedef unsigned short u16;
typedef unsigned int u32;
typedef _Float16 h16x2 __attribute__((ext_vector_type(2)));
typedef _Float16 f16x8 __attribute__((ext_vector_type(8)));
typedef float f32x4 __attribute__((ext_vector_type(4)));

constexpr int B_ = 64, T_ = 256, V_ = 65, E_ = 384, H_ = 6, L_ = 6, D_ = 64, F_ = 1536;
constexpr int BT = B_ * T_;
constexpr int XN = BT * E_;

__device__ __forceinline__ float ldw(const void* p, long long i, int f32) {
    return f32 ? ((const float*)p)[i]
               : __bfloat162float(((const __hip_bfloat16*)p)[i]);
}
__device__ __forceinline__ float b2f(u16 u) { union { u32 i; float f; } x; x.i = (u32)u << 16; return x.f; }
__device__ __forceinline__ u16 f2b(float f) {
    __hip_bfloat16 h = __float2bfloat16(f);
    union { __hip_bfloat16 h; u16 u; } x; x.h = h; return x.u;
}
__device__ __forceinline__ float blo(u32 u) { union { u32 i; float f; } x; x.i = u << 16; return x.f; }
__device__ __forceinline__ float bhi(u32 u) { union { u32 i; float f; } x; x.i = u & 0xffff0000u; return x.f; }

// pack two floats into an f16x2 (u32)
__device__ __forceinline__ u32 pack_h2(float a, float b) {
    union { h16x2 h; u32 u; } x;
    x.h[0] = (_Float16)a; x.h[1] = (_Float16)b;
    return x.u;
}
// 2-wide f16 dot with fp32 accumulate: c += a.x*b.x + a.y*b.y
__device__ __forceinline__ float dot2(u32 a, u32 b, float c) {
    union { u32 u; h16x2 h; } xa, xb; xa.u = a; xb.u = b;
#if __has_builtin(__builtin_amdgcn_fdot2)
    return __builtin_amdgcn_fdot2(xa.h, xb.h, c, false);
#else
    return c + (float)xa.h[0] * (float)xb.h[0] + (float)xa.h[1] * (float)xb.h[1];
#endif
}

__global__ void init_k(int* flag, float* lossacc) {
    if (threadIdx.x == 0) { *flag = 0; *lossacc = 0.f; }
}

__global__ void detect_k(const void* tok, int n, int* flag) {
    int i = blockIdx.x * blockDim.x + threadIdx.x;
    if (i < n) {
        float v = __bfloat162float(((const __hip_bfloat16*)tok)[i]);
        if (!(fabsf(v) < 1e4f)) *flag = 1;
    }
}

// ---------------- embedding (verbatim) ----------------
__global__ void embed_k(const int* __restrict__ idx, const void* __restrict__ tok,
                        const void* __restrict__ pos, const int* __restrict__ flag,
                        __hip_bfloat16* __restrict__ x) {
    int i = blockIdx.x * blockDim.x + threadIdx.x;
    if (i >= XN) return;
    int f = *flag;
    int row = i / E_, e = i - row * E_;
    int t = row % T_;
    x[i] = __float2bfloat16(ldw(tok, (long long)idx[row] * E_ + e, f) +
                            ldw(pos, (long long)t * E_ + e, f));
}

// ---------------- layernorm (verbatim) ----------------
__global__ void ln_k(const __hip_bfloat16* __restrict__ x,
                     const void* __restrict__ g, long long goff,
                     const void* __restrict__ b, long long boff,
                     const int* __restrict__ flag,
                     __hip_bfloat16* __restrict__ out) {
    int f = *flag;
    int row = blockIdx.x;
    int lane = threadIdx.x;
    const __hip_bfloat16* xr = x + (size_t)row * E_;
    float vals[6];
    float s = 0.f, ss = 0.f;
    #pragma unroll
    for (int i = 0; i < 6; i++) {
        float v = __bfloat162float(xr[lane + 64 * i]);
        vals[i] = v; s += v; ss += v * v;
    }
    #pragma unroll
    for (int off = 32; off; off >>= 1) {
        s  += __shfl_down(s,  off, 64);
        ss += __shfl_down(ss, off, 64);
    }
    s = __shfl(s, 0, 64); ss = __shfl(ss, 0, 64);
    float mu = s * (1.f / E_);
    float var = ss * (1.f / E_) - mu * mu;
    float rs = rsqrtf(var + 1e-5f);
    __hip_bfloat16* orow = out + (size_t)row * E_;
    #pragma unroll
    for (int i = 0; i < 6; i++) {
        int e = lane + 64 * i;
        float r = (vals[i] - mu) * rs * ldw(g, goff + e, f) + ldw(b, boff + e, f);
        orow[e] = __float2bfloat16(r);
    }
}

// ---------------- legacy 64x64 dot2 GEMM (kept for lm head, N=65) ----------------
__global__ __launch_bounds__(256) void gemm64_k(
        const __hip_bfloat16* __restrict__ A,
        const void* __restrict__ W, long long woff,
        const void* __restrict__ bias, long long boff, int has_bias,
        const int* __restrict__ flag,
        void* __restrict__ Cv, int c_f32,
        int M, int N, int K, int residual, int relu) {
    __shared__ __align__(16) u32 As2[16][68];   // [kpair][row]
    __shared__ __align__(16) u32 Ws2[16][68];   // [kpair][col]
    int f = *flag;
    int tid = threadIdx.x;
    int row0 = blockIdx.y * 64;
    int col0 = blockIdx.x * 64;
    int tr = tid >> 4;            // 0..15 compute row group
    int tc = tid & 15;            // 0..15 compute col group
    int lr_ = tid >> 2;           // 0..63 A-load row
    int lkp4 = (tid & 3) * 4;     // A-load kpair base (4 pairs = 8 k)
    int wkp = tid >> 4;           // 0..15 W-load kpair
    int wc4 = (tid & 15) * 4;     // W-load col offset
    float acc[4][4];
    #pragma unroll
    for (int i = 0; i < 4; i++)
        #pragma unroll
        for (int j = 0; j < 4; j++) acc[i][j] = 0.f;

    for (int kt = 0; kt < K; kt += 32) {   // K multiple of 32 (384, 1536)
        uint4 a8 = *(const uint4*)((const u16*)A + (size_t)(row0 + lr_) * K + kt + lkp4 * 2);
        As2[lkp4 + 0][lr_] = pack_h2(blo(a8.x), bhi(a8.x));
        As2[lkp4 + 1][lr_] = pack_h2(blo(a8.y), bhi(a8.y));
        As2[lkp4 + 2][lr_] = pack_h2(blo(a8.z), bhi(a8.z));
        As2[lkp4 + 3][lr_] = pack_h2(blo(a8.w), bhi(a8.w));
        #pragma unroll
        for (int j = 0; j < 4; j++) {
            int c = col0 + wc4 + j;
            float w0 = (c < N) ? ldw(W, woff + (long long)(kt + 2 * wkp) * N + c, f) : 0.f;
            float w1 = (c < N) ? ldw(W, woff + (long long)(kt + 2 * wkp + 1) * N + c, f) : 0.f;
            Ws2[wkp][wc4 + j] = pack_h2(w0, w1);
        }
        __syncthreads();
        #pragma unroll
        for (int kp = 0; kp < 16; kp++) {
            uint4 a4 = *(const uint4*)&As2[kp][tr * 4];
            uint4 w4 = *(const uint4*)&Ws2[kp][tc * 4];
            u32 av[4] = {a4.x, a4.y, a4.z, a4.w};
            u32 wv[4] = {w4.x, w4.y, w4.z, w4.w};
            #pragma unroll
            for (int i = 0; i < 4; i++)
                #pragma unroll
                for (int j = 0; j < 4; j++)
                    acc[i][j] = dot2(av[i], wv[j], acc[i][j]);
        }
        __syncthreads();
    }
    #pragma unroll
    for (int i = 0; i < 4; i++) {
        int row = row0 + tr * 4 + i;
        #pragma unroll
        for (int j = 0; j < 4; j++) {
            int col = col0 + tc * 4 + j;
            if (col < N) {
                float r = acc[i][j];
                if (has_bias) r += ldw(bias, boff + col, f);
                size_t o = (size_t)row * N + col;
                if (c_f32) {
                    ((float*)Cv)[o] = r;
                } else {
                    __hip_bfloat16* C = (__hip_bfloat16*)Cv;
                    if (residual) r += __bfloat162float(C[o]);
                    if (relu) r = fmaxf(r, 0.f);
                    C[o] = __float2bfloat16(r);
                }
            }
        }
    }
}

// ---------------- MFMA GEMM: 128x128 tile, BK=64, 4 waves, f16 in / f32 acc ----------------
__global__ __launch_bounds__(256, 2) void gemm_mfma_k(
        const __hip_bfloat16* __restrict__ A,
        const void* __restrict__ W, long long woff,
        const void* __restrict__ bias, long long boff, int has_bias,
        const int* __restrict__ flag,
        __hip_bfloat16* __restrict__ C,
        int N, int K, int residual, int relu) {
    __shared__ __align__(16) u32 As4[128][32];   // [row][32 u32] = 64 f16 of k
    __shared__ __align__(16) u32 Ws4[128][32];   // [col][32 u32] = 64 f16 of k (W transposed)
    const int f = *flag;
    const int tid = threadIdx.x;
    const int lane = tid & 63;
    const int wv = tid >> 6;          // wave 0..3
    const int wr = wv >> 1, wc = wv & 1;
    const int row0 = blockIdx.y << 7;
    const int col0 = blockIdx.x << 7;
    const int l15 = lane & 15, l4 = lane >> 4;

    f32x4 acc[4][4];
    #pragma unroll
    for (int m = 0; m < 4; m++)
        #pragma unroll
        for (int n = 0; n < 4; n++)
            acc[m][n] = f32x4{0.f, 0.f, 0.f, 0.f};

    const int arow = tid >> 3;        // 0..31 (A stage: +p*32)
    const int aslot = tid & 7;        // 16B slot within a 128B k-row
    const u16* Ab = (const u16*)A + (size_t)row0 * K;
    const int wcol0 = tid & 63;       // W stage col base
    const int ksbase = (tid >> 6) << 1;

    for (int kt = 0; kt < K; kt += 64) {
        // ---- stage A tile [128][64] (bf16 -> f16), coalesced 16B per lane ----
        #pragma unroll
        for (int p = 0; p < 4; p++) {
            int r = arow + (p << 5);
            uint4 a8 = *(const uint4*)(Ab + (size_t)r * K + kt + aslot * 8);
            uint4 o;
            o.x = pack_h2(blo(a8.x), bhi(a8.x));
            o.y = pack_h2(blo(a8.y), bhi(a8.y));
            o.z = pack_h2(blo(a8.z), bhi(a8.z));
            o.w = pack_h2(blo(a8.w), bhi(a8.w));
            *(uint4*)&As4[r][(aslot ^ (r & 7)) << 2] = o;
        }
        // ---- stage W^T tile [128 cols][64 k] (dual dtype -> f16) ----
        #pragma unroll
        for (int p = 0; p < 4; p++) {
            int c = wcol0 + ((p & 1) << 6);       // 0..127
            int ks = ksbase + (p >> 1);           // 0..7 (8 k per slot)
            uint4 o;
            if (f) {
                const float* Wf = (const float*)W + woff + (size_t)(kt + ks * 8) * N + col0 + c;
                o.x = pack_h2(Wf[0],     Wf[(size_t)N]);
                o.y = pack_h2(Wf[2 * (size_t)N], Wf[3 * (size_t)N]);
                o.z = pack_h2(Wf[4 * (size_t)N], Wf[5 * (size_t)N]);
                o.w = pack_h2(Wf[6 * (size_t)N], Wf[7 * (size_t)N]);
            } else {
                const u16* Wb = (const u16*)W + woff + (size_t)(kt + ks * 8) * N + col0 + c;
                o.x = pack_h2(b2f(Wb[0]),     b2f(Wb[(size_t)N]));
                o.y = pack_h2(b2f(Wb[2 * (size_t)N]), b2f(Wb[3 * (size_t)N]));
                o.z = pack_h2(b2f(Wb[4 * (size_t)N]), b2f(Wb[5 * (size_t)N]));
                o.w = pack_h2(b2f(Wb[6 * (size_t)N]), b2f(Wb[7 * (size_t)N]));
            }
            *(uint4*)&Ws4[c][(ks ^ (c & 7)) << 2] = o;
        }
        __syncthreads();
        // ---- compute: 2 k-halves x 4x4 fragments ----
        #pragma unroll
        for (int kh = 0; kh < 2; kh++) {
            f16x8 af[4], wf[4];
            int s = (kh << 2) + l4;   // 16B slot = k/8
            #pragma unroll
            for (int m = 0; m < 4; m++) {
                int r = (wr << 6) + (m << 4) + l15;
                af[m] = *(const f16x8*)&As4[r][(s ^ (r & 7)) << 2];
            }
            #pragma unroll
            for (int n = 0; n < 4; n++) {
                int c = (wc << 6) + (n << 4) + l15;
                wf[n] = *(const f16x8*)&Ws4[c][(s ^ (c & 7)) << 2];
            }
            #pragma unroll
            for (int m = 0; m < 4; m++)
                #pragma unroll
                for (int n = 0; n < 4; n++)
                    acc[m][n] = __builtin_amdgcn_mfma_f32_16x16x32_f16(af[m], wf[n], acc[m][n], 0, 0, 0);
        }
        __syncthreads();
    }

    // ---- epilogue: bias / residual / relu, bf16 out ----
    float bv[4];
    #pragma unroll
    for (int n = 0; n < 4; n++)
        bv[n] = has_bias ? ldw(bias, boff + col0 + (wc << 6) + (n << 4) + l15, f) : 0.f;
    #pragma unroll
    for (int m = 0; m < 4; m++) {
        #pragma unroll
        for (int i = 0; i < 4; i++) {
            int row = row0 + (wr << 6) + (m << 4) + (l4 << 2) + i;
            __hip_bfloat16* Cr = C + (size_t)row * N + col0 + (wc << 6) + l15;
            #pragma unroll
            for (int n = 0; n < 4; n++) {
                float r = acc[m][n][i] + bv[n];
                if (residual) r += __bfloat162float(Cr[n << 4]);
                if (relu) r = fmaxf(r, 0.f);
                Cr[n << 4] = __float2bfloat16(r);
            }
        }
    }
}

// ---------------- MFMA attention ----------------
// Per block: (b, h, chunk). 64 q-rows [q0, q0+64), NK = q0+64 keys.
// Phase 1: S^T[key][q] = K·Q^T via mfma (A=K rows=key, B=Q^T cols=q).
//   C-layout: q = lane&15 (fixed per lane) -> softmax row-reduce = 2 shfl_xor.
// Phase 2: O[q][d] = P·V via mfma (A=P from LDS, B=V^T key-pair-packed in LDS).
// LDS: Kls 32KB (K, then reused as Vt), Pls 32KB. Total 64KB.
template<int NK>
__device__ __forceinline__ void attn_body(
        const u16* __restrict__ qbase, const u16* __restrict__ kbase,
        const u16* __restrict__ vbase, u16* __restrict__ abase,
        int q0, u32* Kls, u32* Pls) {
    constexpr int NKF = NK / 16;   // 16x16 key fragments
    constexpr int NKS = NK / 32;   // K=32 mfma steps over keys
    const int tid = threadIdx.x;
    const int lane = tid & 63;
    const int w = tid >> 6;
    const int l15 = lane & 15, l4 = lane >> 4;

    // ---- stage K [NK][64] f16, slot ^= key&7 ----
    {
        int r8 = tid >> 3, slot = tid & 7;
        #pragma unroll
        for (int p = 0; p < NK / 32; p++) {
            int key = r8 + p * 32;
            uint4 a8 = *(const uint4*)(kbase + (size_t)key * E_ + slot * 8);
            uint4 o;
            o.x = pack_h2(blo(a8.x), bhi(a8.x));
            o.y = pack_h2(blo(a8.y), bhi(a8.y));
            o.z = pack_h2(blo(a8.z), bhi(a8.z));
            o.w = pack_h2(blo(a8.w), bhi(a8.w));
            *(uint4*)&Kls[key * 32 + ((slot ^ (key & 7)) << 2)] = o;
        }
    }
    __syncthreads();

    const int qrow = w * 16 + l15;        // local q row (phase1 B col, phase2 A row)
    const int qi = q0 + qrow;             // global q index
    f32x4 acc[NKF];
    #pragma unroll
    for (int kf = 0; kf < NKF; kf++) acc[kf] = f32x4{0.f, 0.f, 0.f, 0.f};

    // ---- phase 1: S^T = K @ Q^T ----
    #pragma unroll
    for (int kh = 0; kh < 2; kh++) {
        uint4 q8 = *(const uint4*)(qbase + (size_t)qi * E_ + (kh * 4 + l4) * 8);
        union { f16x8 h; uint4 u; } qu;
        qu.u.x = pack_h2(blo(q8.x), bhi(q8.x));
        qu.u.y = pack_h2(blo(q8.y), bhi(q8.y));
        qu.u.z = pack_h2(blo(q8.z), bhi(q8.z));
        qu.u.w = pack_h2(blo(q8.w), bhi(q8.w));
        #pragma unroll
        for (int kf = 0; kf < NKF; kf++) {
            int krow = kf * 16 + l15;
            f16x8 kf8 = *(const f16x8*)&Kls[krow * 32 + ((((kh << 2) + l4) ^ (krow & 7)) << 2)];
            acc[kf] = __builtin_amdgcn_mfma_f32_16x16x32_f16(kf8, qu.h, acc[kf], 0, 0, 0);
        }
    }

    // ---- softmax (keys of lane: kf*16 + l4*4 + r; q fixed = qrow) ----
    float m = -1e30f;
    #pragma unroll
    for (int kf = 0; kf < NKF; kf++)
        #pragma unroll
        for (int r = 0; r < 4; r++) {
            int key = kf * 16 + l4 * 4 + r;
            float s = acc[kf][r] * 0.125f;
            if (key > qi) s = -1e30f;
            acc[kf][r] = s;
            m = fmaxf(m, s);
        }
    m = fmaxf(m, __shfl_xor(m, 16, 64));
    m = fmaxf(m, __shfl_xor(m, 32, 64));
    float sum = 0.f;
    #pragma unroll
    for (int kf = 0; kf < NKF; kf++)
        #pragma unroll
        for (int r = 0; r < 4; r++) {
            float p = __expf(acc[kf][r] - m);
            acc[kf][r] = p;
            sum += p;
        }
    sum += __shfl_xor(sum, 16, 64);
    sum += __shfl_xor(sum, 32, 64);
    float inv = 1.f / sum;

    // ---- store normalized P^T -> Pls[q][kp] f16 pairs, slot ^= q&15 ----
    #pragma unroll
    for (int kf = 0; kf < NKF; kf++) {
        uint2 pw;
        pw.x = pack_h2(acc[kf][0] * inv, acc[kf][1] * inv);
        pw.y = pack_h2(acc[kf][2] * inv, acc[kf][3] * inv);
        int j = kf * 2 + (l4 >> 1);
        *(uint2*)&Pls[qrow * 128 + ((j ^ (qrow & 15)) << 2) + ((l4 & 1) << 1)] = pw;
    }
    __syncthreads();   // all K reads + P writes done

    // ---- restage V^T into Kls: Vt[d][kp] = {V[2kp][d], V[2kp+1][d]}, slot ^= d&15 ----
    for (int kp = lane; kp < NK / 2; kp += 64) {
        #pragma unroll
        for (int dq = 0; dq < 2; dq++) {
            int db = w + dq * 4;          // 0..7, 8 d's per task
            uint4 v0 = *(const uint4*)(vbase + (size_t)(2 * kp) * E_ + db * 8);
            uint4 v1 = *(const uint4*)(vbase + (size_t)(2 * kp + 1) * E_ + db * 8);
            u32 uu[8];
            uu[0] = pack_h2(blo(v0.x), blo(v1.x));
            uu[1] = pack_h2(bhi(v0.x), bhi(v1.x));
            uu[2] = pack_h2(blo(v0.y), blo(v1.y));
            uu[3] = pack_h2(bhi(v0.y), bhi(v1.y));
            uu[4] = pack_h2(blo(v0.z), blo(v1.z));
            uu[5] = pack_h2(bhi(v0.z), bhi(v1.z));
            uu[6] = pack_h2(blo(v0.w), blo(v1.w));
            uu[7] = pack_h2(bhi(v0.w), bhi(v1.w));
            #pragma unroll
            for (int i = 0; i < 8; i++) {
                int d = db * 8 + i;
                Kls[d * 128 + (((kp >> 2) ^ (d & 15)) << 2) + (kp & 3)] = uu[i];
            }
        }
    }
    __syncthreads();

    // ---- phase 2: O = P @ V ----
    f32x4 o2[4];
    #pragma unroll
    for (int df = 0; df < 4; df++) o2[df] = f32x4{0.f, 0.f, 0.f, 0.f};
    #pragma unroll
    for (int ks = 0; ks < NKS; ks++) {
        f16x8 pa = *(const f16x8*)&Pls[qrow * 128 + (((ks * 4 + l4) ^ (qrow & 15)) << 2)];
        #pragma unroll
        for (int df = 0; df < 4; df++) {
            int d = df * 16 + l15;
            f16x8 vb8 = *(const f16x8*)&Kls[d * 128 + (((ks * 4 + l4) ^ (d & 15)) << 2)];
            o2[df] = __builtin_amdgcn_mfma_f32_16x16x32_f16(pa, vb8, o2[df], 0, 0, 0);
        }
    }
    // C-layout: d = df*16 + l15, q local = w*16 + l4*4 + r
    #pragma unroll
    for (int df = 0; df < 4; df++)
        #pragma unroll
        for (int r = 0; r < 4; r++) {
            int qg = q0 + w * 16 + l4 * 4 + r;
            abase[(size_t)qg * E_ + df * 16 + l15] = f2b(o2[df][r]);
        }
}

__global__ __launch_bounds__(256) void attn_mfma_k(
        const __hip_bfloat16* __restrict__ q, const __hip_bfloat16* __restrict__ k,
        const __hip_bfloat16* __restrict__ v, __hip_bfloat16* __restrict__ att) {
    __shared__ __align__(16) u32 Kls[256 * 32];   // 32 KB
    __shared__ __align__(16) u32 Pls[64 * 128];   // 32 KB
    int chunk = blockIdx.x & 3;
    int bh = blockIdx.x >> 2;
    int b = bh / H_, h = bh % H_;
    const u16* qbase = (const u16*)q + ((size_t)b * T_) * E_ + h * D_;
    const u16* kbase = (const u16*)k + ((size_t)b * T_) * E_ + h * D_;
    const u16* vbase = (const u16*)v + ((size_t)b * T_) * E_ + h * D_;
    u16* abase = (u16*)att + ((size_t)b * T_) * E_ + h * D_;
    int q0 = chunk * 64;
    switch (chunk) {
        case 0: attn_body< 64>(qbase, kbase, vbase, abase, q0, Kls, Pls); break;
        case 1: attn_body<128>(qbase, kbase, vbase, abase, q0, Kls, Pls); break;
        case 2: attn_body<192>(qbase, kbase, vbase, abase, q0, Kls, Pls); break;
        default: attn_body<256>(qbase, kbase, vbase, abase, q0, Kls, Pls); break;
    }
}

// ---------------- loss tail (verbatim) ----------------
__global__ void outcvt_k(const float* __restrict__ logits, const int* __restrict__ flag,
                         void* __restrict__ out) {
    int i = blockIdx.x * blockDim.x + threadIdx.x;
    if (i >= BT * V_) return;
    if (*flag) ((float*)out)[i] = logits[i];
    else ((__hip_bfloat16*)out)[i] = __float2bfloat16(logits[i]);
}

__global__ void rowloss_k(const float* __restrict__ logits, const int* __restrict__ tgt,
                          float* __restrict__ accum) {
    int row = blockIdx.x;
    int l = threadIdx.x;
    const float* lr = logits + (size_t)row * V_;
    float v0 = lr[l];
    float v64 = (l == 0) ? lr[64] : -1e30f;
    float m = fmaxf(v0, v64);
    #pragma unroll
    for (int off = 32; off; off >>= 1) m = fmaxf(m, __shfl_xor(m, off, 64));
    float se = __expf(v0 - m) + ((l == 0) ? __expf(v64 - m) : 0.f);
    #pragma unroll
    for (int off = 32; off; off >>= 1) se += __shfl_xor(se, off, 64);
    if (l == 0) {
        float lp = lr[tgt[row]] - m - __logf(se);
        atomicAdd(accum, -lp);
    }
}

__global__ void final_k(const float* __restrict__ accum, const int* __restrict__ flag,
                        void* __restrict__ out) {
    if (threadIdx.x == 0) {
        float v = *accum * (1.f / BT);
        if (*flag) ((float*)out)[(size_t)BT * V_] = v;
        else ((__hip_bfloat16*)out)[(size_t)BT * V_] = __float2bfloat16(v);
    }
}

extern "C" void kernel_launch(void* const* d_in, const int* in_sizes, int n_in,
                              void* d_out, int out_size, void* d_ws, size_t ws_size,
                              hipStream_t stream) {
    const int* idx     = (const int*)d_in[0];
    const int* targets = (const int*)d_in[1];
    const void* tok  = d_in[2];
    const void* pos  = d_in[3];
    const void* Wq   = d_in[4];
    const void* Wk   = d_in[5];
    const void* Wv   = d_in[6];
    const void* Wo   = d_in[7];
    const void* bo   = d_in[8];
    const void* W1   = d_in[9];
    const void* b1   = d_in[10];
    const void* W2   = d_in[11];
    const void* b2   = d_in[12];
    const void* ln1g = d_in[13];
    const void* ln1b = d_in[14];
    const void* ln2g = d_in[15];
    const void* ln2b = d_in[16];
    const void* lnfg = d_in[17];
    const void* lnfb = d_in[18];
    const void* Wlm  = d_in[19];
    const void* blm  = d_in[20];

    // ---- workspace layout IDENTICAL to passing rounds ----
    char* wsb = (char*)d_ws;
    int*   flag    = (int*)wsb;
    float* lossacc = (float*)(wsb + 8);
    float* logits  = (float*)(wsb + 256);
    __hip_bfloat16* xb = (__hip_bfloat16*)(wsb + 256 + sizeof(float) * (size_t)BT * V_);
    __hip_bfloat16* hb = xb + (size_t)XN;
    __hip_bfloat16* qb = hb + (size_t)XN;
    __hip_bfloat16* kb = qb + (size_t)XN;
    __hip_bfloat16* vb = kb + (size_t)XN;
    __hip_bfloat16* ab = vb + (size_t)XN;
    __hip_bfloat16* ffnb = qb;

    dim3 grdV(2, 256);
    dim3 grdEm(E_ / 128, BT / 128);   // (3, 128)
    dim3 grdFm(F_ / 128, BT / 128);   // (12, 128)
    const long long EE = (long long)E_ * E_;

    init_k<<<1, 64, 0, stream>>>(flag, lossacc);
    detect_k<<<(V_ * E_ + 255) / 256, 256, 0, stream>>>(tok, V_ * E_, flag);
    embed_k<<<(XN + 255) / 256, 256, 0, stream>>>(idx, tok, pos, flag, xb);

    for (int l = 0; l < L_; l++) {
        ln_k<<<BT, 64, 0, stream>>>(xb, ln1g, (long long)l * E_, ln1b, (long long)l * E_, flag, hb);
        gemm_mfma_k<<<grdEm, 256, 0, stream>>>(hb, Wq, l * EE, nullptr, 0, 0, flag, qb, E_, E_, 0, 0);
        gemm_mfma_k<<<grdEm, 256, 0, stream>>>(hb, Wk, l * EE, nullptr, 0, 0, flag, kb, E_, E_, 0, 0);
        gemm_mfma_k<<<grdEm, 256, 0, stream>>>(hb, Wv, l * EE, nullptr, 0, 0, flag, vb, E_, E_, 0, 0);
        attn_mfma_k<<<B_ * H_ * 4, 256, 0, stream>>>(qb, kb, vb, ab);
        gemm_mfma_k<<<grdEm, 256, 0, stream>>>(ab, Wo, l * EE, bo, (long long)l * E_, 1, flag, xb, E_, E_, 1, 0);
        ln_k<<<BT, 64, 0, stream>>>(xb, ln2g, (long long)l * E_, ln2b, (long long)l * E_, flag, hb);
        gemm_mfma_k<<<grdFm, 256, 0, stream>>>(hb, W1, (long long)l * E_ * F_, b1, (long long)l * F_, 1, flag, ffnb, F_, E_, 0, 1);
        gemm_mfma_k<<<grdEm, 256, 0, stream>>>(ffnb, W2, (long long)l * F_ * E_, b2, (long long)l * E_, 1, flag, xb, E_, F_, 1, 0);
    }

    ln_k<<<BT, 64, 0, stream>>>(xb, lnfg, 0, lnfb, 0, flag, hb);
    gemm64_k<<<grdV, 256, 0, stream>>>(hb, Wlm, 0, blm, 0, 1, flag, logits, 1, BT, V_, E_, 0, 0);

    outcvt_k<<<(BT * V_ + 255) / 256, 256, 0, stream>>>(logits, flag, d_out);
    rowloss_k<<<BT, 64, 0, stream>>>(logits, targets, lossacc);
    final_k<<<1, 64, 0, stream>>>(lossacc, flag, d_out);
}

// Round 3
// 1392.221 us; speedup vs baseline: 4.5444x; 1.7025x over previous
//
#include <hip/hip_runtime.h>
#include <hip/hip_bf16.h>

typedef unsigned short u16;
typedef unsigned int u32;
typedef _Float16 h16x2 __attribute__((ext_vector_type(2)));
typedef _Float16 f16x8 __attribute__((ext_vector_type(8)));
typedef float f32x4 __attribute__((ext_vector_type(4)));

constexpr int B_ = 64, T_ = 256, V_ = 65, E_ = 384, H_ = 6, L_ = 6, D_ = 64, F_ = 1536;
constexpr int BT = B_ * T_;
constexpr int XN = BT * E_;

__device__ __forceinline__ float ldw(const void* p, long long i, int f32) {
    return f32 ? ((const float*)p)[i]
               : __bfloat162float(((const __hip_bfloat16*)p)[i]);
}
__device__ __forceinline__ float b2f(u16 u) { union { u32 i; float f; } x; x.i = (u32)u << 16; return x.f; }
__device__ __forceinline__ u16 f2b(float f) {
    __hip_bfloat16 h = __float2bfloat16(f);
    union { __hip_bfloat16 h; u16 u; } x; x.h = h; return x.u;
}
__device__ __forceinline__ float blo(u32 u) { union { u32 i; float f; } x; x.i = u << 16; return x.f; }
__device__ __forceinline__ float bhi(u32 u) { union { u32 i; float f; } x; x.i = u & 0xffff0000u; return x.f; }

// pack two floats into an f16x2 (u32)
__device__ __forceinline__ u32 pack_h2(float a, float b) {
    union { h16x2 h; u32 u; } x;
    x.h[0] = (_Float16)a; x.h[1] = (_Float16)b;
    return x.u;
}
// 2-wide f16 dot with fp32 accumulate: c += a.x*b.x + a.y*b.y
__device__ __forceinline__ float dot2(u32 a, u32 b, float c) {
    union { u32 u; h16x2 h; } xa, xb; xa.u = a; xb.u = b;
#if __has_builtin(__builtin_amdgcn_fdot2)
    return __builtin_amdgcn_fdot2(xa.h, xb.h, c, false);
#else
    return c + (float)xa.h[0] * (float)xb.h[0] + (float)xa.h[1] * (float)xb.h[1];
#endif
}

__global__ void init_k(int* flag, float* lossacc) {
    if (threadIdx.x == 0) { *flag = 0; *lossacc = 0.f; }
}

__global__ void detect_k(const void* tok, int n, int* flag) {
    int i = blockIdx.x * blockDim.x + threadIdx.x;
    if (i < n) {
        float v = __bfloat162float(((const __hip_bfloat16*)tok)[i]);
        if (!(fabsf(v) < 1e4f)) *flag = 1;
    }
}

// ---------------- embedding (verbatim) ----------------
__global__ void embed_k(const int* __restrict__ idx, const void* __restrict__ tok,
                        const void* __restrict__ pos, const int* __restrict__ flag,
                        __hip_bfloat16* __restrict__ x) {
    int i = blockIdx.x * blockDim.x + threadIdx.x;
    if (i >= XN) return;
    int f = *flag;
    int row = i / E_, e = i - row * E_;
    int t = row % T_;
    x[i] = __float2bfloat16(ldw(tok, (long long)idx[row] * E_ + e, f) +
                            ldw(pos, (long long)t * E_ + e, f));
}

// ---------------- layernorm: 4 rows per block (wave per row) ----------------
__global__ __launch_bounds__(256) void ln4_k(const __hip_bfloat16* __restrict__ x,
                     const void* __restrict__ g, long long goff,
                     const void* __restrict__ b, long long boff,
                     const int* __restrict__ flag,
                     __hip_bfloat16* __restrict__ out) {
    int f = *flag;
    int w = threadIdx.x >> 6, lane = threadIdx.x & 63;
    int row = blockIdx.x * 4 + w;
    const __hip_bfloat16* xr = x + (size_t)row * E_;
    float vals[6];
    float s = 0.f, ss = 0.f;
    #pragma unroll
    for (int i = 0; i < 6; i++) {
        float v = __bfloat162float(xr[lane + 64 * i]);
        vals[i] = v; s += v; ss += v * v;
    }
    #pragma unroll
    for (int off = 32; off; off >>= 1) {
        s  += __shfl_down(s,  off, 64);
        ss += __shfl_down(ss, off, 64);
    }
    s = __shfl(s, 0, 64); ss = __shfl(ss, 0, 64);
    float mu = s * (1.f / E_);
    float var = ss * (1.f / E_) - mu * mu;
    float rs = rsqrtf(var + 1e-5f);
    __hip_bfloat16* orow = out + (size_t)row * E_;
    #pragma unroll
    for (int i = 0; i < 6; i++) {
        int e = lane + 64 * i;
        float r = (vals[i] - mu) * rs * ldw(g, goff + e, f) + ldw(b, boff + e, f);
        orow[e] = __float2bfloat16(r);
    }
}

// ---------------- legacy 64x64 dot2 GEMM (kept for lm head, N=65) ----------------
__global__ __launch_bounds__(256) void gemm64_k(
        const __hip_bfloat16* __restrict__ A,
        const void* __restrict__ W, long long woff,
        const void* __restrict__ bias, long long boff, int has_bias,
        const int* __restrict__ flag,
        void* __restrict__ Cv, int c_f32,
        int M, int N, int K, int residual, int relu) {
    __shared__ __align__(16) u32 As2[16][68];   // [kpair][row]
    __shared__ __align__(16) u32 Ws2[16][68];   // [kpair][col]
    int f = *flag;
    int tid = threadIdx.x;
    int row0 = blockIdx.y * 64;
    int col0 = blockIdx.x * 64;
    int tr = tid >> 4;
    int tc = tid & 15;
    int lr_ = tid >> 2;
    int lkp4 = (tid & 3) * 4;
    int wkp = tid >> 4;
    int wc4 = (tid & 15) * 4;
    float acc[4][4];
    #pragma unroll
    for (int i = 0; i < 4; i++)
        #pragma unroll
        for (int j = 0; j < 4; j++) acc[i][j] = 0.f;

    for (int kt = 0; kt < K; kt += 32) {
        uint4 a8 = *(const uint4*)((const u16*)A + (size_t)(row0 + lr_) * K + kt + lkp4 * 2);
        As2[lkp4 + 0][lr_] = pack_h2(blo(a8.x), bhi(a8.x));
        As2[lkp4 + 1][lr_] = pack_h2(blo(a8.y), bhi(a8.y));
        As2[lkp4 + 2][lr_] = pack_h2(blo(a8.z), bhi(a8.z));
        As2[lkp4 + 3][lr_] = pack_h2(blo(a8.w), bhi(a8.w));
        #pragma unroll
        for (int j = 0; j < 4; j++) {
            int c = col0 + wc4 + j;
            float w0 = (c < N) ? ldw(W, woff + (long long)(kt + 2 * wkp) * N + c, f) : 0.f;
            float w1 = (c < N) ? ldw(W, woff + (long long)(kt + 2 * wkp + 1) * N + c, f) : 0.f;
            Ws2[wkp][wc4 + j] = pack_h2(w0, w1);
        }
        __syncthreads();
        #pragma unroll
        for (int kp = 0; kp < 16; kp++) {
            uint4 a4 = *(const uint4*)&As2[kp][tr * 4];
            uint4 w4 = *(const uint4*)&Ws2[kp][tc * 4];
            u32 av[4] = {a4.x, a4.y, a4.z, a4.w};
            u32 wv[4] = {w4.x, w4.y, w4.z, w4.w};
            #pragma unroll
            for (int i = 0; i < 4; i++)
                #pragma unroll
                for (int j = 0; j < 4; j++)
                    acc[i][j] = dot2(av[i], wv[j], acc[i][j]);
        }
        __syncthreads();
    }
    #pragma unroll
    for (int i = 0; i < 4; i++) {
        int row = row0 + tr * 4 + i;
        #pragma unroll
        for (int j = 0; j < 4; j++) {
            int col = col0 + tc * 4 + j;
            if (col < N) {
                float r = acc[i][j];
                if (has_bias) r += ldw(bias, boff + col, f);
                size_t o = (size_t)row * N + col;
                if (c_f32) {
                    ((float*)Cv)[o] = r;
                } else {
                    __hip_bfloat16* C = (__hip_bfloat16*)Cv;
                    if (residual) r += __bfloat162float(C[o]);
                    if (relu) r = fmaxf(r, 0.f);
                    C[o] = __float2bfloat16(r);
                }
            }
        }
    }
}

// ---------------- MFMA GEMM body: 128x128 tile, BK=64, LDS double-buffer ----------------
// Pipeline per K-step: issue next-tile global loads -> MFMA current LDS buffer ->
// pack+write regs to other buffer -> ONE barrier. sched_barrier(0) keeps the
// vmcnt-dependent pack ops from hoisting above the MFMA cluster.
__device__ __forceinline__ void gemm_mfma_body(
        const __hip_bfloat16* __restrict__ A,
        const void* __restrict__ W, long long woff,
        const void* __restrict__ bias, long long boff, int has_bias,
        int f, __hip_bfloat16* __restrict__ C,
        int N, int K, int residual, int relu,
        int bx, int by, u32* As, u32* Ws) {
    const int tid = threadIdx.x;
    const int lane = tid & 63;
    const int wv = tid >> 6;
    const int wr = wv >> 1, wc = wv & 1;
    const int row0 = by << 7;
    const int col0 = bx << 7;
    const int l15 = lane & 15, l4 = lane >> 4;

    f32x4 acc[4][4];
    #pragma unroll
    for (int m = 0; m < 4; m++)
        #pragma unroll
        for (int n = 0; n < 4; n++)
            acc[m][n] = f32x4{0.f, 0.f, 0.f, 0.f};

    const int arow = tid >> 3;        // 0..31
    const int aslot = tid & 7;        // 16B slot in 128B k-row
    const u16* Ab = (const u16*)A + (size_t)row0 * K;
    const int wcol0 = tid & 63;
    const int ksbase = (tid >> 6) << 1;

    uint4 ar_[4];                     // raw A prefetch (bf16 x8 each)
    u32 wr_[32];                      // raw W prefetch, bf16 path
    float wf_[32];                    // raw W prefetch, f32 path

    auto loadTile = [&](int kt) {
        #pragma unroll
        for (int p = 0; p < 4; p++)
            ar_[p] = *(const uint4*)(Ab + (size_t)(arow + (p << 5)) * K + kt + aslot * 8);
        if (f) {
            #pragma unroll
            for (int p = 0; p < 4; p++) {
                int c = wcol0 + ((p & 1) << 6);
                int ks = ksbase + (p >> 1);
                const float* Wf = (const float*)W + woff + (size_t)(kt + ks * 8) * N + col0 + c;
                #pragma unroll
                for (int i = 0; i < 8; i++) wf_[p * 8 + i] = Wf[(size_t)i * N];
            }
        } else {
            #pragma unroll
            for (int p = 0; p < 4; p++) {
                int c = wcol0 + ((p & 1) << 6);
                int ks = ksbase + (p >> 1);
                const u16* Wb = (const u16*)W + woff + (size_t)(kt + ks * 8) * N + col0 + c;
                #pragma unroll
                for (int i = 0; i < 8; i++) wr_[p * 8 + i] = Wb[(size_t)i * N];
            }
        }
    };
    auto storeTile = [&](int buf) {
        #pragma unroll
        for (int p = 0; p < 4; p++) {
            int r = arow + (p << 5);
            uint4 o;
            o.x = pack_h2(blo(ar_[p].x), bhi(ar_[p].x));
            o.y = pack_h2(blo(ar_[p].y), bhi(ar_[p].y));
            o.z = pack_h2(blo(ar_[p].z), bhi(ar_[p].z));
            o.w = pack_h2(blo(ar_[p].w), bhi(ar_[p].w));
            *(uint4*)&As[(size_t)(buf * 128 + r) * 32 + ((aslot ^ (r & 7)) << 2)] = o;
        }
        #pragma unroll
        for (int p = 0; p < 4; p++) {
            int c = wcol0 + ((p & 1) << 6);
            int ks = ksbase + (p >> 1);
            uint4 o;
            if (f) {
                o.x = pack_h2(wf_[p * 8 + 0], wf_[p * 8 + 1]);
                o.y = pack_h2(wf_[p * 8 + 2], wf_[p * 8 + 3]);
                o.z = pack_h2(wf_[p * 8 + 4], wf_[p * 8 + 5]);
                o.w = pack_h2(wf_[p * 8 + 6], wf_[p * 8 + 7]);
            } else {
                o.x = pack_h2(b2f((u16)wr_[p * 8 + 0]), b2f((u16)wr_[p * 8 + 1]));
                o.y = pack_h2(b2f((u16)wr_[p * 8 + 2]), b2f((u16)wr_[p * 8 + 3]));
                o.z = pack_h2(b2f((u16)wr_[p * 8 + 4]), b2f((u16)wr_[p * 8 + 5]));
                o.w = pack_h2(b2f((u16)wr_[p * 8 + 6]), b2f((u16)wr_[p * 8 + 7]));
            }
            *(uint4*)&Ws[(size_t)(buf * 128 + c) * 32 + ((ks ^ (c & 7)) << 2)] = o;
        }
    };
    auto compute = [&](int buf) {
        #pragma unroll
        for (int kh = 0; kh < 2; kh++) {
            f16x8 af[4], wfr[4];
            int s = (kh << 2) + l4;
            #pragma unroll
            for (int m = 0; m < 4; m++) {
                int r = (wr << 6) + (m << 4) + l15;
                af[m] = *(const f16x8*)&As[(size_t)(buf * 128 + r) * 32 + ((s ^ (r & 7)) << 2)];
            }
            #pragma unroll
            for (int n = 0; n < 4; n++) {
                int c = (wc << 6) + (n << 4) + l15;
                wfr[n] = *(const f16x8*)&Ws[(size_t)(buf * 128 + c) * 32 + ((s ^ (c & 7)) << 2)];
            }
            #pragma unroll
            for (int m = 0; m < 4; m++)
                #pragma unroll
                for (int n = 0; n < 4; n++)
                    acc[m][n] = __builtin_amdgcn_mfma_f32_16x16x32_f16(af[m], wfr[n], acc[m][n], 0, 0, 0);
        }
    };

    loadTile(0);
    storeTile(0);
    __syncthreads();
    int cur = 0;
    for (int kt = 64; kt < K; kt += 64) {
        loadTile(kt);
        __builtin_amdgcn_sched_barrier(0);
        compute(cur);
        __builtin_amdgcn_sched_barrier(0);
        storeTile(cur ^ 1);
        __syncthreads();
        cur ^= 1;
    }
    compute(cur);

    // ---- epilogue ----
    float bv[4];
    #pragma unroll
    for (int n = 0; n < 4; n++)
        bv[n] = has_bias ? ldw(bias, boff + col0 + (wc << 6) + (n << 4) + l15, f) : 0.f;
    #pragma unroll
    for (int m = 0; m < 4; m++) {
        #pragma unroll
        for (int i = 0; i < 4; i++) {
            int row = row0 + (wr << 6) + (m << 4) + (l4 << 2) + i;
            __hip_bfloat16* Cr = C + (size_t)row * N + col0 + (wc << 6) + l15;
            #pragma unroll
            for (int n = 0; n < 4; n++) {
                float r = acc[m][n][i] + bv[n];
                if (residual) r += __bfloat162float(Cr[n << 4]);
                if (relu) r = fmaxf(r, 0.f);
                Cr[n << 4] = __float2bfloat16(r);
            }
        }
    }
}

__global__ __launch_bounds__(256, 2) void gemm_mfma_k(
        const __hip_bfloat16* __restrict__ A,
        const void* __restrict__ W, long long woff,
        const void* __restrict__ bias, long long boff, int has_bias,
        const int* __restrict__ flag,
        __hip_bfloat16* __restrict__ C,
        int N, int K, int residual, int relu) {
    __shared__ __align__(16) u32 As[2 * 128 * 32];   // 32 KB
    __shared__ __align__(16) u32 Ws[2 * 128 * 32];   // 32 KB
    gemm_mfma_body(A, W, woff, bias, boff, has_bias, *flag, C, N, K, residual, relu,
                   blockIdx.x, blockIdx.y, As, Ws);
}

// fused Q/K/V: grid (9, 128); blockIdx.x/3 picks {Wq,Wk,Wv}->{qb,kb,vb}
__global__ __launch_bounds__(256, 2) void gemm_qkv_k(
        const __hip_bfloat16* __restrict__ A,
        const void* __restrict__ Wq, const void* __restrict__ Wk, const void* __restrict__ Wv,
        long long woff, const int* __restrict__ flag,
        __hip_bfloat16* __restrict__ qb, __hip_bfloat16* __restrict__ kb,
        __hip_bfloat16* __restrict__ vb) {
    __shared__ __align__(16) u32 As[2 * 128 * 32];
    __shared__ __align__(16) u32 Ws[2 * 128 * 32];
    int which = blockIdx.x / 3, bx = blockIdx.x % 3;
    const void* W = (which == 0) ? Wq : (which == 1) ? Wk : Wv;
    __hip_bfloat16* C = (which == 0) ? qb : (which == 1) ? kb : vb;
    gemm_mfma_body(A, W, woff, nullptr, 0, 0, *flag, C, E_, E_, 0, 0,
                   bx, blockIdx.y, As, Ws);
}

// ---------------- MFMA attention (verbatim from round 2) ----------------
template<int NK>
__device__ __forceinline__ void attn_body(
        const u16* __restrict__ qbase, const u16* __restrict__ kbase,
        const u16* __restrict__ vbase, u16* __restrict__ abase,
        int q0, u32* Kls, u32* Pls) {
    constexpr int NKF = NK / 16;
    constexpr int NKS = NK / 32;
    const int tid = threadIdx.x;
    const int lane = tid & 63;
    const int w = tid >> 6;
    const int l15 = lane & 15, l4 = lane >> 4;

    {
        int r8 = tid >> 3, slot = tid & 7;
        #pragma unroll
        for (int p = 0; p < NK / 32; p++) {
            int key = r8 + p * 32;
            uint4 a8 = *(const uint4*)(kbase + (size_t)key * E_ + slot * 8);
            uint4 o;
            o.x = pack_h2(blo(a8.x), bhi(a8.x));
            o.y = pack_h2(blo(a8.y), bhi(a8.y));
            o.z = pack_h2(blo(a8.z), bhi(a8.z));
            o.w = pack_h2(blo(a8.w), bhi(a8.w));
            *(uint4*)&Kls[key * 32 + ((slot ^ (key & 7)) << 2)] = o;
        }
    }
    __syncthreads();

    const int qrow = w * 16 + l15;
    const int qi = q0 + qrow;
    f32x4 acc[NKF];
    #pragma unroll
    for (int kf = 0; kf < NKF; kf++) acc[kf] = f32x4{0.f, 0.f, 0.f, 0.f};

    #pragma unroll
    for (int kh = 0; kh < 2; kh++) {
        uint4 q8 = *(const uint4*)(qbase + (size_t)qi * E_ + (kh * 4 + l4) * 8);
        union { f16x8 h; uint4 u; } qu;
        qu.u.x = pack_h2(blo(q8.x), bhi(q8.x));
        qu.u.y = pack_h2(blo(q8.y), bhi(q8.y));
        qu.u.z = pack_h2(blo(q8.z), bhi(q8.z));
        qu.u.w = pack_h2(blo(q8.w), bhi(q8.w));
        #pragma unroll
        for (int kf = 0; kf < NKF; kf++) {
            int krow = kf * 16 + l15;
            f16x8 kf8 = *(const f16x8*)&Kls[krow * 32 + ((((kh << 2) + l4) ^ (krow & 7)) << 2)];
            acc[kf] = __builtin_amdgcn_mfma_f32_16x16x32_f16(kf8, qu.h, acc[kf], 0, 0, 0);
        }
    }

    float m = -1e30f;
    #pragma unroll
    for (int kf = 0; kf < NKF; kf++)
        #pragma unroll
        for (int r = 0; r < 4; r++) {
            int key = kf * 16 + l4 * 4 + r;
            float s = acc[kf][r] * 0.125f;
            if (key > qi) s = -1e30f;
            acc[kf][r] = s;
            m = fmaxf(m, s);
        }
    m = fmaxf(m, __shfl_xor(m, 16, 64));
    m = fmaxf(m, __shfl_xor(m, 32, 64));
    float sum = 0.f;
    #pragma unroll
    for (int kf = 0; kf < NKF; kf++)
        #pragma unroll
        for (int r = 0; r < 4; r++) {
            float p = __expf(acc[kf][r] - m);
            acc[kf][r] = p;
            sum += p;
        }
    sum += __shfl_xor(sum, 16, 64);
    sum += __shfl_xor(sum, 32, 64);
    float inv = 1.f / sum;

    #pragma unroll
    for (int kf = 0; kf < NKF; kf++) {
        uint2 pw;
        pw.x = pack_h2(acc[kf][0] * inv, acc[kf][1] * inv);
        pw.y = pack_h2(acc[kf][2] * inv, acc[kf][3] * inv);
        int j = kf * 2 + (l4 >> 1);
        *(uint2*)&Pls[qrow * 128 + ((j ^ (qrow & 15)) << 2) + ((l4 & 1) << 1)] = pw;
    }
    __syncthreads();

    for (int kp = lane; kp < NK / 2; kp += 64) {
        #pragma unroll
        for (int dq = 0; dq < 2; dq++) {
            int db = w + dq * 4;
            uint4 v0 = *(const uint4*)(vbase + (size_t)(2 * kp) * E_ + db * 8);
            uint4 v1 = *(const uint4*)(vbase + (size_t)(2 * kp + 1) * E_ + db * 8);
            u32 uu[8];
            uu[0] = pack_h2(blo(v0.x), blo(v1.x));
            uu[1] = pack_h2(bhi(v0.x), bhi(v1.x));
            uu[2] = pack_h2(blo(v0.y), blo(v1.y));
            uu[3] = pack_h2(bhi(v0.y), bhi(v1.y));
            uu[4] = pack_h2(blo(v0.z), blo(v1.z));
            uu[5] = pack_h2(bhi(v0.z), bhi(v1.z));
            uu[6] = pack_h2(blo(v0.w), blo(v1.w));
            uu[7] = pack_h2(bhi(v0.w), bhi(v1.w));
            #pragma unroll
            for (int i = 0; i < 8; i++) {
                int d = db * 8 + i;
                Kls[d * 128 + (((kp >> 2) ^ (d & 15)) << 2) + (kp & 3)] = uu[i];
            }
        }
    }
    __syncthreads();

    f32x4 o2[4];
    #pragma unroll
    for (int df = 0; df < 4; df++) o2[df] = f32x4{0.f, 0.f, 0.f, 0.f};
    #pragma unroll
    for (int ks = 0; ks < NKS; ks++) {
        f16x8 pa = *(const f16x8*)&Pls[qrow * 128 + (((ks * 4 + l4) ^ (qrow & 15)) << 2)];
        #pragma unroll
        for (int df = 0; df < 4; df++) {
            int d = df * 16 + l15;
            f16x8 vb8 = *(const f16x8*)&Kls[d * 128 + (((ks * 4 + l4) ^ (d & 15)) << 2)];
            o2[df] = __builtin_amdgcn_mfma_f32_16x16x32_f16(pa, vb8, o2[df], 0, 0, 0);
        }
    }
    #pragma unroll
    for (int df = 0; df < 4; df++)
        #pragma unroll
        for (int r = 0; r < 4; r++) {
            int qg = q0 + w * 16 + l4 * 4 + r;
            abase[(size_t)qg * E_ + df * 16 + l15] = f2b(o2[df][r]);
        }
}

__global__ __launch_bounds__(256) void attn_mfma_k(
        const __hip_bfloat16* __restrict__ q, const __hip_bfloat16* __restrict__ k,
        const __hip_bfloat16* __restrict__ v, __hip_bfloat16* __restrict__ att) {
    __shared__ __align__(16) u32 Kls[256 * 32];   // 32 KB
    __shared__ __align__(16) u32 Pls[64 * 128];   // 32 KB
    int chunk = blockIdx.x & 3;
    int bh = blockIdx.x >> 2;
    int b = bh / H_, h = bh % H_;
    const u16* qbase = (const u16*)q + ((size_t)b * T_) * E_ + h * D_;
    const u16* kbase = (const u16*)k + ((size_t)b * T_) * E_ + h * D_;
    const u16* vbase = (const u16*)v + ((size_t)b * T_) * E_ + h * D_;
    u16* abase = (u16*)att + ((size_t)b * T_) * E_ + h * D_;
    int q0 = chunk * 64;
    switch (chunk) {
        case 0: attn_body< 64>(qbase, kbase, vbase, abase, q0, Kls, Pls); break;
        case 1: attn_body<128>(qbase, kbase, vbase, abase, q0, Kls, Pls); break;
        case 2: attn_body<192>(qbase, kbase, vbase, abase, q0, Kls, Pls); break;
        default: attn_body<256>(qbase, kbase, vbase, abase, q0, Kls, Pls); break;
    }
}

// ---------------- loss tail ----------------
__global__ void outcvt_k(const float* __restrict__ logits, const int* __restrict__ flag,
                         void* __restrict__ out) {
    int i = blockIdx.x * blockDim.x + threadIdx.x;
    if (i >= BT * V_) return;
    if (*flag) ((float*)out)[i] = logits[i];
    else ((__hip_bfloat16*)out)[i] = __float2bfloat16(logits[i]);
}

// 256 blocks x 4 waves; each wave does 16 rows; ONE atomic per block.
__global__ __launch_bounds__(256) void rowloss2_k(
        const float* __restrict__ logits, const int* __restrict__ tgt,
        float* __restrict__ accum) {
    __shared__ float part[4];
    int w = threadIdx.x >> 6, lane = threadIdx.x & 63;
    float local = 0.f;
    for (int i = 0; i < 16; i++) {
        int row = blockIdx.x * 64 + w * 16 + i;
        const float* lr = logits + (size_t)row * V_;
        float v0 = lr[lane];
        float v64 = (lane == 0) ? lr[64] : -1e30f;
        float m = fmaxf(v0, v64);
        #pragma unroll
        for (int off = 32; off; off >>= 1) m = fmaxf(m, __shfl_xor(m, off, 64));
        float se = __expf(v0 - m) + ((lane == 0) ? __expf(v64 - m) : 0.f);
        #pragma unroll
        for (int off = 32; off; off >>= 1) se += __shfl_xor(se, off, 64);
        if (lane == 0) local += lr[tgt[row]] - m - __logf(se);
    }
    if (lane == 0) part[w] = local;
    __syncthreads();
    if (threadIdx.x == 0)
        atomicAdd(accum, -(part[0] + part[1] + part[2] + part[3]));
}

__global__ void final_k(const float* __restrict__ accum, const int* __restrict__ flag,
                        void* __restrict__ out) {
    if (threadIdx.x == 0) {
        float v = *accum * (1.f / BT);
        if (*flag) ((float*)out)[(size_t)BT * V_] = v;
        else ((__hip_bfloat16*)out)[(size_t)BT * V_] = __float2bfloat16(v);
    }
}

extern "C" void kernel_launch(void* const* d_in, const int* in_sizes, int n_in,
                              void* d_out, int out_size, void* d_ws, size_t ws_size,
                              hipStream_t stream) {
    const int* idx     = (const int*)d_in[0];
    const int* targets = (const int*)d_in[1];
    const void* tok  = d_in[2];
    const void* pos  = d_in[3];
    const void* Wq   = d_in[4];
    const void* Wk   = d_in[5];
    const void* Wv   = d_in[6];
    const void* Wo   = d_in[7];
    const void* bo   = d_in[8];
    const void* W1   = d_in[9];
    const void* b1   = d_in[10];
    const void* W2   = d_in[11];
    const void* b2   = d_in[12];
    const void* ln1g = d_in[13];
    const void* ln1b = d_in[14];
    const void* ln2g = d_in[15];
    const void* ln2b = d_in[16];
    const void* lnfg = d_in[17];
    const void* lnfb = d_in[18];
    const void* Wlm  = d_in[19];
    const void* blm  = d_in[20];

    // ---- workspace layout IDENTICAL to passing rounds ----
    char* wsb = (char*)d_ws;
    int*   flag    = (int*)wsb;
    float* lossacc = (float*)(wsb + 8);
    float* logits  = (float*)(wsb + 256);
    __hip_bfloat16* xb = (__hip_bfloat16*)(wsb + 256 + sizeof(float) * (size_t)BT * V_);
    __hip_bfloat16* hb = xb + (size_t)XN;
    __hip_bfloat16* qb = hb + (size_t)XN;
    __hip_bfloat16* kb = qb + (size_t)XN;
    __hip_bfloat16* vb = kb + (size_t)XN;
    __hip_bfloat16* ab = vb + (size_t)XN;
    __hip_bfloat16* ffnb = qb;

    dim3 grdV(2, 256);
    dim3 grdEm(E_ / 128, BT / 128);   // (3, 128)
    dim3 grdFm(F_ / 128, BT / 128);   // (12, 128)
    dim3 grdQKV(9, BT / 128);         // fused Q,K,V
    const long long EE = (long long)E_ * E_;

    init_k<<<1, 64, 0, stream>>>(flag, lossacc);
    detect_k<<<(V_ * E_ + 255) / 256, 256, 0, stream>>>(tok, V_ * E_, flag);
    embed_k<<<(XN + 255) / 256, 256, 0, stream>>>(idx, tok, pos, flag, xb);

    for (int l = 0; l < L_; l++) {
        ln4_k<<<BT / 4, 256, 0, stream>>>(xb, ln1g, (long long)l * E_, ln1b, (long long)l * E_, flag, hb);
        gemm_qkv_k<<<grdQKV, 256, 0, stream>>>(hb, Wq, Wk, Wv, l * EE, flag, qb, kb, vb);
        attn_mfma_k<<<B_ * H_ * 4, 256, 0, stream>>>(qb, kb, vb, ab);
        gemm_mfma_k<<<grdEm, 256, 0, stream>>>(ab, Wo, l * EE, bo, (long long)l * E_, 1, flag, xb, E_, E_, 1, 0);
        ln4_k<<<BT / 4, 256, 0, stream>>>(xb, ln2g, (long long)l * E_, ln2b, (long long)l * E_, flag, hb);
        gemm_mfma_k<<<grdFm, 256, 0, stream>>>(hb, W1, (long long)l * E_ * F_, b1, (long long)l * F_, 1, flag, ffnb, F_, E_, 0, 1);
        gemm_mfma_k<<<grdEm, 256, 0, stream>>>(ffnb, W2, (long long)l * F_ * E_, b2, (long long)l * E_, 1, flag, xb, E_, F_, 1, 0);
    }

    ln4_k<<<BT / 4, 256, 0, stream>>>(xb, lnfg, 0, lnfb, 0, flag, hb);
    gemm64_k<<<grdV, 256, 0, stream>>>(hb, Wlm, 0, blm, 0, 1, flag, logits, 1, BT, V_, E_, 0, 0);

    outcvt_k<<<(BT * V_ + 255) / 256, 256, 0, stream>>>(logits, flag, d_out);
    rowloss2_k<<<BT / 64, 256, 0, stream>>>(logits, targets, lossacc);
    final_k<<<1, 64, 0, stream>>>(lossacc, flag, d_out);
}

// Round 4
// 1375.648 us; speedup vs baseline: 4.5991x; 1.0120x over previous
//
#include <hip/hip_runtime.h>
#include <hip/hip_bf16.h>

typedef unsigned short u16;
typedef unsigned int u32;
typedef _Float16 h16x2 __attribute__((ext_vector_type(2)));
typedef _Float16 f16x8 __attribute__((ext_vector_type(8)));
typedef float f32x4 __attribute__((ext_vector_type(4)));

constexpr int B_ = 64, T_ = 256, V_ = 65, E_ = 384, H_ = 6, L_ = 6, D_ = 64, F_ = 1536;
constexpr int BT = B_ * T_;
constexpr int XN = BT * E_;

__device__ __forceinline__ float ldw(const void* p, long long i, int f32) {
    return f32 ? ((const float*)p)[i]
               : __bfloat162float(((const __hip_bfloat16*)p)[i]);
}
__device__ __forceinline__ float b2f(u16 u) { union { u32 i; float f; } x; x.i = (u32)u << 16; return x.f; }
__device__ __forceinline__ u16 f2b(float f) {
    __hip_bfloat16 h = __float2bfloat16(f);
    union { __hip_bfloat16 h; u16 u; } x; x.h = h; return x.u;
}
__device__ __forceinline__ float blo(u32 u) { union { u32 i; float f; } x; x.i = u << 16; return x.f; }
__device__ __forceinline__ float bhi(u32 u) { union { u32 i; float f; } x; x.i = u & 0xffff0000u; return x.f; }
__device__ __forceinline__ float u2f(u32 u) { union { u32 i; float f; } x; x.i = u; return x.f; }

// pack two floats into an f16x2 (u32)
__device__ __forceinline__ u32 pack_h2(float a, float b) {
    union { h16x2 h; u32 u; } x;
    x.h[0] = (_Float16)a; x.h[1] = (_Float16)b;
    return x.u;
}

__global__ void init_k(int* flag, float* lossacc) {
    if (threadIdx.x == 0) { *flag = 0; *lossacc = 0.f; }
}

__global__ void detect_k(const void* tok, int n, int* flag) {
    int i = blockIdx.x * blockDim.x + threadIdx.x;
    if (i < n) {
        float v = __bfloat162float(((const __hip_bfloat16*)tok)[i]);
        if (!(fabsf(v) < 1e4f)) *flag = 1;
    }
}

// ---------------- embedding ----------------
__global__ void embed_k(const int* __restrict__ idx, const void* __restrict__ tok,
                        const void* __restrict__ pos, const int* __restrict__ flag,
                        __hip_bfloat16* __restrict__ x) {
    int i = blockIdx.x * blockDim.x + threadIdx.x;
    if (i >= XN) return;
    int f = *flag;
    int row = i / E_, e = i - row * E_;
    int t = row % T_;
    x[i] = __float2bfloat16(ldw(tok, (long long)idx[row] * E_ + e, f) +
                            ldw(pos, (long long)t * E_ + e, f));
}

// ---------------- layernorm: 4 rows per block (wave per row) ----------------
__global__ __launch_bounds__(256) void ln4_k(const __hip_bfloat16* __restrict__ x,
                     const void* __restrict__ g, long long goff,
                     const void* __restrict__ b, long long boff,
                     const int* __restrict__ flag,
                     __hip_bfloat16* __restrict__ out) {
    int f = *flag;
    int w = threadIdx.x >> 6, lane = threadIdx.x & 63;
    int row = blockIdx.x * 4 + w;
    const __hip_bfloat16* xr = x + (size_t)row * E_;
    float vals[6];
    float s = 0.f, ss = 0.f;
    #pragma unroll
    for (int i = 0; i < 6; i++) {
        float v = __bfloat162float(xr[lane + 64 * i]);
        vals[i] = v; s += v; ss += v * v;
    }
    #pragma unroll
    for (int off = 32; off; off >>= 1) {
        s  += __shfl_down(s,  off, 64);
        ss += __shfl_down(ss, off, 64);
    }
    s = __shfl(s, 0, 64); ss = __shfl(ss, 0, 64);
    float mu = s * (1.f / E_);
    float var = ss * (1.f / E_) - mu * mu;
    float rs = rsqrtf(var + 1e-5f);
    __hip_bfloat16* orow = out + (size_t)row * E_;
    #pragma unroll
    for (int i = 0; i < 6; i++) {
        int e = lane + 64 * i;
        float r = (vals[i] - mu) * rs * ldw(g, goff + e, f) + ldw(b, boff + e, f);
        orow[e] = __float2bfloat16(r);
    }
}

// ---------------- XCD-aware bijective block swizzle (nwg % 8 == 0 for all launches) ----
// Consecutive dispatch slots round-robin over 8 XCDs; remap so each XCD owns a
// contiguous chunk of tile indices (row-blocks with all col-blocks adjacent) ->
// A row-tiles fetched once, W held per-XCD L2.
__device__ __forceinline__ void xcd_swz(int nx, int& bx, int& by) {
    int ld = blockIdx.y * gridDim.x + blockIdx.x;
    int nwg = gridDim.x * gridDim.y;
    int cpx = nwg >> 3;
    int t = (ld & 7) * cpx + (ld >> 3);
    bx = t % nx;
    by = t / nx;
}

// ---------------- MFMA GEMM body: 128x128 tile, BK=64, 2-deep reg prefetch ----------------
// Pair-unrolled K-loop (tile count K/64 is even: 6 or 24). Two named reg sets
// (arA/rwA, arB/rwB) so the ds_write of tile t consumes loads issued a full
// iteration earlier; stores placed AFTER the MFMA cluster so their vmcnt wait
// does not block MFMA issue. One barrier per tile.
template<bool GUARD>
__device__ __forceinline__ void gemm_mfma_body(
        const __hip_bfloat16* __restrict__ A,
        const void* __restrict__ W, long long woff,
        const void* __restrict__ bias, long long boff, int has_bias,
        int f, void* __restrict__ Cv, int c_f32,
        int N, int K, int residual, int relu,
        int bx, int by, u32* As, u32* Ws) {
    const int tid = threadIdx.x;
    const int lane = tid & 63;
    const int wv = tid >> 6;
    const int wr = wv >> 1, wc = wv & 1;
    const int row0 = by << 7;
    const int col0 = bx << 7;
    const int l15 = lane & 15, l4 = lane >> 4;

    f32x4 acc[4][4];
    #pragma unroll
    for (int m = 0; m < 4; m++)
        #pragma unroll
        for (int n = 0; n < 4; n++)
            acc[m][n] = f32x4{0.f, 0.f, 0.f, 0.f};

    const int arow = tid >> 3;        // 0..31
    const int aslot = tid & 7;        // 16B slot in 128B k-row
    const u16* Ab = (const u16*)A + (size_t)row0 * K;
    const int wcol0 = tid & 63;
    const int ksbase = (tid >> 6) << 1;

    uint4 arA[4], arB[4];             // raw A (bf16 x8 each)
    u32 rwA[32], rwB[32];             // raw W (f32 bits or zext bf16)

    auto loadT = [&](uint4 (&ar)[4], u32 (&rw)[32], int kt) {
        #pragma unroll
        for (int p = 0; p < 4; p++)
            ar[p] = *(const uint4*)(Ab + (size_t)(arow + (p << 5)) * K + kt + aslot * 8);
        #pragma unroll
        for (int p = 0; p < 4; p++) {
            int c = wcol0 + ((p & 1) << 6);
            int ks = ksbase + (p >> 1);
            bool ok = !GUARD || (col0 + c) < N;
            if (f) {
                const float* Wf = (const float*)W + woff + (size_t)(kt + ks * 8) * N + col0 + c;
                #pragma unroll
                for (int i = 0; i < 8; i++)
                    rw[p * 8 + i] = ok ? __float_as_uint(Wf[(size_t)i * N]) : 0u;
            } else {
                const u16* Wb = (const u16*)W + woff + (size_t)(kt + ks * 8) * N + col0 + c;
                #pragma unroll
                for (int i = 0; i < 8; i++)
                    rw[p * 8 + i] = ok ? (u32)Wb[(size_t)i * N] : 0u;
            }
        }
    };
    auto storeT = [&](const uint4 (&ar)[4], const u32 (&rw)[32], int buf) {
        #pragma unroll
        for (int p = 0; p < 4; p++) {
            int r = arow + (p << 5);
            uint4 o;
            o.x = pack_h2(blo(ar[p].x), bhi(ar[p].x));
            o.y = pack_h2(blo(ar[p].y), bhi(ar[p].y));
            o.z = pack_h2(blo(ar[p].z), bhi(ar[p].z));
            o.w = pack_h2(blo(ar[p].w), bhi(ar[p].w));
            *(uint4*)&As[(size_t)(buf * 128 + r) * 32 + ((aslot ^ (r & 7)) << 2)] = o;
        }
        #pragma unroll
        for (int p = 0; p < 4; p++) {
            int c = wcol0 + ((p & 1) << 6);
            int ks = ksbase + (p >> 1);
            uint4 o;
            if (f) {
                o.x = pack_h2(u2f(rw[p * 8 + 0]), u2f(rw[p * 8 + 1]));
                o.y = pack_h2(u2f(rw[p * 8 + 2]), u2f(rw[p * 8 + 3]));
                o.z = pack_h2(u2f(rw[p * 8 + 4]), u2f(rw[p * 8 + 5]));
                o.w = pack_h2(u2f(rw[p * 8 + 6]), u2f(rw[p * 8 + 7]));
            } else {
                o.x = pack_h2(b2f((u16)rw[p * 8 + 0]), b2f((u16)rw[p * 8 + 1]));
                o.y = pack_h2(b2f((u16)rw[p * 8 + 2]), b2f((u16)rw[p * 8 + 3]));
                o.z = pack_h2(b2f((u16)rw[p * 8 + 4]), b2f((u16)rw[p * 8 + 5]));
                o.w = pack_h2(b2f((u16)rw[p * 8 + 6]), b2f((u16)rw[p * 8 + 7]));
            }
            *(uint4*)&Ws[(size_t)(buf * 128 + c) * 32 + ((ks ^ (c & 7)) << 2)] = o;
        }
    };
    auto computeT = [&](int buf) {
        __builtin_amdgcn_s_setprio(1);
        #pragma unroll
        for (int kh = 0; kh < 2; kh++) {
            f16x8 af[4], wfr[4];
            int s = (kh << 2) + l4;
            #pragma unroll
            for (int m = 0; m < 4; m++) {
                int r = (wr << 6) + (m << 4) + l15;
                af[m] = *(const f16x8*)&As[(size_t)(buf * 128 + r) * 32 + ((s ^ (r & 7)) << 2)];
            }
            #pragma unroll
            for (int n = 0; n < 4; n++) {
                int c = (wc << 6) + (n << 4) + l15;
                wfr[n] = *(const f16x8*)&Ws[(size_t)(buf * 128 + c) * 32 + ((s ^ (c & 7)) << 2)];
            }
            #pragma unroll
            for (int m = 0; m < 4; m++)
                #pragma unroll
                for (int n = 0; n < 4; n++)
                    acc[m][n] = __builtin_amdgcn_mfma_f32_16x16x32_f16(af[m], wfr[n], acc[m][n], 0, 0, 0);
        }
        __builtin_amdgcn_s_setprio(0);
    };

    const int ntile = K >> 6;          // 6 or 24 (even by construction)
    loadT(arA, rwA, 0);
    storeT(arA, rwA, 0);               // prologue: full-latency stall (once)
    loadT(arB, rwB, 64);
    __syncthreads();
    for (int t = 0; t + 2 <= ntile; t += 2) {
        // first half: tile t from L0; issue loads for tile t+2; store tile t+1
        if (t + 2 < ntile) loadT(arA, rwA, (t + 2) << 6);
        __builtin_amdgcn_sched_barrier(0);
        computeT(0);
        __builtin_amdgcn_sched_barrier(0);
        storeT(arB, rwB, 1);
        __syncthreads();
        // second half: tile t+1 from L1; issue loads for tile t+3; store tile t+2
        if (t + 3 < ntile) loadT(arB, rwB, (t + 3) << 6);
        __builtin_amdgcn_sched_barrier(0);
        computeT(1);
        __builtin_amdgcn_sched_barrier(0);
        if (t + 2 < ntile) storeT(arA, rwA, 0);
        __syncthreads();
    }

    // ---- epilogue ----
    float bv[4];
    #pragma unroll
    for (int n = 0; n < 4; n++) {
        int col = col0 + (wc << 6) + (n << 4) + l15;
        bv[n] = (has_bias && (!GUARD || col < N)) ? ldw(bias, boff + col, f) : 0.f;
    }
    #pragma unroll
    for (int m = 0; m < 4; m++) {
        #pragma unroll
        for (int i = 0; i < 4; i++) {
            int row = row0 + (wr << 6) + (m << 4) + (l4 << 2) + i;
            #pragma unroll
            for (int n = 0; n < 4; n++) {
                int col = col0 + (wc << 6) + (n << 4) + l15;
                if (GUARD && col >= N) continue;
                float r = acc[m][n][i] + bv[n];
                size_t o = (size_t)row * N + col;
                if (c_f32) {
                    ((float*)Cv)[o] = r;
                } else {
                    __hip_bfloat16* C = (__hip_bfloat16*)Cv;
                    if (residual) r += __bfloat162float(C[o]);
                    if (relu) r = fmaxf(r, 0.f);
                    C[o] = __float2bfloat16(r);
                }
            }
        }
    }
}

__global__ __launch_bounds__(256, 2) void gemm_mfma_k(
        const __hip_bfloat16* __restrict__ A,
        const void* __restrict__ W, long long woff,
        const void* __restrict__ bias, long long boff, int has_bias,
        const int* __restrict__ flag,
        __hip_bfloat16* __restrict__ C,
        int N, int K, int residual, int relu) {
    __shared__ __align__(16) u32 As[2 * 128 * 32];   // 32 KB
    __shared__ __align__(16) u32 Ws[2 * 128 * 32];   // 32 KB
    int bx, by;
    xcd_swz(gridDim.x, bx, by);
    gemm_mfma_body<false>(A, W, woff, bias, boff, has_bias, *flag, C, 0,
                          N, K, residual, relu, bx, by, As, Ws);
}

// fused Q/K/V: grid (9, 128); per row-block the 9 tiles (3 weights x 3 cols) are
// adjacent after the swizzle so they share the A row-tile in one XCD's L2.
__global__ __launch_bounds__(256, 2) void gemm_qkv_k(
        const __hip_bfloat16* __restrict__ A,
        const void* __restrict__ Wq, const void* __restrict__ Wk, const void* __restrict__ Wv,
        long long woff, const int* __restrict__ flag,
        __hip_bfloat16* __restrict__ qb, __hip_bfloat16* __restrict__ kb,
        __hip_bfloat16* __restrict__ vb) {
    __shared__ __align__(16) u32 As[2 * 128 * 32];
    __shared__ __align__(16) u32 Ws[2 * 128 * 32];
    int sx, by;
    xcd_swz(9, sx, by);
    int which = sx / 3, bx = sx % 3;
    const void* W = (which == 0) ? Wq : (which == 1) ? Wk : Wv;
    __hip_bfloat16* C = (which == 0) ? qb : (which == 1) ? kb : vb;
    gemm_mfma_body<false>(A, W, woff, nullptr, 0, 0, *flag, C, 0,
                          E_, E_, 0, 0, bx, by, As, Ws);
}

// lm head: N=65 inside one guarded 128-col tile, f32 out. grid (1, 128).
__global__ __launch_bounds__(256, 2) void gemm_lm_k(
        const __hip_bfloat16* __restrict__ A,
        const void* __restrict__ W,
        const void* __restrict__ bias,
        const int* __restrict__ flag,
        float* __restrict__ logits) {
    __shared__ __align__(16) u32 As[2 * 128 * 32];
    __shared__ __align__(16) u32 Ws[2 * 128 * 32];
    int bx, by;
    xcd_swz(1, bx, by);
    gemm_mfma_body<true>(A, W, 0, bias, 0, 1, *flag, logits, 1,
                         V_, E_, 0, 0, bx, by, As, Ws);
}

// ---------------- MFMA attention (verbatim from round 2) ----------------
template<int NK>
__device__ __forceinline__ void attn_body(
        const u16* __restrict__ qbase, const u16* __restrict__ kbase,
        const u16* __restrict__ vbase, u16* __restrict__ abase,
        int q0, u32* Kls, u32* Pls) {
    constexpr int NKF = NK / 16;
    constexpr int NKS = NK / 32;
    const int tid = threadIdx.x;
    const int lane = tid & 63;
    const int w = tid >> 6;
    const int l15 = lane & 15, l4 = lane >> 4;

    {
        int r8 = tid >> 3, slot = tid & 7;
        #pragma unroll
        for (int p = 0; p < NK / 32; p++) {
            int key = r8 + p * 32;
            uint4 a8 = *(const uint4*)(kbase + (size_t)key * E_ + slot * 8);
            uint4 o;
            o.x = pack_h2(blo(a8.x), bhi(a8.x));
            o.y = pack_h2(blo(a8.y), bhi(a8.y));
            o.z = pack_h2(blo(a8.z), bhi(a8.z));
            o.w = pack_h2(blo(a8.w), bhi(a8.w));
            *(uint4*)&Kls[key * 32 + ((slot ^ (key & 7)) << 2)] = o;
        }
    }
    __syncthreads();

    const int qrow = w * 16 + l15;
    const int qi = q0 + qrow;
    f32x4 acc[NKF];
    #pragma unroll
    for (int kf = 0; kf < NKF; kf++) acc[kf] = f32x4{0.f, 0.f, 0.f, 0.f};

    #pragma unroll
    for (int kh = 0; kh < 2; kh++) {
        uint4 q8 = *(const uint4*)(qbase + (size_t)qi * E_ + (kh * 4 + l4) * 8);
        union { f16x8 h; uint4 u; } qu;
        qu.u.x = pack_h2(blo(q8.x), bhi(q8.x));
        qu.u.y = pack_h2(blo(q8.y), bhi(q8.y));
        qu.u.z = pack_h2(blo(q8.z), bhi(q8.z));
        qu.u.w = pack_h2(blo(q8.w), bhi(q8.w));
        #pragma unroll
        for (int kf = 0; kf < NKF; kf++) {
            int krow = kf * 16 + l15;
            f16x8 kf8 = *(const f16x8*)&Kls[krow * 32 + ((((kh << 2) + l4) ^ (krow & 7)) << 2)];
            acc[kf] = __builtin_amdgcn_mfma_f32_16x16x32_f16(kf8, qu.h, acc[kf], 0, 0, 0);
        }
    }

    float m = -1e30f;
    #pragma unroll
    for (int kf = 0; kf < NKF; kf++)
        #pragma unroll
        for (int r = 0; r < 4; r++) {
            int key = kf * 16 + l4 * 4 + r;
            float s = acc[kf][r] * 0.125f;
            if (key > qi) s = -1e30f;
            acc[kf][r] = s;
            m = fmaxf(m, s);
        }
    m = fmaxf(m, __shfl_xor(m, 16, 64));
    m = fmaxf(m, __shfl_xor(m, 32, 64));
    float sum = 0.f;
    #pragma unroll
    for (int kf = 0; kf < NKF; kf++)
        #pragma unroll
        for (int r = 0; r < 4; r++) {
            float p = __expf(acc[kf][r] - m);
            acc[kf][r] = p;
            sum += p;
        }
    sum += __shfl_xor(sum, 16, 64);
    sum += __shfl_xor(sum, 32, 64);
    float inv = 1.f / sum;

    #pragma unroll
    for (int kf = 0; kf < NKF; kf++) {
        uint2 pw;
        pw.x = pack_h2(acc[kf][0] * inv, acc[kf][1] * inv);
        pw.y = pack_h2(acc[kf][2] * inv, acc[kf][3] * inv);
        int j = kf * 2 + (l4 >> 1);
        *(uint2*)&Pls[qrow * 128 + ((j ^ (qrow & 15)) << 2) + ((l4 & 1) << 1)] = pw;
    }
    __syncthreads();

    for (int kp = lane; kp < NK / 2; kp += 64) {
        #pragma unroll
        for (int dq = 0; dq < 2; dq++) {
            int db = w + dq * 4;
            uint4 v0 = *(const uint4*)(vbase + (size_t)(2 * kp) * E_ + db * 8);
            uint4 v1 = *(const uint4*)(vbase + (size_t)(2 * kp + 1) * E_ + db * 8);
            u32 uu[8];
            uu[0] = pack_h2(blo(v0.x), blo(v1.x));
            uu[1] = pack_h2(bhi(v0.x), bhi(v1.x));
            uu[2] = pack_h2(blo(v0.y), blo(v1.y));
            uu[3] = pack_h2(bhi(v0.y), bhi(v1.y));
            uu[4] = pack_h2(blo(v0.z), blo(v1.z));
            uu[5] = pack_h2(bhi(v0.z), bhi(v1.z));
            uu[6] = pack_h2(blo(v0.w), blo(v1.w));
            uu[7] = pack_h2(bhi(v0.w), bhi(v1.w));
            #pragma unroll
            for (int i = 0; i < 8; i++) {
                int d = db * 8 + i;
                Kls[d * 128 + (((kp >> 2) ^ (d & 15)) << 2) + (kp & 3)] = uu[i];
            }
        }
    }
    __syncthreads();

    f32x4 o2[4];
    #pragma unroll
    for (int df = 0; df < 4; df++) o2[df] = f32x4{0.f, 0.f, 0.f, 0.f};
    #pragma unroll
    for (int ks = 0; ks < NKS; ks++) {
        f16x8 pa = *(const f16x8*)&Pls[qrow * 128 + (((ks * 4 + l4) ^ (qrow & 15)) << 2)];
        #pragma unroll
        for (int df = 0; df < 4; df++) {
            int d = df * 16 + l15;
            f16x8 vb8 = *(const f16x8*)&Kls[d * 128 + (((ks * 4 + l4) ^ (d & 15)) << 2)];
            o2[df] = __builtin_amdgcn_mfma_f32_16x16x32_f16(pa, vb8, o2[df], 0, 0, 0);
        }
    }
    #pragma unroll
    for (int df = 0; df < 4; df++)
        #pragma unroll
        for (int r = 0; r < 4; r++) {
            int qg = q0 + w * 16 + l4 * 4 + r;
            abase[(size_t)qg * E_ + df * 16 + l15] = f2b(o2[df][r]);
        }
}

__global__ __launch_bounds__(256) void attn_mfma_k(
        const __hip_bfloat16* __restrict__ q, const __hip_bfloat16* __restrict__ k,
        const __hip_bfloat16* __restrict__ v, __hip_bfloat16* __restrict__ att) {
    __shared__ __align__(16) u32 Kls[256 * 32];   // 32 KB
    __shared__ __align__(16) u32 Pls[64 * 128];   // 32 KB
    int chunk = blockIdx.x & 3;
    int bh = blockIdx.x >> 2;
    int b = bh / H_, h = bh % H_;
    const u16* qbase = (const u16*)q + ((size_t)b * T_) * E_ + h * D_;
    const u16* kbase = (const u16*)k + ((size_t)b * T_) * E_ + h * D_;
    const u16* vbase = (const u16*)v + ((size_t)b * T_) * E_ + h * D_;
    u16* abase = (u16*)att + ((size_t)b * T_) * E_ + h * D_;
    int q0 = chunk * 64;
    switch (chunk) {
        case 0: attn_body< 64>(qbase, kbase, vbase, abase, q0, Kls, Pls); break;
        case 1: attn_body<128>(qbase, kbase, vbase, abase, q0, Kls, Pls); break;
        case 2: attn_body<192>(qbase, kbase, vbase, abase, q0, Kls, Pls); break;
        default: attn_body<256>(qbase, kbase, vbase, abase, q0, Kls, Pls); break;
    }
}

// ---------------- loss tail ----------------
__global__ void outcvt_k(const float* __restrict__ logits, const int* __restrict__ flag,
                         void* __restrict__ out) {
    int i = blockIdx.x * blockDim.x + threadIdx.x;
    if (i >= BT * V_) return;
    if (*flag) ((float*)out)[i] = logits[i];
    else ((__hip_bfloat16*)out)[i] = __float2bfloat16(logits[i]);
}

// 256 blocks x 4 waves; each wave does 16 rows; ONE atomic per block.
__global__ __launch_bounds__(256) void rowloss2_k(
        const float* __restrict__ logits, const int* __restrict__ tgt,
        float* __restrict__ accum) {
    __shared__ float part[4];
    int w = threadIdx.x >> 6, lane = threadIdx.x & 63;
    float local = 0.f;
    for (int i = 0; i < 16; i++) {
        int row = blockIdx.x * 64 + w * 16 + i;
        const float* lr = logits + (size_t)row * V_;
        float v0 = lr[lane];
        float v64 = (lane == 0) ? lr[64] : -1e30f;
        float m = fmaxf(v0, v64);
        #pragma unroll
        for (int off = 32; off; off >>= 1) m = fmaxf(m, __shfl_xor(m, off, 64));
        float se = __expf(v0 - m) + ((lane == 0) ? __expf(v64 - m) : 0.f);
        #pragma unroll
        for (int off = 32; off; off >>= 1) se += __shfl_xor(se, off, 64);
        if (lane == 0) local += lr[tgt[row]] - m - __logf(se);
    }
    if (lane == 0) part[w] = local;
    __syncthreads();
    if (threadIdx.x == 0)
        atomicAdd(accum, -(part[0] + part[1] + part[2] + part[3]));
}

__global__ void final_k(const float* __restrict__ accum, const int* __restrict__ flag,
                        void* __restrict__ out) {
    if (threadIdx.x == 0) {
        float v = *accum * (1.f / BT);
        if (*flag) ((float*)out)[(size_t)BT * V_] = v;
        else ((__hip_bfloat16*)out)[(size_t)BT * V_] = __float2bfloat16(v);
    }
}

extern "C" void kernel_launch(void* const* d_in, const int* in_sizes, int n_in,
                              void* d_out, int out_size, void* d_ws, size_t ws_size,
                              hipStream_t stream) {
    const int* idx     = (const int*)d_in[0];
    const int* targets = (const int*)d_in[1];
    const void* tok  = d_in[2];
    const void* pos  = d_in[3];
    const void* Wq   = d_in[4];
    const void* Wk   = d_in[5];
    const void* Wv   = d_in[6];
    const void* Wo   = d_in[7];
    const void* bo   = d_in[8];
    const void* W1   = d_in[9];
    const void* b1   = d_in[10];
    const void* W2   = d_in[11];
    const void* b2   = d_in[12];
    const void* ln1g = d_in[13];
    const void* ln1b = d_in[14];
    const void* ln2g = d_in[15];
    const void* ln2b = d_in[16];
    const void* lnfg = d_in[17];
    const void* lnfb = d_in[18];
    const void* Wlm  = d_in[19];
    const void* blm  = d_in[20];

    // ---- workspace layout IDENTICAL to passing rounds ----
    char* wsb = (char*)d_ws;
    int*   flag    = (int*)wsb;
    float* lossacc = (float*)(wsb + 8);
    float* logits  = (float*)(wsb + 256);
    __hip_bfloat16* xb = (__hip_bfloat16*)(wsb + 256 + sizeof(float) * (size_t)BT * V_);
    __hip_bfloat16* hb = xb + (size_t)XN;
    __hip_bfloat16* qb = hb + (size_t)XN;
    __hip_bfloat16* kb = qb + (size_t)XN;
    __hip_bfloat16* vb = kb + (size_t)XN;
    __hip_bfloat16* ab = vb + (size_t)XN;
    __hip_bfloat16* ffnb = qb;

    dim3 grdEm(E_ / 128, BT / 128);   // (3, 128)  nwg=384
    dim3 grdFm(F_ / 128, BT / 128);   // (12, 128) nwg=1536
    dim3 grdQKV(9, BT / 128);         // nwg=1152
    dim3 grdLM(1, BT / 128);          // nwg=128
    const long long EE = (long long)E_ * E_;

    init_k<<<1, 64, 0, stream>>>(flag, lossacc);
    detect_k<<<(V_ * E_ + 255) / 256, 256, 0, stream>>>(tok, V_ * E_, flag);
    embed_k<<<(XN + 255) / 256, 256, 0, stream>>>(idx, tok, pos, flag, xb);

    for (int l = 0; l < L_; l++) {
        ln4_k<<<BT / 4, 256, 0, stream>>>(xb, ln1g, (long long)l * E_, ln1b, (long long)l * E_, flag, hb);
        gemm_qkv_k<<<grdQKV, 256, 0, stream>>>(hb, Wq, Wk, Wv, l * EE, flag, qb, kb, vb);
        attn_mfma_k<<<B_ * H_ * 4, 256, 0, stream>>>(qb, kb, vb, ab);
        gemm_mfma_k<<<grdEm, 256, 0, stream>>>(ab, Wo, l * EE, bo, (long long)l * E_, 1, flag, xb, E_, E_, 1, 0);
        ln4_k<<<BT / 4, 256, 0, stream>>>(xb, ln2g, (long long)l * E_, ln2b, (long long)l * E_, flag, hb);
        gemm_mfma_k<<<grdFm, 256, 0, stream>>>(hb, W1, (long long)l * E_ * F_, b1, (long long)l * F_, 1, flag, ffnb, F_, E_, 0, 1);
        gemm_mfma_k<<<grdEm, 256, 0, stream>>>(ffnb, W2, (long long)l * F_ * E_, b2, (long long)l * E_, 1, flag, xb, E_, F_, 1, 0);
    }

    ln4_k<<<BT / 4, 256, 0, stream>>>(xb, lnfg, 0, lnfb, 0, flag, hb);
    gemm_lm_k<<<grdLM, 256, 0, stream>>>(hb, Wlm, blm, flag, logits);

    outcvt_k<<<(BT * V_ + 255) / 256, 256, 0, stream>>>(logits, flag, d_out);
    rowloss2_k<<<BT / 64, 256, 0, stream>>>(logits, targets, lossacc);
    final_k<<<1, 64, 0, stream>>>(lossacc, flag, d_out);
}

// Round 6
// 1342.300 us; speedup vs baseline: 4.7134x; 1.0248x over previous
//
#include <hip/hip_runtime.h>
#include <hip/hip_bf16.h>

typedef unsigned short u16;
typedef unsigned int u32;
typedef _Float16 h16x2 __attribute__((ext_vector_type(2)));
typedef _Float16 f16x8 __attribute__((ext_vector_type(8)));
typedef float f32x4 __attribute__((ext_vector_type(4)));

constexpr int B_ = 64, T_ = 256, V_ = 65, E_ = 384, H_ = 6, L_ = 6, D_ = 64, F_ = 1536;
constexpr int BT = B_ * T_;
constexpr int XN = BT * E_;
constexpr long long EE = (long long)E_ * E_;          // 147456
constexpr long long EF = (long long)E_ * F_;          // 589824

__device__ __forceinline__ float ldw(const void* p, long long i, int f32) {
    return f32 ? ((const float*)p)[i]
               : __bfloat162float(((const __hip_bfloat16*)p)[i]);
}
__device__ __forceinline__ u16 f2hu(float f) { union { _Float16 h; u16 u; } x; x.h = (_Float16)f; return x.u; }
__device__ __forceinline__ u32 pack_h2(float a, float b) {
    union { h16x2 h; u32 u; } x;
    x.h[0] = (_Float16)a; x.h[1] = (_Float16)b;
    return x.u;
}
// combine low/high f16 halves of two u32s (k-pair build from two V rows)
__device__ __forceinline__ u32 pk_lo(u32 a, u32 b) { return (a & 0xffffu) | (b << 16); }
__device__ __forceinline__ u32 pk_hi(u32 a, u32 b) { return (a >> 16) | (b & 0xffff0000u); }

__global__ void init_k(int* flag, float* lossacc) {
    if (threadIdx.x == 0) { *flag = 0; *lossacc = 0.f; }
}

__global__ void detect_k(const void* tok, int n, int* flag) {
    int i = blockIdx.x * blockDim.x + threadIdx.x;
    if (i < n) {
        float v = __bfloat162float(((const __hip_bfloat16*)tok)[i]);
        if (!(fabsf(v) < 1e4f)) *flag = 1;
    }
}

// ---------------- per-layer weight transpose: W[K][N] (bf16|f32) -> Wt[N][K] f16 ----------
// slot layout: [Wq|Wk|Wv|Wo](4*EE) | W1t (EF, [F][E]) | W2t (EF, [E][F])
__global__ __launch_bounds__(256) void wtrans_l_k(
        const void* __restrict__ Wq, const void* __restrict__ Wk,
        const void* __restrict__ Wv, const void* __restrict__ Wo,
        const void* __restrict__ W1, const void* __restrict__ W2,
        int l, const int* __restrict__ flag, _Float16* __restrict__ wls) {
    int f = *flag;
    int r = blockIdx.x;          // 0..431
    const void* src; long long soff; _Float16* dst;
    int K, N, kt, nt;
    if (r < 144) {
        int m = r / 36, t = r % 36;
        src = (m == 0) ? Wq : (m == 1) ? Wk : (m == 2) ? Wv : Wo;
        soff = (long long)l * EE;
        dst = wls + (size_t)m * EE;
        K = E_; N = E_; kt = t / 6; nt = t % 6;
    } else if (r < 288) {
        int t = r - 144;
        src = W1; soff = (long long)l * EF;
        dst = wls + 4 * EE;
        K = E_; N = F_; kt = t / 24; nt = t % 24;
    } else {
        int t = r - 288;
        src = W2; soff = (long long)l * EF;
        dst = wls + 4 * EE + EF;
        K = F_; N = E_; kt = t / 6; nt = t % 6;
    }
    __shared__ _Float16 tile[64][65];
    int k0 = kt * 64, n0 = nt * 64;
    #pragma unroll 4
    for (int p = 0; p < 16; p++) {
        int k = p * 4 + (threadIdx.x >> 6), n = threadIdx.x & 63;
        tile[k][n] = (_Float16)ldw(src, soff + (long long)(k0 + k) * N + n0 + n, f);
    }
    __syncthreads();
    #pragma unroll 4
    for (int p = 0; p < 16; p++) {
        int n = p * 4 + (threadIdx.x >> 6), k = threadIdx.x & 63;
        dst[(size_t)(n0 + n) * K + k0 + k] = tile[k][n];
    }
}

// lm head: Wlm[E][V] -> wlm[128 padded rows][E] f16 (rows >= V zero)
__global__ __launch_bounds__(256) void wtrans_lm_k(
        const void* __restrict__ Wlm, const int* __restrict__ flag,
        _Float16* __restrict__ wlm) {
    int f = *flag;
    int t = blockIdx.x;          // 0..11
    int kt = t / 2, nt = t % 2;
    __shared__ _Float16 tile[64][65];
    int k0 = kt * 64, n0 = nt * 64;
    #pragma unroll 4
    for (int p = 0; p < 16; p++) {
        int k = p * 4 + (threadIdx.x >> 6), n = threadIdx.x & 63;
        float v = (n0 + n < V_) ? ldw(Wlm, (long long)(k0 + k) * V_ + n0 + n, f) : 0.f;
        tile[k][n] = (_Float16)v;
    }
    __syncthreads();
    #pragma unroll 4
    for (int p = 0; p < 16; p++) {
        int n = p * 4 + (threadIdx.x >> 6), k = threadIdx.x & 63;
        wlm[(size_t)(n0 + n) * E_ + k0 + k] = tile[k][n];
    }
}

// ---------------- embedding (residual stream xb stays bf16) ----------------
__global__ void embed_k(const int* __restrict__ idx, const void* __restrict__ tok,
                        const void* __restrict__ pos, const int* __restrict__ flag,
                        __hip_bfloat16* __restrict__ x) {
    int i = blockIdx.x * blockDim.x + threadIdx.x;
    if (i >= XN) return;
    int f = *flag;
    int row = i / E_, e = i - row * E_;
    int t = row % T_;
    x[i] = __float2bfloat16(ldw(tok, (long long)idx[row] * E_ + e, f) +
                            ldw(pos, (long long)t * E_ + e, f));
}

// ---------------- layernorm: bf16 in, f16 out, 4 rows/block ----------------
__global__ __launch_bounds__(256) void ln4_k(const __hip_bfloat16* __restrict__ x,
                     const void* __restrict__ g, long long goff,
                     const void* __restrict__ b, long long boff,
                     const int* __restrict__ flag,
                     _Float16* __restrict__ out) {
    int f = *flag;
    int w = threadIdx.x >> 6, lane = threadIdx.x & 63;
    int row = blockIdx.x * 4 + w;
    const __hip_bfloat16* xr = x + (size_t)row * E_;
    float vals[6];
    float s = 0.f, ss = 0.f;
    #pragma unroll
    for (int i = 0; i < 6; i++) {
        float v = __bfloat162float(xr[lane + 64 * i]);
        vals[i] = v; s += v; ss += v * v;
    }
    #pragma unroll
    for (int off = 32; off; off >>= 1) {
        s  += __shfl_down(s,  off, 64);
        ss += __shfl_down(ss, off, 64);
    }
    s = __shfl(s, 0, 64); ss = __shfl(ss, 0, 64);
    float mu = s * (1.f / E_);
    float var = ss * (1.f / E_) - mu * mu;
    float rs = rsqrtf(var + 1e-5f);
    _Float16* orow = out + (size_t)row * E_;
    #pragma unroll
    for (int i = 0; i < 6; i++) {
        int e = lane + 64 * i;
        float r = (vals[i] - mu) * rs * ldw(g, goff + e, f) + ldw(b, boff + e, f);
        orow[e] = (_Float16)r;
    }
}

// ---------------- XCD-aware bijective block swizzle (nwg % 8 == 0) ----------------
__device__ __forceinline__ void xcd_swz(int nx, int& bx, int& by) {
    int ld = blockIdx.y * gridDim.x + blockIdx.x;
    int nwg = gridDim.x * gridDim.y;
    int cpx = nwg >> 3;
    int t = (ld & 7) * cpx + (ld >> 3);
    bx = t % nx;
    by = t / nx;
}

// ---------------- async stage: 128 rows x 64 k (f16) -> 16KB LDS buffer ----------------
// global_load_lds, 16B/lane. LDS dest linear; SOURCE pre-inverse-swizzled so that
// LDS physical slot p of row r holds logical slot p^(r&7) (rule-21 both-sides pattern;
// read side then uses physical = s ^ (r&7), identical to the proven r2-r4 read math).
__device__ __forceinline__ void stage_lds(const u16* __restrict__ gsrc, int ldK,
                                          u32* lbuf, int wi, int lane) {
    #pragma unroll
    for (int p = 0; p < 4; p++) {
        int i = (wi << 2) + p;
        int S = (i << 6) + lane;
        int r = S >> 3, cs = S & 7;
        const u16* gp = gsrc + (size_t)r * ldK + ((cs ^ (r & 7)) << 3);
        __builtin_amdgcn_global_load_lds(
            (const __attribute__((address_space(1))) u32*)gp,
            (__attribute__((address_space(3))) u32*)(lbuf + (i << 8)),
            16, 0, 0);
    }
}

// ---------------- MFMA GEMM body: 128x128 tile, BK=64, gload_lds double-buffer ----------
// CMODE: 0 = f16 out (+relu opt), 1 = bf16 residual out, 2 = f32 out guarded (lm head)
template<int CMODE>
__device__ __forceinline__ void gemm_body(
        const _Float16* __restrict__ A,
        const _Float16* __restrict__ Wt,     // [N][K] f16 pre-transposed
        const void* __restrict__ bias, long long boff, int has_bias, int f,
        void* __restrict__ Cv, int N, int K, int relu,
        int bx, int by, u32* Af, u32* Wf) {
    const int tid = threadIdx.x;
    const int lane = tid & 63;
    const int wi = tid >> 6;
    const int wr = wi >> 1, wc = wi & 1;
    const int row0 = by << 7, col0 = bx << 7;
    const int l15 = lane & 15, l4 = lane >> 4;

    f32x4 acc[4][4];
    #pragma unroll
    for (int m = 0; m < 4; m++)
        #pragma unroll
        for (int n = 0; n < 4; n++)
            acc[m][n] = f32x4{0.f, 0.f, 0.f, 0.f};

    const u16* Ab = (const u16*)A + (size_t)row0 * K;
    const u16* Wb = (const u16*)Wt + (size_t)col0 * K;

    const int ntile = K >> 6;
    stage_lds(Ab, K, Af, wi, lane);
    stage_lds(Wb, K, Wf, wi, lane);
    asm volatile("s_waitcnt vmcnt(0)" ::: "memory");
    __syncthreads();

    for (int t = 0; t < ntile; t++) {
        int buf = t & 1;
        if (t + 1 < ntile) {
            stage_lds(Ab + ((t + 1) << 6), K, Af + ((buf ^ 1) << 12), wi, lane);
            stage_lds(Wb + ((t + 1) << 6), K, Wf + ((buf ^ 1) << 12), wi, lane);
        }
        __builtin_amdgcn_s_setprio(1);
        #pragma unroll
        for (int kh = 0; kh < 2; kh++) {
            f16x8 a4[4], w4[4];
            int s = (kh << 2) + l4;
            #pragma unroll
            for (int m = 0; m < 4; m++) {
                int r = (wr << 6) + (m << 4) + l15;
                a4[m] = *(const f16x8*)&Af[(buf << 12) + r * 32 + ((s ^ (r & 7)) << 2)];
            }
            #pragma unroll
            for (int n = 0; n < 4; n++) {
                int c = (wc << 6) + (n << 4) + l15;
                w4[n] = *(const f16x8*)&Wf[(buf << 12) + c * 32 + ((s ^ (c & 7)) << 2)];
            }
            #pragma unroll
            for (int m = 0; m < 4; m++)
                #pragma unroll
                for (int n = 0; n < 4; n++)
                    acc[m][n] = __builtin_amdgcn_mfma_f32_16x16x32_f16(a4[m], w4[n], acc[m][n], 0, 0, 0);
        }
        __builtin_amdgcn_s_setprio(0);
        asm volatile("s_waitcnt vmcnt(0)" ::: "memory");
        __syncthreads();
    }

    // ---- epilogue ----
    float bv[4];
    #pragma unroll
    for (int n = 0; n < 4; n++) {
        int col = col0 + (wc << 6) + (n << 4) + l15;
        bv[n] = (has_bias && (CMODE != 2 || col < N)) ? ldw(bias, boff + col, f) : 0.f;
    }
    #pragma unroll
    for (int m = 0; m < 4; m++) {
        #pragma unroll
        for (int i = 0; i < 4; i++) {
            int row = row0 + (wr << 6) + (m << 4) + (l4 << 2) + i;
            #pragma unroll
            for (int n = 0; n < 4; n++) {
                int col = col0 + (wc << 6) + (n << 4) + l15;
                if (CMODE == 2 && col >= N) continue;
                float r = acc[m][n][i] + bv[n];
                size_t o = (size_t)row * N + col;
                if (CMODE == 0) {
                    if (relu) r = fmaxf(r, 0.f);
                    ((_Float16*)Cv)[o] = (_Float16)r;
                } else if (CMODE == 1) {
                    __hip_bfloat16* C = (__hip_bfloat16*)Cv;
                    r += __bfloat162float(C[o]);
                    C[o] = __float2bfloat16(r);
                } else {
                    ((float*)Cv)[o] = r;
                }
            }
        }
    }
}

__global__ __launch_bounds__(256, 2) void gemm_f16o_k(
        const _Float16* __restrict__ A, const _Float16* __restrict__ Wt,
        const void* __restrict__ bias, long long boff, const int* __restrict__ flag,
        _Float16* __restrict__ C, int N, int K, int relu) {
    __shared__ __align__(16) u32 Af[8192];
    __shared__ __align__(16) u32 Wf[8192];
    int bx, by;
    xcd_swz(gridDim.x, bx, by);
    gemm_body<0>(A, Wt, bias, boff, 1, *flag, C, N, K, relu, bx, by, Af, Wf);
}

__global__ __launch_bounds__(256, 2) void gemm_res_k(
        const _Float16* __restrict__ A, const _Float16* __restrict__ Wt,
        const void* __restrict__ bias, long long boff, const int* __restrict__ flag,
        __hip_bfloat16* __restrict__ C, int N, int K) {
    __shared__ __align__(16) u32 Af[8192];
    __shared__ __align__(16) u32 Wf[8192];
    int bx, by;
    xcd_swz(gridDim.x, bx, by);
    gemm_body<1>(A, Wt, bias, boff, 1, *flag, C, N, K, 0, bx, by, Af, Wf);
}

// fused Q/K/V: grid (9, 128)
__global__ __launch_bounds__(256, 2) void gemm_qkv_k(
        const _Float16* __restrict__ A, const _Float16* __restrict__ wls,
        _Float16* __restrict__ qb, _Float16* __restrict__ kb, _Float16* __restrict__ vb) {
    __shared__ __align__(16) u32 Af[8192];
    __shared__ __align__(16) u32 Wf[8192];
    int sx, by;
    xcd_swz(9, sx, by);
    int which = sx / 3, bx = sx % 3;
    const _Float16* Wt = wls + (size_t)which * EE;
    _Float16* C = (which == 0) ? qb : (which == 1) ? kb : vb;
    gemm_body<0>(A, Wt, nullptr, 0, 0, 0, C, E_, E_, 0, bx, by, Af, Wf);
}

// lm head: N=65 in one guarded 128-col tile (wlm padded to 128 rows), f32 out
__global__ __launch_bounds__(256, 2) void gemm_lmh_k(
        const _Float16* __restrict__ A, const _Float16* __restrict__ Wt,
        const void* __restrict__ bias, const int* __restrict__ flag,
        float* __restrict__ logits) {
    __shared__ __align__(16) u32 Af[8192];
    __shared__ __align__(16) u32 Wf[8192];
    int bx, by;
    xcd_swz(1, bx, by);
    gemm_body<2>(A, Wt, bias, 0, 1, *flag, logits, V_, E_, 0, bx, by, Af, Wf);
}

// ---------------- MFMA attention, f16 I/O ----------------
template<int NK>
__device__ __forceinline__ void attn_body(
        const u16* __restrict__ qbase, const u16* __restrict__ kbase,
        const u16* __restrict__ vbase, u16* __restrict__ abase,
        int q0, u32* Kls, u32* Pls) {
    constexpr int NKF = NK / 16;
    constexpr int NKS = NK / 32;
    const int tid = threadIdx.x;
    const int lane = tid & 63;
    const int w = tid >> 6;
    const int l15 = lane & 15, l4 = lane >> 4;

    {   // stage K [NK][64] f16 (pure copy), slot ^= key&7
        int r8 = tid >> 3, slot = tid & 7;
        #pragma unroll
        for (int p = 0; p < NK / 32; p++) {
            int key = r8 + p * 32;
            uint4 a8 = *(const uint4*)(kbase + (size_t)key * E_ + slot * 8);
            *(uint4*)&Kls[key * 32 + ((slot ^ (key & 7)) << 2)] = a8;
        }
    }
    __syncthreads();

    const int qrow = w * 16 + l15;
    const int qi = q0 + qrow;
    f32x4 acc[NKF];
    #pragma unroll
    for (int kf = 0; kf < NKF; kf++) acc[kf] = f32x4{0.f, 0.f, 0.f, 0.f};

    // ---- phase 1: S^T = K @ Q^T ----
    #pragma unroll
    for (int kh = 0; kh < 2; kh++) {
        f16x8 qh = *(const f16x8*)(qbase + (size_t)qi * E_ + ((kh << 2) + l4) * 8);
        #pragma unroll
        for (int kf = 0; kf < NKF; kf++) {
            int krow = kf * 16 + l15;
            f16x8 kf8 = *(const f16x8*)&Kls[krow * 32 + ((((kh << 2) + l4) ^ (krow & 7)) << 2)];
            acc[kf] = __builtin_amdgcn_mfma_f32_16x16x32_f16(kf8, qh, acc[kf], 0, 0, 0);
        }
    }

    float m = -1e30f;
    #pragma unroll
    for (int kf = 0; kf < NKF; kf++)
        #pragma unroll
        for (int r = 0; r < 4; r++) {
            int key = kf * 16 + l4 * 4 + r;
            float s = acc[kf][r] * 0.125f;
            if (key > qi) s = -1e30f;
            acc[kf][r] = s;
            m = fmaxf(m, s);
        }
    m = fmaxf(m, __shfl_xor(m, 16, 64));
    m = fmaxf(m, __shfl_xor(m, 32, 64));
    float sum = 0.f;
    #pragma unroll
    for (int kf = 0; kf < NKF; kf++)
        #pragma unroll
        for (int r = 0; r < 4; r++) {
            float p = __expf(acc[kf][r] - m);
            acc[kf][r] = p;
            sum += p;
        }
    sum += __shfl_xor(sum, 16, 64);
    sum += __shfl_xor(sum, 32, 64);
    float inv = 1.f / sum;

    #pragma unroll
    for (int kf = 0; kf < NKF; kf++) {
        uint2 pw;
        pw.x = pack_h2(acc[kf][0] * inv, acc[kf][1] * inv);
        pw.y = pack_h2(acc[kf][2] * inv, acc[kf][3] * inv);
        int j = kf * 2 + (l4 >> 1);
        *(uint2*)&Pls[qrow * 128 + ((j ^ (qrow & 15)) << 2) + ((l4 & 1) << 1)] = pw;
    }
    __syncthreads();

    // restage V^T into Kls (bit-ops only, f16 input)
    for (int kp = lane; kp < NK / 2; kp += 64) {
        #pragma unroll
        for (int dq = 0; dq < 2; dq++) {
            int db = w + dq * 4;
            uint4 v0 = *(const uint4*)(vbase + (size_t)(2 * kp) * E_ + db * 8);
            uint4 v1 = *(const uint4*)(vbase + (size_t)(2 * kp + 1) * E_ + db * 8);
            u32 uu[8];
            uu[0] = pk_lo(v0.x, v1.x); uu[1] = pk_hi(v0.x, v1.x);
            uu[2] = pk_lo(v0.y, v1.y); uu[3] = pk_hi(v0.y, v1.y);
            uu[4] = pk_lo(v0.z, v1.z); uu[5] = pk_hi(v0.z, v1.z);
            uu[6] = pk_lo(v0.w, v1.w); uu[7] = pk_hi(v0.w, v1.w);
            #pragma unroll
            for (int i = 0; i < 8; i++) {
                int d = db * 8 + i;
                Kls[d * 128 + (((kp >> 2) ^ (d & 15)) << 2) + (kp & 3)] = uu[i];
            }
        }
    }
    __syncthreads();

    f32x4 o2[4];
    #pragma unroll
    for (int df = 0; df < 4; df++) o2[df] = f32x4{0.f, 0.f, 0.f, 0.f};
    #pragma unroll
    for (int ks = 0; ks < NKS; ks++) {
        f16x8 pa = *(const f16x8*)&Pls[qrow * 128 + (((ks * 4 + l4) ^ (qrow & 15)) << 2)];
        #pragma unroll
        for (int df = 0; df < 4; df++) {
            int d = df * 16 + l15;
            f16x8 vb8 = *(const f16x8*)&Kls[d * 128 + (((ks * 4 + l4) ^ (d & 15)) << 2)];
            o2[df] = __builtin_amdgcn_mfma_f32_16x16x32_f16(pa, vb8, o2[df], 0, 0, 0);
        }
    }
    #pragma unroll
    for (int df = 0; df < 4; df++)
        #pragma unroll
        for (int r = 0; r < 4; r++) {
            int qg = q0 + w * 16 + l4 * 4 + r;
            abase[(size_t)qg * E_ + df * 16 + l15] = f2hu(o2[df][r]);
        }
}

__global__ __launch_bounds__(256) void attn_mfma_k(
        const _Float16* __restrict__ q, const _Float16* __restrict__ k,
        const _Float16* __restrict__ v, _Float16* __restrict__ att) {
    __shared__ __align__(16) u32 Kls[256 * 32];   // 32 KB
    __shared__ __align__(16) u32 Pls[64 * 128];   // 32 KB
    int chunk = blockIdx.x & 3;
    int bh = blockIdx.x >> 2;
    int b = bh / H_, h = bh % H_;
    const u16* qbase = (const u16*)q + ((size_t)b * T_) * E_ + h * D_;
    const u16* kbase = (const u16*)k + ((size_t)b * T_) * E_ + h * D_;
    const u16* vbase = (const u16*)v + ((size_t)b * T_) * E_ + h * D_;
    u16* abase = (u16*)att + ((size_t)b * T_) * E_ + h * D_;
    int q0 = chunk * 64;
    switch (chunk) {
        case 0: attn_body< 64>(qbase, kbase, vbase, abase, q0, Kls, Pls); break;
        case 1: attn_body<128>(qbase, kbase, vbase, abase, q0, Kls, Pls); break;
        case 2: attn_body<192>(qbase, kbase, vbase, abase, q0, Kls, Pls); break;
        default: attn_body<256>(qbase, kbase, vbase, abase, q0, Kls, Pls); break;
    }
}

// ---------------- loss tail ----------------
__global__ void outcvt_k(const float* __restrict__ logits, const int* __restrict__ flag,
                         void* __restrict__ out) {
    int i = blockIdx.x * blockDim.x + threadIdx.x;
    if (i >= BT * V_) return;
    if (*flag) ((float*)out)[i] = logits[i];
    else ((__hip_bfloat16*)out)[i] = __float2bfloat16(logits[i]);
}

__global__ __launch_bounds__(256) void rowloss2_k(
        const float* __restrict__ logits, const int* __restrict__ tgt,
        float* __restrict__ accum) {
    __shared__ float part[4];
    int w = threadIdx.x >> 6, lane = threadIdx.x & 63;
    float local = 0.f;
    for (int i = 0; i < 16; i++) {
        int row = blockIdx.x * 64 + w * 16 + i;
        const float* lr = logits + (size_t)row * V_;
        float v0 = lr[lane];
        float v64 = (lane == 0) ? lr[64] : -1e30f;
        float m = fmaxf(v0, v64);
        #pragma unroll
        for (int off = 32; off; off >>= 1) m = fmaxf(m, __shfl_xor(m, off, 64));
        float se = __expf(v0 - m) + ((lane == 0) ? __expf(v64 - m) : 0.f);
        #pragma unroll
        for (int off = 32; off; off >>= 1) se += __shfl_xor(se, off, 64);
        if (lane == 0) local += lr[tgt[row]] - m - __logf(se);
    }
    if (lane == 0) part[w] = local;
    __syncthreads();
    if (threadIdx.x == 0)
        atomicAdd(accum, -(part[0] + part[1] + part[2] + part[3]));
}

__global__ void final_k(const float* __restrict__ accum, const int* __restrict__ flag,
                        void* __restrict__ out) {
    if (threadIdx.x == 0) {
        float v = *accum * (1.f / BT);
        if (*flag) ((float*)out)[(size_t)BT * V_] = v;
        else ((__hip_bfloat16*)out)[(size_t)BT * V_] = __float2bfloat16(v);
    }
}

extern "C" void kernel_launch(void* const* d_in, const int* in_sizes, int n_in,
                              void* d_out, int out_size, void* d_ws, size_t ws_size,
                              hipStream_t stream) {
    const int* idx     = (const int*)d_in[0];
    const int* targets = (const int*)d_in[1];
    const void* tok  = d_in[2];
    const void* pos  = d_in[3];
    const void* Wq   = d_in[4];
    const void* Wk   = d_in[5];
    const void* Wv   = d_in[6];
    const void* Wo   = d_in[7];
    const void* bo   = d_in[8];
    const void* W1   = d_in[9];
    const void* b1   = d_in[10];
    const void* W2   = d_in[11];
    const void* b2   = d_in[12];
    const void* ln1g = d_in[13];
    const void* ln1b = d_in[14];
    const void* ln2g = d_in[15];
    const void* ln2b = d_in[16];
    const void* lnfg = d_in[17];
    const void* lnfb = d_in[18];
    const void* Wlm  = d_in[19];
    const void* blm  = d_in[20];

    // ---- workspace layout (total ~71 MiB, below the r2-r4 proven-safe footprint) ----
    // p: xb 2XN | hb 2XN | qb 2XN | kb 2XN | vb 2XN | wls 6.75MiB | wlm 96KiB
    // ffnb = qb overlay, spans [qb, qb+4XN) = qb+kb exactly (half-FFN: 8192 x F f16).
    char* wsb = (char*)d_ws;
    int*   flag    = (int*)wsb;
    float* lossacc = (float*)(wsb + 8);
    float* logits  = (float*)(wsb + 256);
    char* p = wsb + 256 + sizeof(float) * (size_t)BT * V_;
    __hip_bfloat16* xb = (__hip_bfloat16*)p;                 // bf16 residual stream
    _Float16* hb = (_Float16*)(p + 2 * (size_t)XN);
    _Float16* qb = (_Float16*)(p + 4 * (size_t)XN);
    _Float16* kb = (_Float16*)(p + 6 * (size_t)XN);
    _Float16* vb = (_Float16*)(p + 8 * (size_t)XN);
    _Float16* wls = (_Float16*)(p + 10 * (size_t)XN);        // 4*EE + 2*EF f16
    _Float16* wlm = wls + 4 * EE + 2 * EF;                   // 128*384 f16
    _Float16* ab = hb;       // attn out (hb dead after qkv gemm)
    _Float16* ffnb = qb;     // half-FFN hidden: 8192*1536 f16 = 4XN bytes (qb+kb)

    dim3 grdEm(3, 128);      // nwg=384
    dim3 grdQKV(9, 128);     // nwg=1152
    dim3 grdW1h(12, 64);     // nwg=768 (half rows)
    dim3 grdW2h(3, 64);      // nwg=192 (half rows)
    dim3 grdLM(1, 128);      // nwg=128
    constexpr int HROWS = BT / 2;   // 8192

    init_k<<<1, 64, 0, stream>>>(flag, lossacc);
    detect_k<<<(V_ * E_ + 255) / 256, 256, 0, stream>>>(tok, V_ * E_, flag);
    wtrans_lm_k<<<12, 256, 0, stream>>>(Wlm, flag, wlm);
    embed_k<<<(XN + 255) / 256, 256, 0, stream>>>(idx, tok, pos, flag, xb);

    for (int l = 0; l < L_; l++) {
        wtrans_l_k<<<432, 256, 0, stream>>>(Wq, Wk, Wv, Wo, W1, W2, l, flag, wls);
        ln4_k<<<BT / 4, 256, 0, stream>>>(xb, ln1g, (long long)l * E_, ln1b, (long long)l * E_, flag, hb);
        gemm_qkv_k<<<grdQKV, 256, 0, stream>>>(hb, wls, qb, kb, vb);
        attn_mfma_k<<<B_ * H_ * 4, 256, 0, stream>>>(qb, kb, vb, ab);
        gemm_res_k<<<grdEm, 256, 0, stream>>>(ab, wls + 3 * EE, bo, (long long)l * E_, flag, xb, E_, E_);
        ln4_k<<<BT / 4, 256, 0, stream>>>(xb, ln2g, (long long)l * E_, ln2b, (long long)l * E_, flag, hb);
        for (int h = 0; h < 2; h++) {
            gemm_f16o_k<<<grdW1h, 256, 0, stream>>>(hb + (size_t)h * HROWS * E_, wls + 4 * EE,
                                                    b1, (long long)l * F_, flag, ffnb, F_, E_, 1);
            gemm_res_k<<<grdW2h, 256, 0, stream>>>(ffnb, wls + 4 * EE + EF,
                                                   b2, (long long)l * E_, flag,
                                                   xb + (size_t)h * HROWS * E_, E_, F_);
        }
    }

    ln4_k<<<BT / 4, 256, 0, stream>>>(xb, lnfg, 0, lnfb, 0, flag, hb);
    gemm_lmh_k<<<grdLM, 256, 0, stream>>>(hb, wlm, blm, flag, logits);

    outcvt_k<<<(BT * V_ + 255) / 256, 256, 0, stream>>>(logits, flag, d_out);
    rowloss2_k<<<BT / 64, 256, 0, stream>>>(logits, targets, lossacc);
    final_k<<<1, 64, 0, stream>>>(lossacc, flag, d_out);
}

// Round 8
// 1318.913 us; speedup vs baseline: 4.7969x; 1.0177x over previous
//
#include <hip/hip_runtime.h>
#include <hip/hip_bf16.h>

typedef unsigned short u16;
typedef unsigned int u32;
typedef _Float16 h16x2 __attribute__((ext_vector_type(2)));
typedef _Float16 f16x8 __attribute__((ext_vector_type(8)));
typedef float f32x4 __attribute__((ext_vector_type(4)));

constexpr int B_ = 64, T_ = 256, V_ = 65, E_ = 384, H_ = 6, L_ = 6, D_ = 64, F_ = 1536;
constexpr int BT = B_ * T_;
constexpr int XN = BT * E_;
constexpr long long EE = (long long)E_ * E_;          // 147456
constexpr long long EF = (long long)E_ * F_;          // 589824
constexpr long long WSLOT = 4 * EE + 2 * EF;          // 1769472 f16 per layer

__device__ __forceinline__ float ldw(const void* p, long long i, int f32) {
    return f32 ? ((const float*)p)[i]
               : __bfloat162float(((const __hip_bfloat16*)p)[i]);
}
__device__ __forceinline__ u16 f2hu(float f) { union { _Float16 h; u16 u; } x; x.h = (_Float16)f; return x.u; }
__device__ __forceinline__ u16 f2b(float f) {
    __hip_bfloat16 h = __float2bfloat16(f);
    union { __hip_bfloat16 h; u16 u; } x; x.h = h; return x.u;
}
__device__ __forceinline__ float blo(u32 u) { union { u32 i; float f; } x; x.i = u << 16; return x.f; }
__device__ __forceinline__ float bhi(u32 u) { union { u32 i; float f; } x; x.i = u & 0xffff0000u; return x.f; }
__device__ __forceinline__ u32 pack_h2(float a, float b) {
    union { h16x2 h; u32 u; } x;
    x.h[0] = (_Float16)a; x.h[1] = (_Float16)b;
    return x.u;
}
// combine low/high f16 halves of two u32s (k-pair build from two V rows)
__device__ __forceinline__ u32 pk_lo(u32 a, u32 b) { return (a & 0xffffu) | (b << 16); }
__device__ __forceinline__ u32 pk_hi(u32 a, u32 b) { return (a >> 16) | (b & 0xffff0000u); }

__global__ void init_k(int* flag, float* lossacc) {
    if (threadIdx.x == 0) { *flag = 0; *lossacc = 0.f; }
}

__global__ void detect_k(const void* tok, int n, int* flag) {
    int i = blockIdx.x * blockDim.x + threadIdx.x;
    if (i < n) {
        float v = __bfloat162float(((const __hip_bfloat16*)tok)[i]);
        if (!(fabsf(v) < 1e4f)) *flag = 1;
    }
}

// ---------------- ALL weight transposes in ONE dispatch (hoisted out of layer loop) ----
// per-layer slot: [Wq|Wk|Wv|Wo](4*EE) | W1t (EF, [F][E]) | W2t (EF, [E][F])
// blocks 0..2591: layer tiles (l = b/432). blocks 2592..2603: lm head (padded 128 rows).
__global__ __launch_bounds__(256) void wtrans_all_k(
        const void* __restrict__ Wq, const void* __restrict__ Wk,
        const void* __restrict__ Wv, const void* __restrict__ Wo,
        const void* __restrict__ W1, const void* __restrict__ W2,
        const void* __restrict__ Wlm, const int* __restrict__ flag,
        _Float16* __restrict__ wt) {
    int f = *flag;
    int b = blockIdx.x;
    __shared__ _Float16 tile[64][65];
    if (b < 2592) {
        int l = b / 432, r = b % 432;
        const void* src; long long soff; _Float16* dst;
        int K, N, kt, nt;
        _Float16* wls = wt + (size_t)l * WSLOT;
        if (r < 144) {
            int m = r / 36, t = r % 36;
            src = (m == 0) ? Wq : (m == 1) ? Wk : (m == 2) ? Wv : Wo;
            soff = (long long)l * EE;
            dst = wls + (size_t)m * EE;
            K = E_; N = E_; kt = t / 6; nt = t % 6;
        } else if (r < 288) {
            int t = r - 144;
            src = W1; soff = (long long)l * EF;
            dst = wls + 4 * EE;
            K = E_; N = F_; kt = t / 24; nt = t % 24;
        } else {
            int t = r - 288;
            src = W2; soff = (long long)l * EF;
            dst = wls + 4 * EE + EF;
            K = F_; N = E_; kt = t / 6; nt = t % 6;
        }
        int k0 = kt * 64, n0 = nt * 64;
        #pragma unroll 4
        for (int p = 0; p < 16; p++) {
            int k = p * 4 + (threadIdx.x >> 6), n = threadIdx.x & 63;
            tile[k][n] = (_Float16)ldw(src, soff + (long long)(k0 + k) * N + n0 + n, f);
        }
        __syncthreads();
        #pragma unroll 4
        for (int p = 0; p < 16; p++) {
            int n = p * 4 + (threadIdx.x >> 6), k = threadIdx.x & 63;
            dst[(size_t)(n0 + n) * K + k0 + k] = tile[k][n];
        }
    } else {
        int t = b - 2592;            // 0..11
        _Float16* wlm = wt + 6 * WSLOT;
        int kt = t / 2, nt = t % 2;
        int k0 = kt * 64, n0 = nt * 64;
        #pragma unroll 4
        for (int p = 0; p < 16; p++) {
            int k = p * 4 + (threadIdx.x >> 6), n = threadIdx.x & 63;
            float v = (n0 + n < V_) ? ldw(Wlm, (long long)(k0 + k) * V_ + n0 + n, f) : 0.f;
            tile[k][n] = (_Float16)v;
        }
        __syncthreads();
        #pragma unroll 4
        for (int p = 0; p < 16; p++) {
            int n = p * 4 + (threadIdx.x >> 6), k = threadIdx.x & 63;
            wlm[(size_t)(n0 + n) * E_ + k0 + k] = tile[k][n];
        }
    }
}

// ---------------- embedding: 2 elems/thread (residual stream xb stays bf16) ----------------
__global__ void embed_k(const int* __restrict__ idx, const void* __restrict__ tok,
                        const void* __restrict__ pos, const int* __restrict__ flag,
                        __hip_bfloat16* __restrict__ x) {
    int i = blockIdx.x * blockDim.x + threadIdx.x;
    if (i >= XN / 2) return;
    int f = *flag;
    int e2 = i * 2;
    int row = e2 / E_, e = e2 - row * E_;
    int t = row % T_;
    long long tb = (long long)idx[row] * E_ + e;
    long long pb = (long long)t * E_ + e;
    float r0 = ldw(tok, tb, f) + ldw(pos, pb, f);
    float r1 = ldw(tok, tb + 1, f) + ldw(pos, pb + 1, f);
    ((u32*)x)[i] = (u32)f2b(r0) | ((u32)f2b(r1) << 16);
}

// ---------------- layernorm: bf16 in, f16 out, 4 rows/block, 4B-packed I/O ----------------
__global__ __launch_bounds__(256) void ln4_k(const __hip_bfloat16* __restrict__ x,
                     const void* __restrict__ g, long long goff,
                     const void* __restrict__ b, long long boff,
                     const int* __restrict__ flag,
                     _Float16* __restrict__ out) {
    int f = *flag;
    int w = threadIdx.x >> 6, lane = threadIdx.x & 63;
    int row = blockIdx.x * 4 + w;
    const u32* xr = (const u32*)(x + (size_t)row * E_);   // bf16 pairs
    float v[6];
    float s = 0.f, ss = 0.f;
    #pragma unroll
    for (int i = 0; i < 3; i++) {
        u32 u = xr[i * 64 + lane];
        float a = blo(u), c = bhi(u);
        v[2 * i] = a; v[2 * i + 1] = c;
        s += a + c; ss += a * a + c * c;
    }
    #pragma unroll
    for (int off = 32; off; off >>= 1) {
        s  += __shfl_down(s,  off, 64);
        ss += __shfl_down(ss, off, 64);
    }
    s = __shfl(s, 0, 64); ss = __shfl(ss, 0, 64);
    float mu = s * (1.f / E_);
    float var = ss * (1.f / E_) - mu * mu;
    float rs = rsqrtf(var + 1e-5f);
    u32* orow = (u32*)(out + (size_t)row * E_);
    #pragma unroll
    for (int i = 0; i < 3; i++) {
        int e = (i * 64 + lane) * 2;
        float r0 = (v[2 * i]     - mu) * rs * ldw(g, goff + e,     f) + ldw(b, boff + e,     f);
        float r1 = (v[2 * i + 1] - mu) * rs * ldw(g, goff + e + 1, f) + ldw(b, boff + e + 1, f);
        orow[i * 64 + lane] = pack_h2(r0, r1);
    }
}

// ---------------- XCD-aware bijective block swizzle (nwg % 8 == 0) ----------------
__device__ __forceinline__ void xcd_swz(int nx, int& bx, int& by) {
    int ld = blockIdx.y * gridDim.x + blockIdx.x;
    int nwg = gridDim.x * gridDim.y;
    int cpx = nwg >> 3;
    int t = (ld & 7) * cpx + (ld >> 3);
    bx = t % nx;
    by = t / nx;
}

// ---------------- async stage: 128 rows x 64 k (f16) -> 16KB LDS buffer ----------------
// global_load_lds, 16B/lane. LDS dest linear; SOURCE pre-inverse-swizzled so that
// LDS physical slot p of row r holds logical slot p^(r&7) (rule-21 both-sides pattern).
__device__ __forceinline__ void stage_lds(const u16* __restrict__ gsrc, int ldK,
                                          u32* lbuf, int wi, int lane) {
    #pragma unroll
    for (int p = 0; p < 4; p++) {
        int i = (wi << 2) + p;
        int S = (i << 6) + lane;
        int r = S >> 3, cs = S & 7;
        const u16* gp = gsrc + (size_t)r * ldK + ((cs ^ (r & 7)) << 3);
        __builtin_amdgcn_global_load_lds(
            (const __attribute__((address_space(1))) u32*)gp,
            (__attribute__((address_space(3))) u32*)(lbuf + (i << 8)),
            16, 0, 0);
    }
}

// ---------------- MFMA GEMM body: 128x128 tile, BK=64, gload_lds double-buffer ----------
// CMODE: 0 = f16 out (+relu opt), 1 = bf16 residual out, 2 = f32 out guarded (lm head)
template<int CMODE>
__device__ __forceinline__ void gemm_body(
        const _Float16* __restrict__ A,
        const _Float16* __restrict__ Wt,     // [N][K] f16 pre-transposed
        const void* __restrict__ bias, long long boff, int has_bias, int f,
        void* __restrict__ Cv, int N, int K, int relu,
        int bx, int by, u32* Af, u32* Wf) {
    const int tid = threadIdx.x;
    const int lane = tid & 63;
    const int wi = tid >> 6;
    const int wr = wi >> 1, wc = wi & 1;
    const int row0 = by << 7, col0 = bx << 7;
    const int l15 = lane & 15, l4 = lane >> 4;

    f32x4 acc[4][4];
    #pragma unroll
    for (int m = 0; m < 4; m++)
        #pragma unroll
        for (int n = 0; n < 4; n++)
            acc[m][n] = f32x4{0.f, 0.f, 0.f, 0.f};

    const u16* Ab = (const u16*)A + (size_t)row0 * K;
    const u16* Wb = (const u16*)Wt + (size_t)col0 * K;

    const int ntile = K >> 6;
    stage_lds(Ab, K, Af, wi, lane);
    stage_lds(Wb, K, Wf, wi, lane);
    asm volatile("s_waitcnt vmcnt(0)" ::: "memory");
    __syncthreads();

    for (int t = 0; t < ntile; t++) {
        int buf = t & 1;
        if (t + 1 < ntile) {
            stage_lds(Ab + ((t + 1) << 6), K, Af + ((buf ^ 1) << 12), wi, lane);
            stage_lds(Wb + ((t + 1) << 6), K, Wf + ((buf ^ 1) << 12), wi, lane);
        }
        __builtin_amdgcn_s_setprio(1);
        #pragma unroll
        for (int kh = 0; kh < 2; kh++) {
            f16x8 a4[4], w4[4];
            int s = (kh << 2) + l4;
            #pragma unroll
            for (int m = 0; m < 4; m++) {
                int r = (wr << 6) + (m << 4) + l15;
                a4[m] = *(const f16x8*)&Af[(buf << 12) + r * 32 + ((s ^ (r & 7)) << 2)];
            }
            #pragma unroll
            for (int n = 0; n < 4; n++) {
                int c = (wc << 6) + (n << 4) + l15;
                w4[n] = *(const f16x8*)&Wf[(buf << 12) + c * 32 + ((s ^ (c & 7)) << 2)];
            }
            #pragma unroll
            for (int m = 0; m < 4; m++)
                #pragma unroll
                for (int n = 0; n < 4; n++)
                    acc[m][n] = __builtin_amdgcn_mfma_f32_16x16x32_f16(a4[m], w4[n], acc[m][n], 0, 0, 0);
        }
        __builtin_amdgcn_s_setprio(0);
        asm volatile("s_waitcnt vmcnt(0)" ::: "memory");
        __syncthreads();
    }

    // ---- epilogue ----
    float bv[4];
    #pragma unroll
    for (int n = 0; n < 4; n++) {
        int col = col0 + (wc << 6) + (n << 4) + l15;
        bv[n] = (has_bias && (CMODE != 2 || col < N)) ? ldw(bias, boff + col, f) : 0.f;
    }
    #pragma unroll
    for (int m = 0; m < 4; m++) {
        #pragma unroll
        for (int i = 0; i < 4; i++) {
            int row = row0 + (wr << 6) + (m << 4) + (l4 << 2) + i;
            #pragma unroll
            for (int n = 0; n < 4; n++) {
                int col = col0 + (wc << 6) + (n << 4) + l15;
                if (CMODE == 2 && col >= N) continue;
                float r = acc[m][n][i] + bv[n];
                size_t o = (size_t)row * N + col;
                if (CMODE == 0) {
                    if (relu) r = fmaxf(r, 0.f);
                    ((_Float16*)Cv)[o] = (_Float16)r;
                } else if (CMODE == 1) {
                    __hip_bfloat16* C = (__hip_bfloat16*)Cv;
                    r += __bfloat162float(C[o]);
                    C[o] = __float2bfloat16(r);
                } else {
                    ((float*)Cv)[o] = r;
                }
            }
        }
    }
}

__global__ __launch_bounds__(256, 2) void gemm_f16o_k(
        const _Float16* __restrict__ A, const _Float16* __restrict__ Wt,
        const void* __restrict__ bias, long long boff, const int* __restrict__ flag,
        _Float16* __restrict__ C, int N, int K, int relu) {
    __shared__ __align__(16) u32 Af[8192];
    __shared__ __align__(16) u32 Wf[8192];
    int bx, by;
    xcd_swz(gridDim.x, bx, by);
    gemm_body<0>(A, Wt, bias, boff, 1, *flag, C, N, K, relu, bx, by, Af, Wf);
}

__global__ __launch_bounds__(256, 2) void gemm_res_k(
        const _Float16* __restrict__ A, const _Float16* __restrict__ Wt,
        const void* __restrict__ bias, long long boff, const int* __restrict__ flag,
        __hip_bfloat16* __restrict__ C, int N, int K) {
    __shared__ __align__(16) u32 Af[8192];
    __shared__ __align__(16) u32 Wf[8192];
    int bx, by;
    xcd_swz(gridDim.x, bx, by);
    gemm_body<1>(A, Wt, bias, boff, 1, *flag, C, N, K, 0, bx, by, Af, Wf);
}

// fused Q/K/V: grid (9, 128)
__global__ __launch_bounds__(256, 2) void gemm_qkv_k(
        const _Float16* __restrict__ A, const _Float16* __restrict__ wls,
        _Float16* __restrict__ qb, _Float16* __restrict__ kb, _Float16* __restrict__ vb) {
    __shared__ __align__(16) u32 Af[8192];
    __shared__ __align__(16) u32 Wf[8192];
    int sx, by;
    xcd_swz(9, sx, by);
    int which = sx / 3, bx = sx % 3;
    const _Float16* Wt = wls + (size_t)which * EE;
    _Float16* C = (which == 0) ? qb : (which == 1) ? kb : vb;
    gemm_body<0>(A, Wt, nullptr, 0, 0, 0, C, E_, E_, 0, bx, by, Af, Wf);
}

// lm head: N=65 in one guarded 128-col tile (wlm padded to 128 rows), f32 out
__global__ __launch_bounds__(256, 2) void gemm_lmh_k(
        const _Float16* __restrict__ A, const _Float16* __restrict__ Wt,
        const void* __restrict__ bias, const int* __restrict__ flag,
        float* __restrict__ logits) {
    __shared__ __align__(16) u32 Af[8192];
    __shared__ __align__(16) u32 Wf[8192];
    int bx, by;
    xcd_swz(1, bx, by);
    gemm_body<2>(A, Wt, bias, 0, 1, *flag, logits, V_, E_, 0, bx, by, Af, Wf);
}

// ---------------- MFMA attention, f16 I/O ----------------
template<int NK>
__device__ __forceinline__ void attn_body(
        const u16* __restrict__ qbase, const u16* __restrict__ kbase,
        const u16* __restrict__ vbase, u16* __restrict__ abase,
        int q0, u32* Kls, u32* Pls) {
    constexpr int NKF = NK / 16;
    constexpr int NKS = NK / 32;
    const int tid = threadIdx.x;
    const int lane = tid & 63;
    const int w = tid >> 6;
    const int l15 = lane & 15, l4 = lane >> 4;

    {   // stage K [NK][64] f16 (pure copy), slot ^= key&7
        int r8 = tid >> 3, slot = tid & 7;
        #pragma unroll
        for (int p = 0; p < NK / 32; p++) {
            int key = r8 + p * 32;
            uint4 a8 = *(const uint4*)(kbase + (size_t)key * E_ + slot * 8);
            *(uint4*)&Kls[key * 32 + ((slot ^ (key & 7)) << 2)] = a8;
        }
    }
    __syncthreads();

    const int qrow = w * 16 + l15;
    const int qi = q0 + qrow;
    f32x4 acc[NKF];
    #pragma unroll
    for (int kf = 0; kf < NKF; kf++) acc[kf] = f32x4{0.f, 0.f, 0.f, 0.f};

    // ---- phase 1: S^T = K @ Q^T ----
    #pragma unroll
    for (int kh = 0; kh < 2; kh++) {
        f16x8 qh = *(const f16x8*)(qbase + (size_t)qi * E_ + ((kh << 2) + l4) * 8);
        #pragma unroll
        for (int kf = 0; kf < NKF; kf++) {
            int krow = kf * 16 + l15;
            f16x8 kf8 = *(const f16x8*)&Kls[krow * 32 + ((((kh << 2) + l4) ^ (krow & 7)) << 2)];
            acc[kf] = __builtin_amdgcn_mfma_f32_16x16x32_f16(kf8, qh, acc[kf], 0, 0, 0);
        }
    }

    float m = -1e30f;
    #pragma unroll
    for (int kf = 0; kf < NKF; kf++)
        #pragma unroll
        for (int r = 0; r < 4; r++) {
            int key = kf * 16 + l4 * 4 + r;
            float s = acc[kf][r] * 0.125f;
            if (key > qi) s = -1e30f;
            acc[kf][r] = s;
            m = fmaxf(m, s);
        }
    m = fmaxf(m, __shfl_xor(m, 16, 64));
    m = fmaxf(m, __shfl_xor(m, 32, 64));
    float sum = 0.f;
    #pragma unroll
    for (int kf = 0; kf < NKF; kf++)
        #pragma unroll
        for (int r = 0; r < 4; r++) {
            float p = __expf(acc[kf][r] - m);
            acc[kf][r] = p;
            sum += p;
        }
    sum += __shfl_xor(sum, 16, 64);
    sum += __shfl_xor(sum, 32, 64);
    float inv = 1.f / sum;

    #pragma unroll
    for (int kf = 0; kf < NKF; kf++) {
        uint2 pw;
        pw.x = pack_h2(acc[kf][0] * inv, acc[kf][1] * inv);
        pw.y = pack_h2(acc[kf][2] * inv, acc[kf][3] * inv);
        int j = kf * 2 + (l4 >> 1);
        *(uint2*)&Pls[qrow * 128 + ((j ^ (qrow & 15)) << 2) + ((l4 & 1) << 1)] = pw;
    }
    __syncthreads();

    // restage V^T into Kls (bit-ops only, f16 input)
    for (int kp = lane; kp < NK / 2; kp += 64) {
        #pragma unroll
        for (int dq = 0; dq < 2; dq++) {
            int db = w + dq * 4;
            uint4 v0 = *(const uint4*)(vbase + (size_t)(2 * kp) * E_ + db * 8);
            uint4 v1 = *(const uint4*)(vbase + (size_t)(2 * kp + 1) * E_ + db * 8);
            u32 uu[8];
            uu[0] = pk_lo(v0.x, v1.x); uu[1] = pk_hi(v0.x, v1.x);
            uu[2] = pk_lo(v0.y, v1.y); uu[3] = pk_hi(v0.y, v1.y);
            uu[4] = pk_lo(v0.z, v1.z); uu[5] = pk_hi(v0.z, v1.z);
            uu[6] = pk_lo(v0.w, v1.w); uu[7] = pk_hi(v0.w, v1.w);
            #pragma unroll
            for (int i = 0; i < 8; i++) {
                int d = db * 8 + i;
                Kls[d * 128 + (((kp >> 2) ^ (d & 15)) << 2) + (kp & 3)] = uu[i];
            }
        }
    }
    __syncthreads();

    f32x4 o2[4];
    #pragma unroll
    for (int df = 0; df < 4; df++) o2[df] = f32x4{0.f, 0.f, 0.f, 0.f};
    #pragma unroll
    for (int ks = 0; ks < NKS; ks++) {
        f16x8 pa = *(const f16x8*)&Pls[qrow * 128 + (((ks * 4 + l4) ^ (qrow & 15)) << 2)];
        #pragma unroll
        for (int df = 0; df < 4; df++) {
            int d = df * 16 + l15;
            f16x8 vb8 = *(const f16x8*)&Kls[d * 128 + (((ks * 4 + l4) ^ (d & 15)) << 2)];
            o2[df] = __builtin_amdgcn_mfma_f32_16x16x32_f16(pa, vb8, o2[df], 0, 0, 0);
        }
    }
    #pragma unroll
    for (int df = 0; df < 4; df++)
        #pragma unroll
        for (int r = 0; r < 4; r++) {
            int qg = q0 + w * 16 + l4 * 4 + r;
            abase[(size_t)qg * E_ + df * 16 + l15] = f2hu(o2[df][r]);
        }
}

__global__ __launch_bounds__(256) void attn_mfma_k(
        const _Float16* __restrict__ q, const _Float16* __restrict__ k,
        const _Float16* __restrict__ v, _Float16* __restrict__ att) {
    __shared__ __align__(16) u32 Kls[256 * 32];   // 32 KB
    __shared__ __align__(16) u32 Pls[64 * 128];   // 32 KB
    int chunk = blockIdx.x & 3;
    int bh = blockIdx.x >> 2;
    int b = bh / H_, h = bh % H_;
    const u16* qbase = (const u16*)q + ((size_t)b * T_) * E_ + h * D_;
    const u16* kbase = (const u16*)k + ((size_t)b * T_) * E_ + h * D_;
    const u16* vbase = (const u16*)v + ((size_t)b * T_) * E_ + h * D_;
    u16* abase = (u16*)att + ((size_t)b * T_) * E_ + h * D_;
    int q0 = chunk * 64;
    switch (chunk) {
        case 0: attn_body< 64>(qbase, kbase, vbase, abase, q0, Kls, Pls); break;
        case 1: attn_body<128>(qbase, kbase, vbase, abase, q0, Kls, Pls); break;
        case 2: attn_body<192>(qbase, kbase, vbase, abase, q0, Kls, Pls); break;
        default: attn_body<256>(qbase, kbase, vbase, abase, q0, Kls, Pls); break;
    }
}

// ---------------- loss tail ----------------
__global__ void outcvt_k(const float* __restrict__ logits, const int* __restrict__ flag,
                         void* __restrict__ out) {
    int i = blockIdx.x * blockDim.x + threadIdx.x;
    if (i >= BT * V_) return;
    if (*flag) ((float*)out)[i] = logits[i];
    else ((__hip_bfloat16*)out)[i] = __float2bfloat16(logits[i]);
}

__global__ __launch_bounds__(256) void rowloss2_k(
        const float* __restrict__ logits, const int* __restrict__ tgt,
        float* __restrict__ accum) {
    __shared__ float part[4];
    int w = threadIdx.x >> 6, lane = threadIdx.x & 63;
    float local = 0.f;
    for (int i = 0; i < 16; i++) {
        int row = blockIdx.x * 64 + w * 16 + i;
        const float* lr = logits + (size_t)row * V_;
        float v0 = lr[lane];
        float v64 = (lane == 0) ? lr[64] : -1e30f;
        float m = fmaxf(v0, v64);
        #pragma unroll
        for (int off = 32; off; off >>= 1) m = fmaxf(m, __shfl_xor(m, off, 64));
        float se = __expf(v0 - m) + ((lane == 0) ? __expf(v64 - m) : 0.f);
        #pragma unroll
        for (int off = 32; off; off >>= 1) se += __shfl_xor(se, off, 64);
        if (lane == 0) local += lr[tgt[row]] - m - __logf(se);
    }
    if (lane == 0) part[w] = local;
    __syncthreads();
    if (threadIdx.x == 0)
        atomicAdd(accum, -(part[0] + part[1] + part[2] + part[3]));
}

__global__ void final_k(const float* __restrict__ accum, const int* __restrict__ flag,
                        void* __restrict__ out) {
    if (threadIdx.x == 0) {
        float v = *accum * (1.f / BT);
        if (*flag) ((float*)out)[(size_t)BT * V_] = v;
        else ((__hip_bfloat16*)out)[(size_t)BT * V_] = __float2bfloat16(v);
    }
}

extern "C" void kernel_launch(void* const* d_in, const int* in_sizes, int n_in,
                              void* d_out, int out_size, void* d_ws, size_t ws_size,
                              hipStream_t stream) {
    const int* idx     = (const int*)d_in[0];
    const int* targets = (const int*)d_in[1];
    const void* tok  = d_in[2];
    const void* pos  = d_in[3];
    const void* Wq   = d_in[4];
    const void* Wk   = d_in[5];
    const void* Wv   = d_in[6];
    const void* Wo   = d_in[7];
    const void* bo   = d_in[8];
    const void* W1   = d_in[9];
    const void* b1   = d_in[10];
    const void* W2   = d_in[11];
    const void* b2   = d_in[12];
    const void* ln1g = d_in[13];
    const void* ln1b = d_in[14];
    const void* ln2g = d_in[15];
    const void* ln2b = d_in[16];
    const void* lnfg = d_in[17];
    const void* lnfb = d_in[18];
    const void* Wlm  = d_in[19];
    const void* blm  = d_in[20];

    // ---- workspace layout (~89 MiB total, same footprint round 4 allocated fine) ----
    // p: xb 2XN | hb 2XN | qb 2XN | kb 2XN | vb 2XN | wt 6*WSLOT f16 (20.3MiB) | wlm 96KiB
    // ffnb overlay spans [qb, qb+4XN) = qb+kb exactly (half-FFN: 8192 x F f16) -> never
    // reaches vb or wt.
    char* wsb = (char*)d_ws;
    int*   flag    = (int*)wsb;
    float* lossacc = (float*)(wsb + 8);
    float* logits  = (float*)(wsb + 256);
    char* p = wsb + 256 + sizeof(float) * (size_t)BT * V_;
    __hip_bfloat16* xb = (__hip_bfloat16*)p;                 // bf16 residual stream
    _Float16* hb = (_Float16*)(p + 2 * (size_t)XN);
    _Float16* qb = (_Float16*)(p + 4 * (size_t)XN);
    _Float16* kb = (_Float16*)(p + 6 * (size_t)XN);
    _Float16* vb = (_Float16*)(p + 8 * (size_t)XN);
    _Float16* wt = (_Float16*)(p + 10 * (size_t)XN);         // 6*WSLOT f16
    _Float16* wlm = wt + 6 * WSLOT;                          // 128*384 f16
    _Float16* ab = hb;       // attn out (hb dead after qkv gemm)
    _Float16* ffnb = qb;     // half-FFN hidden: 8192*1536 f16 = 4XN bytes (qb+kb)

    dim3 grdEm(3, 128);      // nwg=384
    dim3 grdQKV(9, 128);     // nwg=1152
    dim3 grdW1h(12, 64);     // nwg=768 (half rows)
    dim3 grdW2h(3, 64);      // nwg=192 (half rows)
    dim3 grdLM(1, 128);      // nwg=128
    constexpr int HROWS = BT / 2;   // 8192

    init_k<<<1, 64, 0, stream>>>(flag, lossacc);
    detect_k<<<(V_ * E_ + 255) / 256, 256, 0, stream>>>(tok, V_ * E_, flag);
    wtrans_all_k<<<2604, 256, 0, stream>>>(Wq, Wk, Wv, Wo, W1, W2, Wlm, flag, wt);
    embed_k<<<(XN / 2 + 255) / 256, 256, 0, stream>>>(idx, tok, pos, flag, xb);

    for (int l = 0; l < L_; l++) {
        const _Float16* wls = wt + (size_t)l * WSLOT;
        ln4_k<<<BT / 4, 256, 0, stream>>>(xb, ln1g, (long long)l * E_, ln1b, (long long)l * E_, flag, hb);
        gemm_qkv_k<<<grdQKV, 256, 0, stream>>>(hb, wls, qb, kb, vb);
        attn_mfma_k<<<B_ * H_ * 4, 256, 0, stream>>>(qb, kb, vb, ab);
        gemm_res_k<<<grdEm, 256, 0, stream>>>(ab, wls + 3 * EE, bo, (long long)l * E_, flag, xb, E_, E_);
        ln4_k<<<BT / 4, 256, 0, stream>>>(xb, ln2g, (long long)l * E_, ln2b, (long long)l * E_, flag, hb);
        for (int h = 0; h < 2; h++) {
            gemm_f16o_k<<<grdW1h, 256, 0, stream>>>(hb + (size_t)h * HROWS * E_, wls + 4 * EE,
                                                    b1, (long long)l * F_, flag, ffnb, F_, E_, 1);
            gemm_res_k<<<grdW2h, 256, 0, stream>>>(ffnb, wls + 4 * EE + EF,
                                                   b2, (long long)l * E_, flag,
                                                   xb + (size_t)h * HROWS * E_, E_, F_);
        }
    }

    ln4_k<<<BT / 4, 256, 0, stream>>>(xb, lnfg, 0, lnfb, 0, flag, hb);
    gemm_lmh_k<<<grdLM, 256, 0, stream>>>(hb, wlm, blm, flag, logits);

    outcvt_k<<<(BT * V_ + 255) / 256, 256, 0, stream>>>(logits, flag, d_out);
    rowloss2_k<<<BT / 64, 256, 0, stream>>>(logits, targets, lossacc);
    final_k<<<1, 64, 0, stream>>>(lossacc, flag, d_out);
}

// Round 10
// 1095.006 us; speedup vs baseline: 5.7778x; 1.2045x over previous
//
#include <hip/hip_runtime.h>
#include <hip/hip_bf16.h>

typedef unsigned short u16;
typedef unsigned int u32;
typedef _Float16 h16x2 __attribute__((ext_vector_type(2)));
typedef _Float16 f16x8 __attribute__((ext_vector_type(8)));
typedef float f32x4 __attribute__((ext_vector_type(4)));

constexpr int B_ = 64, T_ = 256, V_ = 65, E_ = 384, H_ = 6, L_ = 6, D_ = 64, F_ = 1536;
constexpr int BT = B_ * T_;
constexpr int XN = BT * E_;
constexpr long long EE = (long long)E_ * E_;          // 147456
constexpr long long EF = (long long)E_ * F_;          // 589824
constexpr long long WSLOT = 4 * EE + 2 * EF;          // 1769472 f16 per layer

__device__ __forceinline__ float ldw(const void* p, long long i, int f32) {
    return f32 ? ((const float*)p)[i]
               : __bfloat162float(((const __hip_bfloat16*)p)[i]);
}
__device__ __forceinline__ u16 f2hu(float f) { union { _Float16 h; u16 u; } x; x.h = (_Float16)f; return x.u; }
__device__ __forceinline__ u16 f2b(float f) {
    __hip_bfloat16 h = __float2bfloat16(f);
    union { __hip_bfloat16 h; u16 u; } x; x.h = h; return x.u;
}
__device__ __forceinline__ float blo(u32 u) { union { u32 i; float f; } x; x.i = u << 16; return x.f; }
__device__ __forceinline__ float bhi(u32 u) { union { u32 i; float f; } x; x.i = u & 0xffff0000u; return x.f; }
__device__ __forceinline__ u32 pack_h2(float a, float b) {
    union { h16x2 h; u32 u; } x;
    x.h[0] = (_Float16)a; x.h[1] = (_Float16)b;
    return x.u;
}
// combine low/high f16 halves of two u32s (k-pair build from two V rows)
__device__ __forceinline__ u32 pk_lo(u32 a, u32 b) { return (a & 0xffffu) | (b << 16); }
__device__ __forceinline__ u32 pk_hi(u32 a, u32 b) { return (a >> 16) | (b & 0xffff0000u); }

__global__ void init_k(int* flag, float* lossacc) {
    if (threadIdx.x == 0) { *flag = 0; *lossacc = 0.f; }
}

__global__ void detect_k(const void* tok, int n, int* flag) {
    int i = blockIdx.x * blockDim.x + threadIdx.x;
    if (i < n) {
        float v = __bfloat162float(((const __hip_bfloat16*)tok)[i]);
        if (!(fabsf(v) < 1e4f)) *flag = 1;
    }
}

// ---------------- ALL weight transposes in ONE dispatch (hoisted out of layer loop) ----
// per-layer slot: [Wq|Wk|Wv|Wo](4*EE) | W1t (EF, [F][E]) | W2t (EF, [E][F])
// blocks 0..2591: layer tiles (l = b/432). blocks 2592..2603: lm head (padded 128 rows).
__global__ __launch_bounds__(256) void wtrans_all_k(
        const void* __restrict__ Wq, const void* __restrict__ Wk,
        const void* __restrict__ Wv, const void* __restrict__ Wo,
        const void* __restrict__ W1, const void* __restrict__ W2,
        const void* __restrict__ Wlm, const int* __restrict__ flag,
        _Float16* __restrict__ wt) {
    int f = *flag;
    int b = blockIdx.x;
    __shared__ _Float16 tile[64][65];
    if (b < 2592) {
        int l = b / 432, r = b % 432;
        const void* src; long long soff; _Float16* dst;
        int K, N, kt, nt;
        _Float16* wls = wt + (size_t)l * WSLOT;
        if (r < 144) {
            int m = r / 36, t = r % 36;
            src = (m == 0) ? Wq : (m == 1) ? Wk : (m == 2) ? Wv : Wo;
            soff = (long long)l * EE;
            dst = wls + (size_t)m * EE;
            K = E_; N = E_; kt = t / 6; nt = t % 6;
        } else if (r < 288) {
            int t = r - 144;
            src = W1; soff = (long long)l * EF;
            dst = wls + 4 * EE;
            K = E_; N = F_; kt = t / 24; nt = t % 24;
        } else {
            int t = r - 288;
            src = W2; soff = (long long)l * EF;
            dst = wls + 4 * EE + EF;
            K = F_; N = E_; kt = t / 6; nt = t % 6;
        }
        int k0 = kt * 64, n0 = nt * 64;
        #pragma unroll 4
        for (int p = 0; p < 16; p++) {
            int k = p * 4 + (threadIdx.x >> 6), n = threadIdx.x & 63;
            tile[k][n] = (_Float16)ldw(src, soff + (long long)(k0 + k) * N + n0 + n, f);
        }
        __syncthreads();
        #pragma unroll 4
        for (int p = 0; p < 16; p++) {
            int n = p * 4 + (threadIdx.x >> 6), k = threadIdx.x & 63;
            dst[(size_t)(n0 + n) * K + k0 + k] = tile[k][n];
        }
    } else {
        int t = b - 2592;            // 0..11
        _Float16* wlm = wt + 6 * WSLOT;
        int kt = t / 2, nt = t % 2;
        int k0 = kt * 64, n0 = nt * 64;
        #pragma unroll 4
        for (int p = 0; p < 16; p++) {
            int k = p * 4 + (threadIdx.x >> 6), n = threadIdx.x & 63;
            float v = (n0 + n < V_) ? ldw(Wlm, (long long)(k0 + k) * V_ + n0 + n, f) : 0.f;
            tile[k][n] = (_Float16)v;
        }
        __syncthreads();
        #pragma unroll 4
        for (int p = 0; p < 16; p++) {
            int n = p * 4 + (threadIdx.x >> 6), k = threadIdx.x & 63;
            wlm[(size_t)(n0 + n) * E_ + k0 + k] = tile[k][n];
        }
    }
}

// ---------------- embedding: 2 elems/thread (residual stream xb stays bf16) ----------------
__global__ void embed_k(const int* __restrict__ idx, const void* __restrict__ tok,
                        const void* __restrict__ pos, const int* __restrict__ flag,
                        __hip_bfloat16* __restrict__ x) {
    int i = blockIdx.x * blockDim.x + threadIdx.x;
    if (i >= XN / 2) return;
    int f = *flag;
    int e2 = i * 2;
    int row = e2 / E_, e = e2 - row * E_;
    int t = row % T_;
    long long tb = (long long)idx[row] * E_ + e;
    long long pb = (long long)t * E_ + e;
    float r0 = ldw(tok, tb, f) + ldw(pos, pb, f);
    float r1 = ldw(tok, tb + 1, f) + ldw(pos, pb + 1, f);
    ((u32*)x)[i] = (u32)f2b(r0) | ((u32)f2b(r1) << 16);
}

// ---------------- layernorm: bf16 in, f16 out, 4 rows/block, 4B-packed I/O ----------------
__global__ __launch_bounds__(256) void ln4_k(const __hip_bfloat16* __restrict__ x,
                     const void* __restrict__ g, long long goff,
                     const void* __restrict__ b, long long boff,
                     const int* __restrict__ flag,
                     _Float16* __restrict__ out) {
    int f = *flag;
    int w = threadIdx.x >> 6, lane = threadIdx.x & 63;
    int row = blockIdx.x * 4 + w;
    const u32* xr = (const u32*)(x + (size_t)row * E_);   // bf16 pairs
    float v[6];
    float s = 0.f, ss = 0.f;
    #pragma unroll
    for (int i = 0; i < 3; i++) {
        u32 u = xr[i * 64 + lane];
        float a = blo(u), c = bhi(u);
        v[2 * i] = a; v[2 * i + 1] = c;
        s += a + c; ss += a * a + c * c;
    }
    #pragma unroll
    for (int off = 32; off; off >>= 1) {
        s  += __shfl_down(s,  off, 64);
        ss += __shfl_down(ss, off, 64);
    }
    s = __shfl(s, 0, 64); ss = __shfl(ss, 0, 64);
    float mu = s * (1.f / E_);
    float var = ss * (1.f / E_) - mu * mu;
    float rs = rsqrtf(var + 1e-5f);
    u32* orow = (u32*)(out + (size_t)row * E_);
    #pragma unroll
    for (int i = 0; i < 3; i++) {
        int e = (i * 64 + lane) * 2;
        float r0 = (v[2 * i]     - mu) * rs * ldw(g, goff + e,     f) + ldw(b, boff + e,     f);
        float r1 = (v[2 * i + 1] - mu) * rs * ldw(g, goff + e + 1, f) + ldw(b, boff + e + 1, f);
        orow[i * 64 + lane] = pack_h2(r0, r1);
    }
}

// ---------------- XCD-aware bijective block swizzle (nwg % 8 == 0) ----------------
__device__ __forceinline__ void xcd_swz(int nx, int& bx, int& by) {
    int ld = blockIdx.y * gridDim.x + blockIdx.x;
    int nwg = gridDim.x * gridDim.y;
    int cpx = nwg >> 3;
    int t = (ld & 7) * cpx + (ld >> 3);
    bx = t % nx;
    by = t / nx;
}

// ---------------- async stage: 128 rows x 64 k (f16) -> 16KB LDS buffer ----------------
// global_load_lds, 16B/lane. LDS dest linear; SOURCE pre-inverse-swizzled so that
// LDS physical slot p of row r holds logical slot p^(r&7) (rule-21 both-sides pattern).
__device__ __forceinline__ void stage_lds(const u16* __restrict__ gsrc, int ldK,
                                          u32* lbuf, int wi, int lane) {
    #pragma unroll
    for (int p = 0; p < 4; p++) {
        int i = (wi << 2) + p;
        int S = (i << 6) + lane;
        int r = S >> 3, cs = S & 7;
        const u16* gp = gsrc + (size_t)r * ldK + ((cs ^ (r & 7)) << 3);
        __builtin_amdgcn_global_load_lds(
            (const __attribute__((address_space(1))) u32*)gp,
            (__attribute__((address_space(3))) u32*)(lbuf + (i << 8)),
            16, 0, 0);
    }
}

// ---------------- MFMA GEMM body: 128x128 tile, BK=64, gload_lds double-buffer ----------
// CMODE: 0 = f16 out (+relu opt), 1 = bf16 residual out, 2 = f32 out guarded (lm head)
template<int CMODE>
__device__ __forceinline__ void gemm_body(
        const _Float16* __restrict__ A,
        const _Float16* __restrict__ Wt,     // [N][K] f16 pre-transposed
        const void* __restrict__ bias, long long boff, int has_bias, int f,
        void* __restrict__ Cv, int N, int K, int relu,
        int bx, int by, u32* Af, u32* Wf) {
    const int tid = threadIdx.x;
    const int lane = tid & 63;
    const int wi = tid >> 6;
    const int wr = wi >> 1, wc = wi & 1;
    const int row0 = by << 7, col0 = bx << 7;
    const int l15 = lane & 15, l4 = lane >> 4;

    f32x4 acc[4][4];
    #pragma unroll
    for (int m = 0; m < 4; m++)
        #pragma unroll
        for (int n = 0; n < 4; n++)
            acc[m][n] = f32x4{0.f, 0.f, 0.f, 0.f};

    const u16* Ab = (const u16*)A + (size_t)row0 * K;
    const u16* Wb = (const u16*)Wt + (size_t)col0 * K;

    const int ntile = K >> 6;
    stage_lds(Ab, K, Af, wi, lane);
    stage_lds(Wb, K, Wf, wi, lane);
    asm volatile("s_waitcnt vmcnt(0)" ::: "memory");
    __syncthreads();

    for (int t = 0; t < ntile; t++) {
        int buf = t & 1;
        if (t + 1 < ntile) {
            stage_lds(Ab + ((t + 1) << 6), K, Af + ((buf ^ 1) << 12), wi, lane);
            stage_lds(Wb + ((t + 1) << 6), K, Wf + ((buf ^ 1) << 12), wi, lane);
        }
        __builtin_amdgcn_s_setprio(1);
        #pragma unroll
        for (int kh = 0; kh < 2; kh++) {
            f16x8 a4[4], w4[4];
            int s = (kh << 2) + l4;
            #pragma unroll
            for (int m = 0; m < 4; m++) {
                int r = (wr << 6) + (m << 4) + l15;
                a4[m] = *(const f16x8*)&Af[(buf << 12) + r * 32 + ((s ^ (r & 7)) << 2)];
            }
            #pragma unroll
            for (int n = 0; n < 4; n++) {
                int c = (wc << 6) + (n << 4) + l15;
                w4[n] = *(const f16x8*)&Wf[(buf << 12) + c * 32 + ((s ^ (c & 7)) << 2)];
            }
            #pragma unroll
            for (int m = 0; m < 4; m++)
                #pragma unroll
                for (int n = 0; n < 4; n++)
                    acc[m][n] = __builtin_amdgcn_mfma_f32_16x16x32_f16(a4[m], w4[n], acc[m][n], 0, 0, 0);
        }
        __builtin_amdgcn_s_setprio(0);
        asm volatile("s_waitcnt vmcnt(0)" ::: "memory");
        __syncthreads();
    }

    // ---- epilogue ----
    float bv[4];
    #pragma unroll
    for (int n = 0; n < 4; n++) {
        int col = col0 + (wc << 6) + (n << 4) + l15;
        bv[n] = (has_bias && (CMODE != 2 || col < N)) ? ldw(bias, boff + col, f) : 0.f;
    }
    #pragma unroll
    for (int m = 0; m < 4; m++) {
        #pragma unroll
        for (int i = 0; i < 4; i++) {
            int row = row0 + (wr << 6) + (m << 4) + (l4 << 2) + i;
            #pragma unroll
            for (int n = 0; n < 4; n++) {
                int col = col0 + (wc << 6) + (n << 4) + l15;
                if (CMODE == 2 && col >= N) continue;
                float r = acc[m][n][i] + bv[n];
                size_t o = (size_t)row * N + col;
                if (CMODE == 0) {
                    if (relu) r = fmaxf(r, 0.f);
                    ((_Float16*)Cv)[o] = (_Float16)r;
                } else if (CMODE == 1) {
                    __hip_bfloat16* C = (__hip_bfloat16*)Cv;
                    r += __bfloat162float(C[o]);
                    C[o] = __float2bfloat16(r);
                } else {
                    ((float*)Cv)[o] = r;
                }
            }
        }
    }
}

__global__ __launch_bounds__(256, 2) void gemm_f16o_k(
        const _Float16* __restrict__ A, const _Float16* __restrict__ Wt,
        const void* __restrict__ bias, long long boff, const int* __restrict__ flag,
        _Float16* __restrict__ C, int N, int K, int relu) {
    __shared__ __align__(16) u32 Af[8192];
    __shared__ __align__(16) u32 Wf[8192];
    int bx, by;
    xcd_swz(gridDim.x, bx, by);
    gemm_body<0>(A, Wt, bias, boff, 1, *flag, C, N, K, relu, bx, by, Af, Wf);
}

__global__ __launch_bounds__(256, 2) void gemm_res_k(
        const _Float16* __restrict__ A, const _Float16* __restrict__ Wt,
        const void* __restrict__ bias, long long boff, const int* __restrict__ flag,
        __hip_bfloat16* __restrict__ C, int N, int K) {
    __shared__ __align__(16) u32 Af[8192];
    __shared__ __align__(16) u32 Wf[8192];
    int bx, by;
    xcd_swz(gridDim.x, bx, by);
    gemm_body<1>(A, Wt, bias, boff, 1, *flag, C, N, K, 0, bx, by, Af, Wf);
}

// fused Q/K/V: grid (9, 128)
__global__ __launch_bounds__(256, 2) void gemm_qkv_k(
        const _Float16* __restrict__ A, const _Float16* __restrict__ wls,
        _Float16* __restrict__ qb, _Float16* __restrict__ kb, _Float16* __restrict__ vb) {
    __shared__ __align__(16) u32 Af[8192];
    __shared__ __align__(16) u32 Wf[8192];
    int sx, by;
    xcd_swz(9, sx, by);
    int which = sx / 3, bx = sx % 3;
    const _Float16* Wt = wls + (size_t)which * EE;
    _Float16* C = (which == 0) ? qb : (which == 1) ? kb : vb;
    gemm_body<0>(A, Wt, nullptr, 0, 0, 0, C, E_, E_, 0, bx, by, Af, Wf);
}

// lm head: N=65 in one guarded 128-col tile (wlm padded to 128 rows), f32 out
__global__ __launch_bounds__(256, 2) void gemm_lmh_k(
        const _Float16* __restrict__ A, const _Float16* __restrict__ Wt,
        const void* __restrict__ bias, const int* __restrict__ flag,
        float* __restrict__ logits) {
    __shared__ __align__(16) u32 Af[8192];
    __shared__ __align__(16) u32 Wf[8192];
    int bx, by;
    xcd_swz(1, bx, by);
    gemm_body<2>(A, Wt, bias, 0, 1, *flag, logits, V_, E_, 0, bx, by, Af, Wf);
}

// ---------------- MFMA attention, f16 I/O ----------------
template<int NK>
__device__ __forceinline__ void attn_body(
        const u16* __restrict__ qbase, const u16* __restrict__ kbase,
        const u16* __restrict__ vbase, u16* __restrict__ abase,
        int q0, u32* Kls, u32* Pls) {
    constexpr int NKF = NK / 16;
    constexpr int NKS = NK / 32;
    const int tid = threadIdx.x;
    const int lane = tid & 63;
    const int w = tid >> 6;
    const int l15 = lane & 15, l4 = lane >> 4;

    {   // stage K [NK][64] f16 (pure copy), slot ^= key&7
        int r8 = tid >> 3, slot = tid & 7;
        #pragma unroll
        for (int p = 0; p < NK / 32; p++) {
            int key = r8 + p * 32;
            uint4 a8 = *(const uint4*)(kbase + (size_t)key * E_ + slot * 8);
            *(uint4*)&Kls[key * 32 + ((slot ^ (key & 7)) << 2)] = a8;
        }
    }
    __syncthreads();

    const int qrow = w * 16 + l15;
    const int qi = q0 + qrow;
    f32x4 acc[NKF];
    #pragma unroll
    for (int kf = 0; kf < NKF; kf++) acc[kf] = f32x4{0.f, 0.f, 0.f, 0.f};

    // ---- phase 1: S^T = K @ Q^T ----
    #pragma unroll
    for (int kh = 0; kh < 2; kh++) {
        f16x8 qh = *(const f16x8*)(qbase + (size_t)qi * E_ + ((kh << 2) + l4) * 8);
        #pragma unroll
        for (int kf = 0; kf < NKF; kf++) {
            int krow = kf * 16 + l15;
            f16x8 kf8 = *(const f16x8*)&Kls[krow * 32 + ((((kh << 2) + l4) ^ (krow & 7)) << 2)];
            acc[kf] = __builtin_amdgcn_mfma_f32_16x16x32_f16(kf8, qh, acc[kf], 0, 0, 0);
        }
    }

    float m = -1e30f;
    #pragma unroll
    for (int kf = 0; kf < NKF; kf++)
        #pragma unroll
        for (int r = 0; r < 4; r++) {
            int key = kf * 16 + l4 * 4 + r;
            float s = acc[kf][r] * 0.125f;
            if (key > qi) s = -1e30f;
            acc[kf][r] = s;
            m = fmaxf(m, s);
        }
    m = fmaxf(m, __shfl_xor(m, 16, 64));
    m = fmaxf(m, __shfl_xor(m, 32, 64));
    float sum = 0.f;
    #pragma unroll
    for (int kf = 0; kf < NKF; kf++)
        #pragma unroll
        for (int r = 0; r < 4; r++) {
            float p = __expf(acc[kf][r] - m);
            acc[kf][r] = p;
            sum += p;
        }
    sum += __shfl_xor(sum, 16, 64);
    sum += __shfl_xor(sum, 32, 64);
    float inv = 1.f / sum;

    #pragma unroll
    for (int kf = 0; kf < NKF; kf++) {
        uint2 pw;
        pw.x = pack_h2(acc[kf][0] * inv, acc[kf][1] * inv);
        pw.y = pack_h2(acc[kf][2] * inv, acc[kf][3] * inv);
        int j = kf * 2 + (l4 >> 1);
        *(uint2*)&Pls[qrow * 128 + ((j ^ (qrow & 15)) << 2) + ((l4 & 1) << 1)] = pw;
    }
    __syncthreads();

    // restage V^T into Kls (bit-ops only, f16 input)
    for (int kp = lane; kp < NK / 2; kp += 64) {
        #pragma unroll
        for (int dq = 0; dq < 2; dq++) {
            int db = w + dq * 4;
            uint4 v0 = *(const uint4*)(vbase + (size_t)(2 * kp) * E_ + db * 8);
            uint4 v1 = *(const uint4*)(vbase + (size_t)(2 * kp + 1) * E_ + db * 8);
            u32 uu[8];
            uu[0] = pk_lo(v0.x, v1.x); uu[1] = pk_hi(v0.x, v1.x);
            uu[2] = pk_lo(v0.y, v1.y); uu[3] = pk_hi(v0.y, v1.y);
            uu[4] = pk_lo(v0.z, v1.z); uu[5] = pk_hi(v0.z, v1.z);
            uu[6] = pk_lo(v0.w, v1.w); uu[7] = pk_hi(v0.w, v1.w);
            #pragma unroll
            for (int i = 0; i < 8; i++) {
                int d = db * 8 + i;
                Kls[d * 128 + (((kp >> 2) ^ (d & 15)) << 2) + (kp & 3)] = uu[i];
            }
        }
    }
    __syncthreads();

    f32x4 o2[4];
    #pragma unroll
    for (int df = 0; df < 4; df++) o2[df] = f32x4{0.f, 0.f, 0.f, 0.f};
    #pragma unroll
    for (int ks = 0; ks < NKS; ks++) {
        f16x8 pa = *(const f16x8*)&Pls[qrow * 128 + (((ks * 4 + l4) ^ (qrow & 15)) << 2)];
        #pragma unroll
        for (int df = 0; df < 4; df++) {
            int d = df * 16 + l15;
            f16x8 vb8 = *(const f16x8*)&Kls[d * 128 + (((ks * 4 + l4) ^ (d & 15)) << 2)];
            o2[df] = __builtin_amdgcn_mfma_f32_16x16x32_f16(pa, vb8, o2[df], 0, 0, 0);
        }
    }
    #pragma unroll
    for (int df = 0; df < 4; df++)
        #pragma unroll
        for (int r = 0; r < 4; r++) {
            int qg = q0 + w * 16 + l4 * 4 + r;
            abase[(size_t)qg * E_ + df * 16 + l15] = f2hu(o2[df][r]);
        }
}

__global__ __launch_bounds__(256) void attn_mfma_k(
        const _Float16* __restrict__ q, const _Float16* __restrict__ k,
        const _Float16* __restrict__ v, _Float16* __restrict__ att) {
    __shared__ __align__(16) u32 Kls[256 * 32];   // 32 KB
    __shared__ __align__(16) u32 Pls[64 * 128];   // 32 KB
    int chunk = blockIdx.x & 3;
    int bh = blockIdx.x >> 2;
    int b = bh / H_, h = bh % H_;
    const u16* qbase = (const u16*)q + ((size_t)b * T_) * E_ + h * D_;
    const u16* kbase = (const u16*)k + ((size_t)b * T_) * E_ + h * D_;
    const u16* vbase = (const u16*)v + ((size_t)b * T_) * E_ + h * D_;
    u16* abase = (u16*)att + ((size_t)b * T_) * E_ + h * D_;
    int q0 = chunk * 64;
    switch (chunk) {
        case 0: attn_body< 64>(qbase, kbase, vbase, abase, q0, Kls, Pls); break;
        case 1: attn_body<128>(qbase, kbase, vbase, abase, q0, Kls, Pls); break;
        case 2: attn_body<192>(qbase, kbase, vbase, abase, q0, Kls, Pls); break;
        default: attn_body<256>(qbase, kbase, vbase, abase, q0, Kls, Pls); break;
    }
}

// ---------------- loss tail ----------------
__global__ void outcvt_k(const float* __restrict__ logits, const int* __restrict__ flag,
                         void* __restrict__ out) {
    int i = blockIdx.x * blockDim.x + threadIdx.x;
    if (i >= BT * V_) return;
    if (*flag) ((float*)out)[i] = logits[i];
    else ((__hip_bfloat16*)out)[i] = __float2bfloat16(logits[i]);
}

__global__ __launch_bounds__(256) void rowloss2_k(
        const float* __restrict__ logits, const int* __restrict__ tgt,
        float* __restrict__ accum) {
    __shared__ float part[4];
    int w = threadIdx.x >> 6, lane = threadIdx.x & 63;
    float local = 0.f;
    for (int i = 0; i < 16; i++) {
        int row = blockIdx.x * 64 + w * 16 + i;
        const float* lr = logits + (size_t)row * V_;
        float v0 = lr[lane];
        float v64 = (lane == 0) ? lr[64] : -1e30f;
        float m = fmaxf(v0, v64);
        #pragma unroll
        for (int off = 32; off; off >>= 1) m = fmaxf(m, __shfl_xor(m, off, 64));
        float se = __expf(v0 - m) + ((lane == 0) ? __expf(v64 - m) : 0.f);
        #pragma unroll
        for (int off = 32; off; off >>= 1) se += __shfl_xor(se, off, 64);
        if (lane == 0) local += lr[tgt[row]] - m - __logf(se);
    }
    if (lane == 0) part[w] = local;
    __syncthreads();
    if (threadIdx.x == 0)
        atomicAdd(accum, -(part[0] + part[1] + part[2] + part[3]));
}

__global__ void final_k(const float* __restrict__ accum, const int* __restrict__ flag,
                        void* __restrict__ out) {
    if (threadIdx.x == 0) {
        float v = *accum * (1.f / BT);
        if (*flag) ((float*)out)[(size_t)BT * V_] = v;
        else ((__hip_bfloat16*)out)[(size_t)BT * V_] = __float2bfloat16(v);
    }
}

extern "C" void kernel_launch(void* const* d_in, const int* in_sizes, int n_in,
                              void* d_out, int out_size, void* d_ws, size_t ws_size,
                              hipStream_t stream) {
    const int* idx     = (const int*)d_in[0];
    const int* targets = (const int*)d_in[1];
    const void* tok  = d_in[2];
    const void* pos  = d_in[3];
    const void* Wq   = d_in[4];
    const void* Wk   = d_in[5];
    const void* Wv   = d_in[6];
    const void* Wo   = d_in[7];
    const void* bo   = d_in[8];
    const void* W1   = d_in[9];
    const void* b1   = d_in[10];
    const void* W2   = d_in[11];
    const void* b2   = d_in[12];
    const void* ln1g = d_in[13];
    const void* ln1b = d_in[14];
    const void* ln2g = d_in[15];
    const void* ln2b = d_in[16];
    const void* lnfg = d_in[17];
    const void* lnfb = d_in[18];
    const void* Wlm  = d_in[19];
    const void* blm  = d_in[20];

    // ---- workspace layout (~139 MiB total; ws is 268 MB per fillBuffer WRITE_SIZE) ----
    // p: xb 2XN | hb 2XN | qb 2XN | kb 2XN | vb 2XN | wt 6*WSLOT f16 | wlm 96KiB
    //    | ffnb FULL 16384 x 1536 f16 (50.3 MB, own region -> no overlays anywhere)
    char* wsb = (char*)d_ws;
    int*   flag    = (int*)wsb;
    float* lossacc = (float*)(wsb + 8);
    float* logits  = (float*)(wsb + 256);
    char* p = wsb + 256 + sizeof(float) * (size_t)BT * V_;
    __hip_bfloat16* xb = (__hip_bfloat16*)p;                 // bf16 residual stream
    _Float16* hb = (_Float16*)(p + 2 * (size_t)XN);
    _Float16* qb = (_Float16*)(p + 4 * (size_t)XN);
    _Float16* kb = (_Float16*)(p + 6 * (size_t)XN);
    _Float16* vb = (_Float16*)(p + 8 * (size_t)XN);
    _Float16* wt = (_Float16*)(p + 10 * (size_t)XN);         // 6*WSLOT f16
    _Float16* wlm = wt + 6 * WSLOT;                          // 128*384 f16
    _Float16* ffnb = wlm + (size_t)128 * E_;                 // FULL FFN hidden [BT][F]
    _Float16* ab = hb;       // attn out (hb dead after qkv gemm)

    dim3 grdEm(3, 128);      // nwg=384
    dim3 grdQKV(9, 128);     // nwg=1152
    dim3 grdW1(12, 128);     // nwg=1536 (FULL rows)
    dim3 grdW2(3, 128);      // nwg=384  (FULL rows)
    dim3 grdLM(1, 128);      // nwg=128

    init_k<<<1, 64, 0, stream>>>(flag, lossacc);
    detect_k<<<(V_ * E_ + 255) / 256, 256, 0, stream>>>(tok, V_ * E_, flag);
    wtrans_all_k<<<2604, 256, 0, stream>>>(Wq, Wk, Wv, Wo, W1, W2, Wlm, flag, wt);
    embed_k<<<(XN / 2 + 255) / 256, 256, 0, stream>>>(idx, tok, pos, flag, xb);

    for (int l = 0; l < L_; l++) {
        const _Float16* wls = wt + (size_t)l * WSLOT;
        ln4_k<<<BT / 4, 256, 0, stream>>>(xb, ln1g, (long long)l * E_, ln1b, (long long)l * E_, flag, hb);
        gemm_qkv_k<<<grdQKV, 256, 0, stream>>>(hb, wls, qb, kb, vb);
        attn_mfma_k<<<B_ * H_ * 4, 256, 0, stream>>>(qb, kb, vb, ab);
        gemm_res_k<<<grdEm, 256, 0, stream>>>(ab, wls + 3 * EE, bo, (long long)l * E_, flag, xb, E_, E_);
        ln4_k<<<BT / 4, 256, 0, stream>>>(xb, ln2g, (long long)l * E_, ln2b, (long long)l * E_, flag, hb);
        gemm_f16o_k<<<grdW1, 256, 0, stream>>>(hb, wls + 4 * EE, b1, (long long)l * F_, flag, ffnb, F_, E_, 1);
        gemm_res_k<<<grdW2, 256, 0, stream>>>(ffnb, wls + 4 * EE + EF, b2, (long long)l * E_, flag, xb, E_, F_);
    }

    ln4_k<<<BT / 4, 256, 0, stream>>>(xb, lnfg, 0, lnfb, 0, flag, hb);
    gemm_lmh_k<<<grdLM, 256, 0, stream>>>(hb, wlm, blm, flag, logits);

    outcvt_k<<<(BT * V_ + 255) / 256, 256, 0, stream>>>(logits, flag, d_out);
    rowloss2_k<<<BT / 64, 256, 0, stream>>>(logits, targets, lossacc);
    final_k<<<1, 64, 0, stream>>>(lossacc, flag, d_out);
}

// Round 11
// 1071.370 us; speedup vs baseline: 5.9053x; 1.0221x over previous
//
#include <hip/hip_runtime.h>
#include <hip/hip_bf16.h>

typedef unsigned short u16;
typedef unsigned int u32;
typedef _Float16 h16x2 __attribute__((ext_vector_type(2)));
typedef _Float16 f16x8 __attribute__((ext_vector_type(8)));
typedef float f32x4 __attribute__((ext_vector_type(4)));

constexpr int B_ = 64, T_ = 256, V_ = 65, E_ = 384, H_ = 6, L_ = 6, D_ = 64, F_ = 1536;
constexpr int BT = B_ * T_;
constexpr int XN = BT * E_;
constexpr long long EE = (long long)E_ * E_;          // 147456
constexpr long long EF = (long long)E_ * F_;          // 589824
constexpr long long WSLOT = 4 * EE + 2 * EF;          // 1769472 f16 per layer

__device__ __forceinline__ float ldw(const void* p, long long i, int f32) {
    return f32 ? ((const float*)p)[i]
               : __bfloat162float(((const __hip_bfloat16*)p)[i]);
}
__device__ __forceinline__ u16 f2hu(float f) { union { _Float16 h; u16 u; } x; x.h = (_Float16)f; return x.u; }
__device__ __forceinline__ u16 f2b(float f) {
    __hip_bfloat16 h = __float2bfloat16(f);
    union { __hip_bfloat16 h; u16 u; } x; x.h = h; return x.u;
}
__device__ __forceinline__ float blo(u32 u) { union { u32 i; float f; } x; x.i = u << 16; return x.f; }
__device__ __forceinline__ float bhi(u32 u) { union { u32 i; float f; } x; x.i = u & 0xffff0000u; return x.f; }
__device__ __forceinline__ u32 pack_h2(float a, float b) {
    union { h16x2 h; u32 u; } x;
    x.h[0] = (_Float16)a; x.h[1] = (_Float16)b;
    return x.u;
}
// combine low/high f16 halves of two u32s (k-pair build from two V rows)
__device__ __forceinline__ u32 pk_lo(u32 a, u32 b) { return (a & 0xffffu) | (b << 16); }
__device__ __forceinline__ u32 pk_hi(u32 a, u32 b) { return (a >> 16) | (b & 0xffff0000u); }

__global__ void init_k(int* flag, float* lossacc) {
    if (threadIdx.x == 0) { *flag = 0; *lossacc = 0.f; }
}

__global__ void detect_k(const void* tok, int n, int* flag) {
    int i = blockIdx.x * blockDim.x + threadIdx.x;
    if (i < n) {
        float v = __bfloat162float(((const __hip_bfloat16*)tok)[i]);
        if (!(fabsf(v) < 1e4f)) *flag = 1;
    }
}

// ---------------- ALL weight transposes in ONE dispatch (hoisted out of layer loop) ----
// per-layer slot: [Wq|Wk|Wv|Wo](4*EE) | W1t (EF, [F][E]) | W2t (EF, [E][F])
// blocks 0..2591: layer tiles (l = b/432). blocks 2592..2603: lm head (padded 128 rows).
__global__ __launch_bounds__(256) void wtrans_all_k(
        const void* __restrict__ Wq, const void* __restrict__ Wk,
        const void* __restrict__ Wv, const void* __restrict__ Wo,
        const void* __restrict__ W1, const void* __restrict__ W2,
        const void* __restrict__ Wlm, const int* __restrict__ flag,
        _Float16* __restrict__ wt) {
    int f = *flag;
    int b = blockIdx.x;
    __shared__ _Float16 tile[64][65];
    if (b < 2592) {
        int l = b / 432, r = b % 432;
        const void* src; long long soff; _Float16* dst;
        int K, N, kt, nt;
        _Float16* wls = wt + (size_t)l * WSLOT;
        if (r < 144) {
            int m = r / 36, t = r % 36;
            src = (m == 0) ? Wq : (m == 1) ? Wk : (m == 2) ? Wv : Wo;
            soff = (long long)l * EE;
            dst = wls + (size_t)m * EE;
            K = E_; N = E_; kt = t / 6; nt = t % 6;
        } else if (r < 288) {
            int t = r - 144;
            src = W1; soff = (long long)l * EF;
            dst = wls + 4 * EE;
            K = E_; N = F_; kt = t / 24; nt = t % 24;
        } else {
            int t = r - 288;
            src = W2; soff = (long long)l * EF;
            dst = wls + 4 * EE + EF;
            K = F_; N = E_; kt = t / 6; nt = t % 6;
        }
        int k0 = kt * 64, n0 = nt * 64;
        #pragma unroll 4
        for (int p = 0; p < 16; p++) {
            int k = p * 4 + (threadIdx.x >> 6), n = threadIdx.x & 63;
            tile[k][n] = (_Float16)ldw(src, soff + (long long)(k0 + k) * N + n0 + n, f);
        }
        __syncthreads();
        #pragma unroll 4
        for (int p = 0; p < 16; p++) {
            int n = p * 4 + (threadIdx.x >> 6), k = threadIdx.x & 63;
            dst[(size_t)(n0 + n) * K + k0 + k] = tile[k][n];
        }
    } else {
        int t = b - 2592;            // 0..11
        _Float16* wlm = wt + 6 * WSLOT;
        int kt = t / 2, nt = t % 2;
        int k0 = kt * 64, n0 = nt * 64;
        #pragma unroll 4
        for (int p = 0; p < 16; p++) {
            int k = p * 4 + (threadIdx.x >> 6), n = threadIdx.x & 63;
            float v = (n0 + n < V_) ? ldw(Wlm, (long long)(k0 + k) * V_ + n0 + n, f) : 0.f;
            tile[k][n] = (_Float16)v;
        }
        __syncthreads();
        #pragma unroll 4
        for (int p = 0; p < 16; p++) {
            int n = p * 4 + (threadIdx.x >> 6), k = threadIdx.x & 63;
            wlm[(size_t)(n0 + n) * E_ + k0 + k] = tile[k][n];
        }
    }
}

// ---------------- embedding: 2 elems/thread (residual stream xb stays bf16) ----------------
__global__ void embed_k(const int* __restrict__ idx, const void* __restrict__ tok,
                        const void* __restrict__ pos, const int* __restrict__ flag,
                        __hip_bfloat16* __restrict__ x) {
    int i = blockIdx.x * blockDim.x + threadIdx.x;
    if (i >= XN / 2) return;
    int f = *flag;
    int e2 = i * 2;
    int row = e2 / E_, e = e2 - row * E_;
    int t = row % T_;
    long long tb = (long long)idx[row] * E_ + e;
    long long pb = (long long)t * E_ + e;
    float r0 = ldw(tok, tb, f) + ldw(pos, pb, f);
    float r1 = ldw(tok, tb + 1, f) + ldw(pos, pb + 1, f);
    ((u32*)x)[i] = (u32)f2b(r0) | ((u32)f2b(r1) << 16);
}

// ---------------- layernorm: bf16 in, f16 out, 4 rows/block, 4B-packed I/O ----------------
__global__ __launch_bounds__(256) void ln4_k(const __hip_bfloat16* __restrict__ x,
                     const void* __restrict__ g, long long goff,
                     const void* __restrict__ b, long long boff,
                     const int* __restrict__ flag,
                     _Float16* __restrict__ out) {
    int f = *flag;
    int w = threadIdx.x >> 6, lane = threadIdx.x & 63;
    int row = blockIdx.x * 4 + w;
    const u32* xr = (const u32*)(x + (size_t)row * E_);   // bf16 pairs
    float v[6];
    float s = 0.f, ss = 0.f;
    #pragma unroll
    for (int i = 0; i < 3; i++) {
        u32 u = xr[i * 64 + lane];
        float a = blo(u), c = bhi(u);
        v[2 * i] = a; v[2 * i + 1] = c;
        s += a + c; ss += a * a + c * c;
    }
    #pragma unroll
    for (int off = 32; off; off >>= 1) {
        s  += __shfl_down(s,  off, 64);
        ss += __shfl_down(ss, off, 64);
    }
    s = __shfl(s, 0, 64); ss = __shfl(ss, 0, 64);
    float mu = s * (1.f / E_);
    float var = ss * (1.f / E_) - mu * mu;
    float rs = rsqrtf(var + 1e-5f);
    u32* orow = (u32*)(out + (size_t)row * E_);
    #pragma unroll
    for (int i = 0; i < 3; i++) {
        int e = (i * 64 + lane) * 2;
        float r0 = (v[2 * i]     - mu) * rs * ldw(g, goff + e,     f) + ldw(b, boff + e,     f);
        float r1 = (v[2 * i + 1] - mu) * rs * ldw(g, goff + e + 1, f) + ldw(b, boff + e + 1, f);
        orow[i * 64 + lane] = pack_h2(r0, r1);
    }
}

// ---------------- XCD-aware bijective block swizzle (nwg % 8 == 0) ----------------
__device__ __forceinline__ void xcd_swz(int nx, int& bx, int& by) {
    int ld = blockIdx.y * gridDim.x + blockIdx.x;
    int nwg = gridDim.x * gridDim.y;
    int cpx = nwg >> 3;
    int t = (ld & 7) * cpx + (ld >> 3);
    bx = t % nx;
    by = t / nx;
}

// ---------------- async stage: 128 rows x 64 k (f16) -> 16KB LDS buffer ----------------
// global_load_lds, 16B/lane, 4 instructions per wave per call. LDS dest linear;
// SOURCE pre-inverse-swizzled so LDS physical slot p of row r holds logical slot
// p^(r&7) (rule-21 both-sides pattern).
__device__ __forceinline__ void stage_lds(const u16* __restrict__ gsrc, int ldK,
                                          u32* lbuf, int wi, int lane) {
    #pragma unroll
    for (int p = 0; p < 4; p++) {
        int i = (wi << 2) + p;
        int S = (i << 6) + lane;
        int r = S >> 3, cs = S & 7;
        const u16* gp = gsrc + (size_t)r * ldK + ((cs ^ (r & 7)) << 3);
        __builtin_amdgcn_global_load_lds(
            (const __attribute__((address_space(1))) u32*)gp,
            (__attribute__((address_space(3))) u32*)(lbuf + (i << 8)),
            16, 0, 0);
    }
}

// ---------------- MFMA GEMM body: 128x128 tile, BK=64, 2-deep counted-vmcnt pipeline ----
// T4 pattern: prologue issues tiles 0,1 (8 gload_lds insts/wave each). Per tile:
//   vmcnt(8)  -> oldest tile's loads landed, next tile's stay IN FLIGHT
//   s_barrier -> all waves' tile-t data in LDS (raw barrier: no compiler drain)
//   MFMA (setprio-wrapped)
//   s_barrier -> all waves done reading buf
//   issue stage(t+2) into the just-freed buf (no wait)
// vmcnt(0) only at the last tile. sched_barrier(0) pins ds_reads inside the
// barrier pair (rule #18). Uniform control flow; <=16 loads outstanding/wave.
// CMODE: 0 = f16 out (+relu opt), 1 = bf16 residual out, 2 = f32 out guarded (lm head)
template<int CMODE>
__device__ __forceinline__ void gemm_body(
        const _Float16* __restrict__ A,
        const _Float16* __restrict__ Wt,     // [N][K] f16 pre-transposed
        const void* __restrict__ bias, long long boff, int has_bias, int f,
        void* __restrict__ Cv, int N, int K, int relu,
        int bx, int by, u32* Af, u32* Wf) {
    const int tid = threadIdx.x;
    const int lane = tid & 63;
    const int wi = tid >> 6;
    const int wr = wi >> 1, wc = wi & 1;
    const int row0 = by << 7, col0 = bx << 7;
    const int l15 = lane & 15, l4 = lane >> 4;

    f32x4 acc[4][4];
    #pragma unroll
    for (int m = 0; m < 4; m++)
        #pragma unroll
        for (int n = 0; n < 4; n++)
            acc[m][n] = f32x4{0.f, 0.f, 0.f, 0.f};

    const u16* Ab = (const u16*)A + (size_t)row0 * K;
    const u16* Wb = (const u16*)Wt + (size_t)col0 * K;

    const int ntile = K >> 6;
    // ---- prologue: 2-deep prefetch ----
    stage_lds(Ab, K, Af, wi, lane);
    stage_lds(Wb, K, Wf, wi, lane);
    if (ntile > 1) {
        stage_lds(Ab + 64, K, Af + (1 << 12), wi, lane);
        stage_lds(Wb + 64, K, Wf + (1 << 12), wi, lane);
    }

    for (int t = 0; t < ntile; t++) {
        const int buf = t & 1;
        if (t + 1 < ntile) asm volatile("s_waitcnt vmcnt(8)" ::: "memory");
        else               asm volatile("s_waitcnt vmcnt(0)" ::: "memory");
        __builtin_amdgcn_s_barrier();
        __builtin_amdgcn_sched_barrier(0);
        __builtin_amdgcn_s_setprio(1);
        #pragma unroll
        for (int kh = 0; kh < 2; kh++) {
            f16x8 a4[4], w4[4];
            int s = (kh << 2) + l4;
            #pragma unroll
            for (int m = 0; m < 4; m++) {
                int r = (wr << 6) + (m << 4) + l15;
                a4[m] = *(const f16x8*)&Af[(buf << 12) + r * 32 + ((s ^ (r & 7)) << 2)];
            }
            #pragma unroll
            for (int n = 0; n < 4; n++) {
                int c = (wc << 6) + (n << 4) + l15;
                w4[n] = *(const f16x8*)&Wf[(buf << 12) + c * 32 + ((s ^ (c & 7)) << 2)];
            }
            #pragma unroll
            for (int m = 0; m < 4; m++)
                #pragma unroll
                for (int n = 0; n < 4; n++)
                    acc[m][n] = __builtin_amdgcn_mfma_f32_16x16x32_f16(a4[m], w4[n], acc[m][n], 0, 0, 0);
        }
        __builtin_amdgcn_s_setprio(0);
        __builtin_amdgcn_sched_barrier(0);
        __builtin_amdgcn_s_barrier();
        if (t + 2 < ntile) {
            stage_lds(Ab + ((t + 2) << 6), K, Af + (buf << 12), wi, lane);
            stage_lds(Wb + ((t + 2) << 6), K, Wf + (buf << 12), wi, lane);
        }
    }

    // ---- epilogue ----
    float bv[4];
    #pragma unroll
    for (int n = 0; n < 4; n++) {
        int col = col0 + (wc << 6) + (n << 4) + l15;
        bv[n] = (has_bias && (CMODE != 2 || col < N)) ? ldw(bias, boff + col, f) : 0.f;
    }
    #pragma unroll
    for (int m = 0; m < 4; m++) {
        #pragma unroll
        for (int i = 0; i < 4; i++) {
            int row = row0 + (wr << 6) + (m << 4) + (l4 << 2) + i;
            #pragma unroll
            for (int n = 0; n < 4; n++) {
                int col = col0 + (wc << 6) + (n << 4) + l15;
                if (CMODE == 2 && col >= N) continue;
                float r = acc[m][n][i] + bv[n];
                size_t o = (size_t)row * N + col;
                if (CMODE == 0) {
                    if (relu) r = fmaxf(r, 0.f);
                    ((_Float16*)Cv)[o] = (_Float16)r;
                } else if (CMODE == 1) {
                    __hip_bfloat16* C = (__hip_bfloat16*)Cv;
                    r += __bfloat162float(C[o]);
                    C[o] = __float2bfloat16(r);
                } else {
                    ((float*)Cv)[o] = r;
                }
            }
        }
    }
}

__global__ __launch_bounds__(256, 2) void gemm_f16o_k(
        const _Float16* __restrict__ A, const _Float16* __restrict__ Wt,
        const void* __restrict__ bias, long long boff, const int* __restrict__ flag,
        _Float16* __restrict__ C, int N, int K, int relu) {
    __shared__ __align__(16) u32 Af[8192];
    __shared__ __align__(16) u32 Wf[8192];
    int bx, by;
    xcd_swz(gridDim.x, bx, by);
    gemm_body<0>(A, Wt, bias, boff, 1, *flag, C, N, K, relu, bx, by, Af, Wf);
}

__global__ __launch_bounds__(256, 2) void gemm_res_k(
        const _Float16* __restrict__ A, const _Float16* __restrict__ Wt,
        const void* __restrict__ bias, long long boff, const int* __restrict__ flag,
        __hip_bfloat16* __restrict__ C, int N, int K) {
    __shared__ __align__(16) u32 Af[8192];
    __shared__ __align__(16) u32 Wf[8192];
    int bx, by;
    xcd_swz(gridDim.x, bx, by);
    gemm_body<1>(A, Wt, bias, boff, 1, *flag, C, N, K, 0, bx, by, Af, Wf);
}

// fused Q/K/V: grid (9, 128)
__global__ __launch_bounds__(256, 2) void gemm_qkv_k(
        const _Float16* __restrict__ A, const _Float16* __restrict__ wls,
        _Float16* __restrict__ qb, _Float16* __restrict__ kb, _Float16* __restrict__ vb) {
    __shared__ __align__(16) u32 Af[8192];
    __shared__ __align__(16) u32 Wf[8192];
    int sx, by;
    xcd_swz(9, sx, by);
    int which = sx / 3, bx = sx % 3;
    const _Float16* Wt = wls + (size_t)which * EE;
    _Float16* C = (which == 0) ? qb : (which == 1) ? kb : vb;
    gemm_body<0>(A, Wt, nullptr, 0, 0, 0, C, E_, E_, 0, bx, by, Af, Wf);
}

// lm head: N=65 in one guarded 128-col tile (wlm padded to 128 rows), f32 out
__global__ __launch_bounds__(256, 2) void gemm_lmh_k(
        const _Float16* __restrict__ A, const _Float16* __restrict__ Wt,
        const void* __restrict__ bias, const int* __restrict__ flag,
        float* __restrict__ logits) {
    __shared__ __align__(16) u32 Af[8192];
    __shared__ __align__(16) u32 Wf[8192];
    int bx, by;
    xcd_swz(1, bx, by);
    gemm_body<2>(A, Wt, bias, 0, 1, *flag, logits, V_, E_, 0, bx, by, Af, Wf);
}

// ---------------- MFMA attention, f16 I/O ----------------
template<int NK>
__device__ __forceinline__ void attn_body(
        const u16* __restrict__ qbase, const u16* __restrict__ kbase,
        const u16* __restrict__ vbase, u16* __restrict__ abase,
        int q0, u32* Kls, u32* Pls) {
    constexpr int NKF = NK / 16;
    constexpr int NKS = NK / 32;
    const int tid = threadIdx.x;
    const int lane = tid & 63;
    const int w = tid >> 6;
    const int l15 = lane & 15, l4 = lane >> 4;

    {   // stage K [NK][64] f16 (pure copy), slot ^= key&7
        int r8 = tid >> 3, slot = tid & 7;
        #pragma unroll
        for (int p = 0; p < NK / 32; p++) {
            int key = r8 + p * 32;
            uint4 a8 = *(const uint4*)(kbase + (size_t)key * E_ + slot * 8);
            *(uint4*)&Kls[key * 32 + ((slot ^ (key & 7)) << 2)] = a8;
        }
    }
    __syncthreads();

    const int qrow = w * 16 + l15;
    const int qi = q0 + qrow;
    f32x4 acc[NKF];
    #pragma unroll
    for (int kf = 0; kf < NKF; kf++) acc[kf] = f32x4{0.f, 0.f, 0.f, 0.f};

    // ---- phase 1: S^T = K @ Q^T ----
    #pragma unroll
    for (int kh = 0; kh < 2; kh++) {
        f16x8 qh = *(const f16x8*)(qbase + (size_t)qi * E_ + ((kh << 2) + l4) * 8);
        #pragma unroll
        for (int kf = 0; kf < NKF; kf++) {
            int krow = kf * 16 + l15;
            f16x8 kf8 = *(const f16x8*)&Kls[krow * 32 + ((((kh << 2) + l4) ^ (krow & 7)) << 2)];
            acc[kf] = __builtin_amdgcn_mfma_f32_16x16x32_f16(kf8, qh, acc[kf], 0, 0, 0);
        }
    }

    float m = -1e30f;
    #pragma unroll
    for (int kf = 0; kf < NKF; kf++)
        #pragma unroll
        for (int r = 0; r < 4; r++) {
            int key = kf * 16 + l4 * 4 + r;
            float s = acc[kf][r] * 0.125f;
            if (key > qi) s = -1e30f;
            acc[kf][r] = s;
            m = fmaxf(m, s);
        }
    m = fmaxf(m, __shfl_xor(m, 16, 64));
    m = fmaxf(m, __shfl_xor(m, 32, 64));
    float sum = 0.f;
    #pragma unroll
    for (int kf = 0; kf < NKF; kf++)
        #pragma unroll
        for (int r = 0; r < 4; r++) {
            float p = __expf(acc[kf][r] - m);
            acc[kf][r] = p;
            sum += p;
        }
    sum += __shfl_xor(sum, 16, 64);
    sum += __shfl_xor(sum, 32, 64);
    float inv = 1.f / sum;

    #pragma unroll
    for (int kf = 0; kf < NKF; kf++) {
        uint2 pw;
        pw.x = pack_h2(acc[kf][0] * inv, acc[kf][1] * inv);
        pw.y = pack_h2(acc[kf][2] * inv, acc[kf][3] * inv);
        int j = kf * 2 + (l4 >> 1);
        *(uint2*)&Pls[qrow * 128 + ((j ^ (qrow & 15)) << 2) + ((l4 & 1) << 1)] = pw;
    }
    __syncthreads();

    // restage V^T into Kls (bit-ops only, f16 input)
    for (int kp = lane; kp < NK / 2; kp += 64) {
        #pragma unroll
        for (int dq = 0; dq < 2; dq++) {
            int db = w + dq * 4;
            uint4 v0 = *(const uint4*)(vbase + (size_t)(2 * kp) * E_ + db * 8);
            uint4 v1 = *(const uint4*)(vbase + (size_t)(2 * kp + 1) * E_ + db * 8);
            u32 uu[8];
            uu[0] = pk_lo(v0.x, v1.x); uu[1] = pk_hi(v0.x, v1.x);
            uu[2] = pk_lo(v0.y, v1.y); uu[3] = pk_hi(v0.y, v1.y);
            uu[4] = pk_lo(v0.z, v1.z); uu[5] = pk_hi(v0.z, v1.z);
            uu[6] = pk_lo(v0.w, v1.w); uu[7] = pk_hi(v0.w, v1.w);
            #pragma unroll
            for (int i = 0; i < 8; i++) {
                int d = db * 8 + i;
                Kls[d * 128 + (((kp >> 2) ^ (d & 15)) << 2) + (kp & 3)] = uu[i];
            }
        }
    }
    __syncthreads();

    f32x4 o2[4];
    #pragma unroll
    for (int df = 0; df < 4; df++) o2[df] = f32x4{0.f, 0.f, 0.f, 0.f};
    #pragma unroll
    for (int ks = 0; ks < NKS; ks++) {
        f16x8 pa = *(const f16x8*)&Pls[qrow * 128 + (((ks * 4 + l4) ^ (qrow & 15)) << 2)];
        #pragma unroll
        for (int df = 0; df < 4; df++) {
            int d = df * 16 + l15;
            f16x8 vb8 = *(const f16x8*)&Kls[d * 128 + (((ks * 4 + l4) ^ (d & 15)) << 2)];
            o2[df] = __builtin_amdgcn_mfma_f32_16x16x32_f16(pa, vb8, o2[df], 0, 0, 0);
        }
    }
    #pragma unroll
    for (int df = 0; df < 4; df++)
        #pragma unroll
        for (int r = 0; r < 4; r++) {
            int qg = q0 + w * 16 + l4 * 4 + r;
            abase[(size_t)qg * E_ + df * 16 + l15] = f2hu(o2[df][r]);
        }
}

__global__ __launch_bounds__(256) void attn_mfma_k(
        const _Float16* __restrict__ q, const _Float16* __restrict__ k,
        const _Float16* __restrict__ v, _Float16* __restrict__ att) {
    __shared__ __align__(16) u32 Kls[256 * 32];   // 32 KB
    __shared__ __align__(16) u32 Pls[64 * 128];   // 32 KB
    int chunk = blockIdx.x & 3;
    int bh = blockIdx.x >> 2;
    int b = bh / H_, h = bh % H_;
    const u16* qbase = (const u16*)q + ((size_t)b * T_) * E_ + h * D_;
    const u16* kbase = (const u16*)k + ((size_t)b * T_) * E_ + h * D_;
    const u16* vbase = (const u16*)v + ((size_t)b * T_) * E_ + h * D_;
    u16* abase = (u16*)att + ((size_t)b * T_) * E_ + h * D_;
    int q0 = chunk * 64;
    switch (chunk) {
        case 0: attn_body< 64>(qbase, kbase, vbase, abase, q0, Kls, Pls); break;
        case 1: attn_body<128>(qbase, kbase, vbase, abase, q0, Kls, Pls); break;
        case 2: attn_body<192>(qbase, kbase, vbase, abase, q0, Kls, Pls); break;
        default: attn_body<256>(qbase, kbase, vbase, abase, q0, Kls, Pls); break;
    }
}

// ---------------- loss tail ----------------
__global__ void outcvt_k(const float* __restrict__ logits, const int* __restrict__ flag,
                         void* __restrict__ out) {
    int i = blockIdx.x * blockDim.x + threadIdx.x;
    if (i >= BT * V_) return;
    if (*flag) ((float*)out)[i] = logits[i];
    else ((__hip_bfloat16*)out)[i] = __float2bfloat16(logits[i]);
}

__global__ __launch_bounds__(256) void rowloss2_k(
        const float* __restrict__ logits, const int* __restrict__ tgt,
        float* __restrict__ accum) {
    __shared__ float part[4];
    int w = threadIdx.x >> 6, lane = threadIdx.x & 63;
    float local = 0.f;
    for (int i = 0; i < 16; i++) {
        int row = blockIdx.x * 64 + w * 16 + i;
        const float* lr = logits + (size_t)row * V_;
        float v0 = lr[lane];
        float v64 = (lane == 0) ? lr[64] : -1e30f;
        float m = fmaxf(v0, v64);
        #pragma unroll
        for (int off = 32; off; off >>= 1) m = fmaxf(m, __shfl_xor(m, off, 64));
        float se = __expf(v0 - m) + ((lane == 0) ? __expf(v64 - m) : 0.f);
        #pragma unroll
        for (int off = 32; off; off >>= 1) se += __shfl_xor(se, off, 64);
        if (lane == 0) local += lr[tgt[row]] - m - __logf(se);
    }
    if (lane == 0) part[w] = local;
    __syncthreads();
    if (threadIdx.x == 0)
        atomicAdd(accum, -(part[0] + part[1] + part[2] + part[3]));
}

__global__ void final_k(const float* __restrict__ accum, const int* __restrict__ flag,
                        void* __restrict__ out) {
    if (threadIdx.x == 0) {
        float v = *accum * (1.f / BT);
        if (*flag) ((float*)out)[(size_t)BT * V_] = v;
        else ((__hip_bfloat16*)out)[(size_t)BT * V_] = __float2bfloat16(v);
    }
}

extern "C" void kernel_launch(void* const* d_in, const int* in_sizes, int n_in,
                              void* d_out, int out_size, void* d_ws, size_t ws_size,
                              hipStream_t stream) {
    const int* idx     = (const int*)d_in[0];
    const int* targets = (const int*)d_in[1];
    const void* tok  = d_in[2];
    const void* pos  = d_in[3];
    const void* Wq   = d_in[4];
    const void* Wk   = d_in[5];
    const void* Wv   = d_in[6];
    const void* Wo   = d_in[7];
    const void* bo   = d_in[8];
    const void* W1   = d_in[9];
    const void* b1   = d_in[10];
    const void* W2   = d_in[11];
    const void* b2   = d_in[12];
    const void* ln1g = d_in[13];
    const void* ln1b = d_in[14];
    const void* ln2g = d_in[15];
    const void* ln2b = d_in[16];
    const void* lnfg = d_in[17];
    const void* lnfb = d_in[18];
    const void* Wlm  = d_in[19];
    const void* blm  = d_in[20];

    // ---- workspace layout (~139 MiB total; ws is 268 MB per fillBuffer WRITE_SIZE) ----
    // p: xb 2XN | hb 2XN | qb 2XN | kb 2XN | vb 2XN | wt 6*WSLOT f16 | wlm 96KiB
    //    | ffnb FULL 16384 x 1536 f16 (50.3 MB, own region -> no overlays anywhere)
    char* wsb = (char*)d_ws;
    int*   flag    = (int*)wsb;
    float* lossacc = (float*)(wsb + 8);
    float* logits  = (float*)(wsb + 256);
    char* p = wsb + 256 + sizeof(float) * (size_t)BT * V_;
    __hip_bfloat16* xb = (__hip_bfloat16*)p;                 // bf16 residual stream
    _Float16* hb = (_Float16*)(p + 2 * (size_t)XN);
    _Float16* qb = (_Float16*)(p + 4 * (size_t)XN);
    _Float16* kb = (_Float16*)(p + 6 * (size_t)XN);
    _Float16* vb = (_Float16*)(p + 8 * (size_t)XN);
    _Float16* wt = (_Float16*)(p + 10 * (size_t)XN);         // 6*WSLOT f16
    _Float16* wlm = wt + 6 * WSLOT;                          // 128*384 f16
    _Float16* ffnb = wlm + (size_t)128 * E_;                 // FULL FFN hidden [BT][F]
    _Float16* ab = hb;       // attn out (hb dead after qkv gemm)

    dim3 grdEm(3, 128);      // nwg=384
    dim3 grdQKV(9, 128);     // nwg=1152
    dim3 grdW1(12, 128);     // nwg=1536 (FULL rows)
    dim3 grdW2(3, 128);      // nwg=384  (FULL rows)
    dim3 grdLM(1, 128);      // nwg=128

    init_k<<<1, 64, 0, stream>>>(flag, lossacc);
    detect_k<<<(V_ * E_ + 255) / 256, 256, 0, stream>>>(tok, V_ * E_, flag);
    wtrans_all_k<<<2604, 256, 0, stream>>>(Wq, Wk, Wv, Wo, W1, W2, Wlm, flag, wt);
    embed_k<<<(XN / 2 + 255) / 256, 256, 0, stream>>>(idx, tok, pos, flag, xb);

    for (int l = 0; l < L_; l++) {
        const _Float16* wls = wt + (size_t)l * WSLOT;
        ln4_k<<<BT / 4, 256, 0, stream>>>(xb, ln1g, (long long)l * E_, ln1b, (long long)l * E_, flag, hb);
        gemm_qkv_k<<<grdQKV, 256, 0, stream>>>(hb, wls, qb, kb, vb);
        attn_mfma_k<<<B_ * H_ * 4, 256, 0, stream>>>(qb, kb, vb, ab);
        gemm_res_k<<<grdEm, 256, 0, stream>>>(ab, wls + 3 * EE, bo, (long long)l * E_, flag, xb, E_, E_);
        ln4_k<<<BT / 4, 256, 0, stream>>>(xb, ln2g, (long long)l * E_, ln2b, (long long)l * E_, flag, hb);
        gemm_f16o_k<<<grdW1, 256, 0, stream>>>(hb, wls + 4 * EE, b1, (long long)l * F_, flag, ffnb, F_, E_, 1);
        gemm_res_k<<<grdW2, 256, 0, stream>>>(ffnb, wls + 4 * EE + EF, b2, (long long)l * E_, flag, xb, E_, F_);
    }

    ln4_k<<<BT / 4, 256, 0, stream>>>(xb, lnfg, 0, lnfb, 0, flag, hb);
    gemm_lmh_k<<<grdLM, 256, 0, stream>>>(hb, wlm, blm, flag, logits);

    outcvt_k<<<(BT * V_ + 255) / 256, 256, 0, stream>>>(logits, flag, d_out);
    rowloss2_k<<<BT / 64, 256, 0, stream>>>(logits, targets, lossacc);
    final_k<<<1, 64, 0, stream>>>(lossacc, flag, d_out);
}

// Round 12
// 1067.696 us; speedup vs baseline: 5.9256x; 1.0034x over previous
//
#include <hip/hip_runtime.h>
#include <hip/hip_bf16.h>

typedef unsigned short u16;
typedef unsigned int u32;
typedef _Float16 h16x2 __attribute__((ext_vector_type(2)));
typedef _Float16 f16x8 __attribute__((ext_vector_type(8)));
typedef float f32x4 __attribute__((ext_vector_type(4)));

constexpr int B_ = 64, T_ = 256, V_ = 65, E_ = 384, H_ = 6, L_ = 6, D_ = 64, F_ = 1536;
constexpr int BT = B_ * T_;
constexpr int XN = BT * E_;
constexpr long long EE = (long long)E_ * E_;          // 147456
constexpr long long EF = (long long)E_ * F_;          // 589824
constexpr long long WSLOT = 4 * EE + 2 * EF;          // f16 per layer
constexpr int NSTAT = 13 * BT * 2;                    // stats floats

__device__ __forceinline__ float ldw(const void* p, long long i, int f32) {
    return f32 ? ((const float*)p)[i]
               : __bfloat162float(((const __hip_bfloat16*)p)[i]);
}
__device__ __forceinline__ u16 f2hu(float f) { union { _Float16 h; u16 u; } x; x.h = (_Float16)f; return x.u; }
__device__ __forceinline__ u32 pack_h2(float a, float b) {
    union { h16x2 h; u32 u; } x;
    x.h[0] = (_Float16)a; x.h[1] = (_Float16)b;
    return x.u;
}
__device__ __forceinline__ u32 pk_lo(u32 a, u32 b) { return (a & 0xffffu) | (b << 16); }
__device__ __forceinline__ u32 pk_hi(u32 a, u32 b) { return (a >> 16) | (b & 0xffff0000u); }

__global__ void init_k(int* flag, float* lossacc) {
    if (threadIdx.x == 0) { *flag = 0; *lossacc = 0.f; }
}

__global__ void zstats_k(float* st) {
    int i = blockIdx.x * blockDim.x + threadIdx.x;
    if (i < NSTAT) st[i] = 0.f;
}

__global__ void detect_k(const void* tok, int n, int* flag) {
    int i = blockIdx.x * blockDim.x + threadIdx.x;
    if (i < n) {
        float v = __bfloat162float(((const __hip_bfloat16*)tok)[i]);
        if (!(fabsf(v) < 1e4f)) *flag = 1;
    }
}

// ---------------- weight transposes, LN-gamma folded: Wt[n][k] = g[k]*W[k][n] ----------
// qkv (g=ln1), W1 (g=ln2), lm (g=lnf) scaled; Wo/W2 raw. Layout per layer slot:
// [Wq|Wk|Wv|Wo](4*EE) | W1t (EF,[F][E]) | W2t (EF,[E][F]); lm padded to 128 rows.
__global__ __launch_bounds__(256) void wtrans_all_k(
        const void* __restrict__ Wq, const void* __restrict__ Wk,
        const void* __restrict__ Wv, const void* __restrict__ Wo,
        const void* __restrict__ W1, const void* __restrict__ W2,
        const void* __restrict__ Wlm,
        const void* __restrict__ ln1g, const void* __restrict__ ln2g,
        const void* __restrict__ lnfg,
        const int* __restrict__ flag, _Float16* __restrict__ wt) {
    int f = *flag;
    int b = blockIdx.x;
    __shared__ _Float16 tile[64][65];
    if (b < 2592) {
        int l = b / 432, r = b % 432;
        const void* src; long long soff; _Float16* dst;
        const void* gp = nullptr; long long go = 0;
        int K, N, kt, nt;
        _Float16* wls = wt + (size_t)l * WSLOT;
        if (r < 144) {
            int m = r / 36, t = r % 36;
            src = (m == 0) ? Wq : (m == 1) ? Wk : (m == 2) ? Wv : Wo;
            soff = (long long)l * EE;
            dst = wls + (size_t)m * EE;
            K = E_; N = E_; kt = t / 6; nt = t % 6;
            if (m < 3) { gp = ln1g; go = (long long)l * E_; }
        } else if (r < 288) {
            int t = r - 144;
            src = W1; soff = (long long)l * EF;
            dst = wls + 4 * EE;
            K = E_; N = F_; kt = t / 24; nt = t % 24;
            gp = ln2g; go = (long long)l * E_;
        } else {
            int t = r - 288;
            src = W2; soff = (long long)l * EF;
            dst = wls + 4 * EE + EF;
            K = F_; N = E_; kt = t / 6; nt = t % 6;
        }
        int k0 = kt * 64, n0 = nt * 64;
        #pragma unroll 4
        for (int p = 0; p < 16; p++) {
            int k = p * 4 + (threadIdx.x >> 6), n = threadIdx.x & 63;
            float v = ldw(src, soff + (long long)(k0 + k) * N + n0 + n, f);
            if (gp) v *= ldw(gp, go + k0 + k, f);
            tile[k][n] = (_Float16)v;
        }
        __syncthreads();
        #pragma unroll 4
        for (int p = 0; p < 16; p++) {
            int n = p * 4 + (threadIdx.x >> 6), k = threadIdx.x & 63;
            dst[(size_t)(n0 + n) * K + k0 + k] = tile[k][n];
        }
    } else {
        int t = b - 2592;            // 0..11
        _Float16* wlm = wt + 6 * WSLOT;
        int kt = t / 2, nt = t % 2;
        int k0 = kt * 64, n0 = nt * 64;
        #pragma unroll 4
        for (int p = 0; p < 16; p++) {
            int k = p * 4 + (threadIdx.x >> 6), n = threadIdx.x & 63;
            float v = 0.f;
            if (n0 + n < V_)
                v = ldw(Wlm, (long long)(k0 + k) * V_ + n0 + n, f) *
                    ldw(lnfg, k0 + k, f);
            tile[k][n] = (_Float16)v;
        }
        __syncthreads();
        #pragma unroll 4
        for (int p = 0; p < 16; p++) {
            int n = p * 4 + (threadIdx.x >> 6), k = threadIdx.x & 63;
            wlm[(size_t)(n0 + n) * E_ + k0 + k] = tile[k][n];
        }
    }
}

// ---------------- fold_k: cs[n]=sum_k g[k]W[k][n], bb[n]=sum_k bln[k]W[k][n]+bias0[n] ---
// blocks 0..71: l=b/12, r=b%12 (r<6: qkv which=r>>1 half=r&1; else W1 part=r-6). block 72: lm.
__global__ __launch_bounds__(256) void fold_k(
        const void* __restrict__ Wq, const void* __restrict__ Wk,
        const void* __restrict__ Wv, const void* __restrict__ W1,
        const void* __restrict__ Wlm,
        const void* __restrict__ ln1g, const void* __restrict__ ln1b,
        const void* __restrict__ ln2g, const void* __restrict__ ln2b,
        const void* __restrict__ lnfg, const void* __restrict__ lnfb,
        const void* __restrict__ b1, const void* __restrict__ blm,
        const int* __restrict__ flag,
        float* __restrict__ csqkv, float* __restrict__ bbqkv,
        float* __restrict__ csw1, float* __restrict__ bbw1,
        float* __restrict__ cslm, float* __restrict__ bblm) {
    int f = *flag;
    int b = blockIdx.x, tid = threadIdx.x;
    float cs = 0.f, bb = 0.f;
    if (b < 72) {
        int l = b / 12, r = b % 12;
        if (r < 6) {
            int which = r >> 1, half = r & 1;
            int n = half * 256 + tid;
            if (n >= E_) return;
            const void* W = (which == 0) ? Wq : (which == 1) ? Wk : Wv;
            long long wo = (long long)l * EE, go = (long long)l * E_;
            for (int k = 0; k < E_; k++) {
                float wv = ldw(W, wo + (long long)k * E_ + n, f);
                cs += ldw(ln1g, go + k, f) * wv;
                bb += ldw(ln1b, go + k, f) * wv;
            }
            csqkv[((size_t)l * 3 + which) * E_ + n] = cs;
            bbqkv[((size_t)l * 3 + which) * E_ + n] = bb;
        } else {
            int n = (r - 6) * 256 + tid;
            long long wo = (long long)l * EF, go = (long long)l * E_;
            for (int k = 0; k < E_; k++) {
                float wv = ldw(W1, wo + (long long)k * F_ + n, f);
                cs += ldw(ln2g, go + k, f) * wv;
                bb += ldw(ln2b, go + k, f) * wv;
            }
            bb += ldw(b1, (long long)l * F_ + n, f);
            csw1[(size_t)l * F_ + n] = cs;
            bbw1[(size_t)l * F_ + n] = bb;
        }
    } else {
        int n = tid;
        if (n >= 128) return;
        if (n < V_) {
            for (int k = 0; k < E_; k++) {
                float wv = ldw(Wlm, (long long)k * V_ + n, f);
                cs += ldw(lnfg, k, f) * wv;
                bb += ldw(lnfb, k, f) * wv;
            }
            bb += ldw(blm, n, f);
        }
        cslm[n] = cs; bblm[n] = bb;
    }
}

// ---------------- embedding: wave per row, f16 residual + direct row stats ----------------
__global__ __launch_bounds__(256) void embed_k(
        const int* __restrict__ idx, const void* __restrict__ tok,
        const void* __restrict__ pos, const int* __restrict__ flag,
        _Float16* __restrict__ x, float* __restrict__ st0) {
    int f = *flag;
    int w = threadIdx.x >> 6, lane = threadIdx.x & 63;
    int row = blockIdx.x * 4 + w;
    int t = row % T_;
    long long tb = (long long)idx[row] * E_;
    long long pb = (long long)t * E_;
    u32* orow = (u32*)(x + (size_t)row * E_);
    float s = 0.f, ss = 0.f;
    #pragma unroll
    for (int i = 0; i < 3; i++) {
        int e = (i * 64 + lane) * 2;
        float r0 = ldw(tok, tb + e, f) + ldw(pos, pb + e, f);
        float r1 = ldw(tok, tb + e + 1, f) + ldw(pos, pb + e + 1, f);
        _Float16 h0 = (_Float16)r0, h1 = (_Float16)r1;
        union { h16x2 h; u32 u; } pk; pk.h[0] = h0; pk.h[1] = h1;
        orow[i * 64 + lane] = pk.u;
        float a = (float)h0, c = (float)h1;
        s += a + c; ss += a * a + c * c;
    }
    #pragma unroll
    for (int off = 32; off; off >>= 1) {
        s  += __shfl_down(s,  off, 64);
        ss += __shfl_down(ss, off, 64);
    }
    if (lane == 0) { st0[2 * row] = s; st0[2 * row + 1] = ss; }
}

// ---------------- XCD-aware bijective block swizzle (nwg % 8 == 0) ----------------
__device__ __forceinline__ void xcd_swz(int nx, int& bx, int& by) {
    int ld = blockIdx.y * gridDim.x + blockIdx.x;
    int nwg = gridDim.x * gridDim.y;
    int cpx = nwg >> 3;
    int t = (ld & 7) * cpx + (ld >> 3);
    bx = t % nx;
    by = t / nx;
}

// ---------------- async stage: 128 rows x 64 k (f16) -> 16KB LDS buffer ----------------
__device__ __forceinline__ void stage_lds(const u16* __restrict__ gsrc, int ldK,
                                          u32* lbuf, int wi, int lane) {
    #pragma unroll
    for (int p = 0; p < 4; p++) {
        int i = (wi << 2) + p;
        int S = (i << 6) + lane;
        int r = S >> 3, cs = S & 7;
        const u16* gp = gsrc + (size_t)r * ldK + ((cs ^ (r & 7)) << 3);
        __builtin_amdgcn_global_load_lds(
            (const __attribute__((address_space(1))) u32*)gp,
            (__attribute__((address_space(3))) u32*)(lbuf + (i << 8)),
            16, 0, 0);
    }
}

// ---------------- MFMA GEMM body: 128x128 tile, BK=64, 2-deep counted-vmcnt pipeline ----
// K-loop identical to round 11 (verified). Epilogue variants:
//  CMODE 0: f16 out (+relu); CMODE 1: f16 residual RMW; CMODE 2: f32 logits + d_out.
//  LNF: A is the RAW residual; out = rs*(acc - mu*cs[col]) + bb[col], (rs,mu) from stin.
//  STATS: accumulate per-row (sum,sumsq) of written f16 values into stout (atomics).
template<int CMODE, bool LNF, bool STATS>
__device__ __forceinline__ void gemm_body(
        const _Float16* __restrict__ A,
        const _Float16* __restrict__ Wt,
        const float* __restrict__ csp, const float* __restrict__ bbp,
        const float* __restrict__ stin,
        const void* __restrict__ bias, long long boff, int has_bias, int f,
        void* __restrict__ Cv, void* __restrict__ dout, float* __restrict__ stout,
        int N, int K, int relu, int bx, int by, u32* Af, u32* Wf) {
    const int tid = threadIdx.x;
    const int lane = tid & 63;
    const int wi = tid >> 6;
    const int wr = wi >> 1, wc = wi & 1;
    const int row0 = by << 7, col0 = bx << 7;
    const int l15 = lane & 15, l4 = lane >> 4;

    f32x4 acc[4][4];
    #pragma unroll
    for (int m = 0; m < 4; m++)
        #pragma unroll
        for (int n = 0; n < 4; n++)
            acc[m][n] = f32x4{0.f, 0.f, 0.f, 0.f};

    const u16* Ab = (const u16*)A + (size_t)row0 * K;
    const u16* Wb = (const u16*)Wt + (size_t)col0 * K;

    const int ntile = K >> 6;
    stage_lds(Ab, K, Af, wi, lane);
    stage_lds(Wb, K, Wf, wi, lane);
    if (ntile > 1) {
        stage_lds(Ab + 64, K, Af + (1 << 12), wi, lane);
        stage_lds(Wb + 64, K, Wf + (1 << 12), wi, lane);
    }

    for (int t = 0; t < ntile; t++) {
        const int buf = t & 1;
        if (t + 1 < ntile) asm volatile("s_waitcnt vmcnt(8)" ::: "memory");
        else               asm volatile("s_waitcnt vmcnt(0)" ::: "memory");
        __builtin_amdgcn_s_barrier();
        __builtin_amdgcn_sched_barrier(0);
        __builtin_amdgcn_s_setprio(1);
        #pragma unroll
        for (int kh = 0; kh < 2; kh++) {
            f16x8 a4[4], w4[4];
            int s = (kh << 2) + l4;
            #pragma unroll
            for (int m = 0; m < 4; m++) {
                int r = (wr << 6) + (m << 4) + l15;
                a4[m] = *(const f16x8*)&Af[(buf << 12) + r * 32 + ((s ^ (r & 7)) << 2)];
            }
            #pragma unroll
            for (int n = 0; n < 4; n++) {
                int c = (wc << 6) + (n << 4) + l15;
                w4[n] = *(const f16x8*)&Wf[(buf << 12) + c * 32 + ((s ^ (c & 7)) << 2)];
            }
            #pragma unroll
            for (int m = 0; m < 4; m++)
                #pragma unroll
                for (int n = 0; n < 4; n++)
                    acc[m][n] = __builtin_amdgcn_mfma_f32_16x16x32_f16(a4[m], w4[n], acc[m][n], 0, 0, 0);
        }
        __builtin_amdgcn_s_setprio(0);
        __builtin_amdgcn_sched_barrier(0);
        __builtin_amdgcn_s_barrier();
        if (t + 2 < ntile) {
            stage_lds(Ab + ((t + 2) << 6), K, Af + (buf << 12), wi, lane);
            stage_lds(Wb + ((t + 2) << 6), K, Wf + (buf << 12), wi, lane);
        }
    }

    // ---- epilogue ----
    float c0[4], c1[4];
    #pragma unroll
    for (int n = 0; n < 4; n++) {
        int col = col0 + (wc << 6) + (n << 4) + l15;
        if (LNF) { c0[n] = csp[col]; c1[n] = bbp[col]; }
        else     { c0[n] = 0.f;
                   c1[n] = (has_bias && (CMODE != 2 || col < N)) ? ldw(bias, boff + col, f) : 0.f; }
    }
    #pragma unroll
    for (int m = 0; m < 4; m++) {
        #pragma unroll
        for (int i = 0; i < 4; i++) {
            int row = row0 + (wr << 6) + (m << 4) + (l4 << 2) + i;
            float mu = 0.f, rs = 1.f;
            if (LNF) {
                float sv = stin[2 * row], ssv = stin[2 * row + 1];
                mu = sv * (1.f / E_);
                rs = rsqrtf(ssv * (1.f / E_) - mu * mu + 1e-5f);
            }
            float ps = 0.f, pss = 0.f;
            #pragma unroll
            for (int n = 0; n < 4; n++) {
                int col = col0 + (wc << 6) + (n << 4) + l15;
                if (CMODE == 2 && col >= N) continue;
                float r = LNF ? rs * (acc[m][n][i] - mu * c0[n]) + c1[n]
                              : acc[m][n][i] + c1[n];
                size_t o = (size_t)row * N + col;
                if (CMODE == 0) {
                    if (relu) r = fmaxf(r, 0.f);
                    ((_Float16*)Cv)[o] = (_Float16)r;
                } else if (CMODE == 1) {
                    _Float16* C = (_Float16*)Cv;
                    r += (float)C[o];
                    _Float16 hv = (_Float16)r;
                    C[o] = hv;
                    if (STATS) { float xv = (float)hv; ps += xv; pss += xv * xv; }
                } else {
                    ((float*)Cv)[o] = r;
                    if (f) ((float*)dout)[o] = r;
                    else ((__hip_bfloat16*)dout)[o] = __float2bfloat16(r);
                }
            }
            if (STATS) {
                #pragma unroll
                for (int off = 1; off < 16; off <<= 1) {
                    ps  += __shfl_xor(ps,  off, 64);
                    pss += __shfl_xor(pss, off, 64);
                }
                if (l15 == 0) {
                    atomicAdd(&stout[2 * row], ps);
                    atomicAdd(&stout[2 * row + 1], pss);
                }
            }
        }
    }
}

// fused Q/K/V with ln1 fold: grid (9, 128)
__global__ __launch_bounds__(256, 2) void gemm_qkv_k(
        const _Float16* __restrict__ A, const _Float16* __restrict__ wls,
        const float* __restrict__ csL, const float* __restrict__ bbL,
        const float* __restrict__ stin,
        _Float16* __restrict__ qb, _Float16* __restrict__ kb, _Float16* __restrict__ vb) {
    __shared__ __align__(16) u32 Af[8192];
    __shared__ __align__(16) u32 Wf[8192];
    int sx, by;
    xcd_swz(9, sx, by);
    int which = sx / 3, bx = sx % 3;
    _Float16* C = (which == 0) ? qb : (which == 1) ? kb : vb;
    gemm_body<0, true, false>(A, wls + (size_t)which * EE,
                              csL + (size_t)which * E_, bbL + (size_t)which * E_, stin,
                              nullptr, 0, 0, 0, C, nullptr, nullptr,
                              E_, E_, 0, bx, by, Af, Wf);
}

// W1 with ln2 fold + relu: grid (12, 128)
__global__ __launch_bounds__(256, 2) void gemm_w1_k(
        const _Float16* __restrict__ A, const _Float16* __restrict__ Wt,
        const float* __restrict__ cs, const float* __restrict__ bb,
        const float* __restrict__ stin, _Float16* __restrict__ C) {
    __shared__ __align__(16) u32 Af[8192];
    __shared__ __align__(16) u32 Wf[8192];
    int bx, by;
    xcd_swz(gridDim.x, bx, by);
    gemm_body<0, true, false>(A, Wt, cs, bb, stin, nullptr, 0, 0, 0,
                              C, nullptr, nullptr, F_, E_, 1, bx, by, Af, Wf);
}

// residual writer (Wo/W2): f16 RMW + row-stats accumulation for the next LN site
__global__ __launch_bounds__(256, 2) void gemm_resst_k(
        const _Float16* __restrict__ A, const _Float16* __restrict__ Wt,
        const void* __restrict__ bias, long long boff, const int* __restrict__ flag,
        _Float16* __restrict__ C, float* __restrict__ stout, int N, int K) {
    __shared__ __align__(16) u32 Af[8192];
    __shared__ __align__(16) u32 Wf[8192];
    int bx, by;
    xcd_swz(gridDim.x, bx, by);
    gemm_body<1, false, true>(A, Wt, nullptr, nullptr, nullptr, bias, boff, 1, *flag,
                              C, nullptr, stout, N, K, 0, bx, by, Af, Wf);
}

// lm head with lnf fold; writes logits f32 AND d_out (outcvt fused). grid (1, 128).
__global__ __launch_bounds__(256, 2) void gemm_lmh_k(
        const _Float16* __restrict__ A, const _Float16* __restrict__ Wt,
        const float* __restrict__ cs, const float* __restrict__ bb,
        const float* __restrict__ stin, const int* __restrict__ flag,
        float* __restrict__ logits, void* __restrict__ dout) {
    __shared__ __align__(16) u32 Af[8192];
    __shared__ __align__(16) u32 Wf[8192];
    int bx, by;
    xcd_swz(1, bx, by);
    gemm_body<2, true, false>(A, Wt, cs, bb, stin, nullptr, 0, 0, *flag,
                              logits, dout, nullptr, V_, E_, 0, bx, by, Af, Wf);
}

// ---------------- MFMA attention, f16 I/O (verbatim) ----------------
template<int NK>
__device__ __forceinline__ void attn_body(
        const u16* __restrict__ qbase, const u16* __restrict__ kbase,
        const u16* __restrict__ vbase, u16* __restrict__ abase,
        int q0, u32* Kls, u32* Pls) {
    constexpr int NKF = NK / 16;
    constexpr int NKS = NK / 32;
    const int tid = threadIdx.x;
    const int lane = tid & 63;
    const int w = tid >> 6;
    const int l15 = lane & 15, l4 = lane >> 4;

    {
        int r8 = tid >> 3, slot = tid & 7;
        #pragma unroll
        for (int p = 0; p < NK / 32; p++) {
            int key = r8 + p * 32;
            uint4 a8 = *(const uint4*)(kbase + (size_t)key * E_ + slot * 8);
            *(uint4*)&Kls[key * 32 + ((slot ^ (key & 7)) << 2)] = a8;
        }
    }
    __syncthreads();

    const int qrow = w * 16 + l15;
    const int qi = q0 + qrow;
    f32x4 acc[NKF];
    #pragma unroll
    for (int kf = 0; kf < NKF; kf++) acc[kf] = f32x4{0.f, 0.f, 0.f, 0.f};

    #pragma unroll
    for (int kh = 0; kh < 2; kh++) {
        f16x8 qh = *(const f16x8*)(qbase + (size_t)qi * E_ + ((kh << 2) + l4) * 8);
        #pragma unroll
        for (int kf = 0; kf < NKF; kf++) {
            int krow = kf * 16 + l15;
            f16x8 kf8 = *(const f16x8*)&Kls[krow * 32 + ((((kh << 2) + l4) ^ (krow & 7)) << 2)];
            acc[kf] = __builtin_amdgcn_mfma_f32_16x16x32_f16(kf8, qh, acc[kf], 0, 0, 0);
        }
    }

    float m = -1e30f;
    #pragma unroll
    for (int kf = 0; kf < NKF; kf++)
        #pragma unroll
        for (int r = 0; r < 4; r++) {
            int key = kf * 16 + l4 * 4 + r;
            float s = acc[kf][r] * 0.125f;
            if (key > qi) s = -1e30f;
            acc[kf][r] = s;
            m = fmaxf(m, s);
        }
    m = fmaxf(m, __shfl_xor(m, 16, 64));
    m = fmaxf(m, __shfl_xor(m, 32, 64));
    float sum = 0.f;
    #pragma unroll
    for (int kf = 0; kf < NKF; kf++)
        #pragma unroll
        for (int r = 0; r < 4; r++) {
            float p = __expf(acc[kf][r] - m);
            acc[kf][r] = p;
            sum += p;
        }
    sum += __shfl_xor(sum, 16, 64);
    sum += __shfl_xor(sum, 32, 64);
    float inv = 1.f / sum;

    #pragma unroll
    for (int kf = 0; kf < NKF; kf++) {
        uint2 pw;
        pw.x = pack_h2(acc[kf][0] * inv, acc[kf][1] * inv);
        pw.y = pack_h2(acc[kf][2] * inv, acc[kf][3] * inv);
        int j = kf * 2 + (l4 >> 1);
        *(uint2*)&Pls[qrow * 128 + ((j ^ (qrow & 15)) << 2) + ((l4 & 1) << 1)] = pw;
    }
    __syncthreads();

    for (int kp = lane; kp < NK / 2; kp += 64) {
        #pragma unroll
        for (int dq = 0; dq < 2; dq++) {
            int db = w + dq * 4;
            uint4 v0 = *(const uint4*)(vbase + (size_t)(2 * kp) * E_ + db * 8);
            uint4 v1 = *(const uint4*)(vbase + (size_t)(2 * kp + 1) * E_ + db * 8);
            u32 uu[8];
            uu[0] = pk_lo(v0.x, v1.x); uu[1] = pk_hi(v0.x, v1.x);
            uu[2] = pk_lo(v0.y, v1.y); uu[3] = pk_hi(v0.y, v1.y);
            uu[4] = pk_lo(v0.z, v1.z); uu[5] = pk_hi(v0.z, v1.z);
            uu[6] = pk_lo(v0.w, v1.w); uu[7] = pk_hi(v0.w, v1.w);
            #pragma unroll
            for (int i = 0; i < 8; i++) {
                int d = db * 8 + i;
                Kls[d * 128 + (((kp >> 2) ^ (d & 15)) << 2) + (kp & 3)] = uu[i];
            }
        }
    }
    __syncthreads();

    f32x4 o2[4];
    #pragma unroll
    for (int df = 0; df < 4; df++) o2[df] = f32x4{0.f, 0.f, 0.f, 0.f};
    #pragma unroll
    for (int ks = 0; ks < NKS; ks++) {
        f16x8 pa = *(const f16x8*)&Pls[qrow * 128 + (((ks * 4 + l4) ^ (qrow & 15)) << 2)];
        #pragma unroll
        for (int df = 0; df < 4; df++) {
            int d = df * 16 + l15;
            f16x8 vb8 = *(const f16x8*)&Kls[d * 128 + (((ks * 4 + l4) ^ (d & 15)) << 2)];
            o2[df] = __builtin_amdgcn_mfma_f32_16x16x32_f16(pa, vb8, o2[df], 0, 0, 0);
        }
    }
    #pragma unroll
    for (int df = 0; df < 4; df++)
        #pragma unroll
        for (int r = 0; r < 4; r++) {
            int qg = q0 + w * 16 + l4 * 4 + r;
            abase[(size_t)qg * E_ + df * 16 + l15] = f2hu(o2[df][r]);
        }
}

__global__ __launch_bounds__(256) void attn_mfma_k(
        const _Float16* __restrict__ q, const _Float16* __restrict__ k,
        const _Float16* __restrict__ v, _Float16* __restrict__ att) {
    __shared__ __align__(16) u32 Kls[256 * 32];   // 32 KB
    __shared__ __align__(16) u32 Pls[64 * 128];   // 32 KB
    int chunk = blockIdx.x & 3;
    int bh = blockIdx.x >> 2;
    int b = bh / H_, h = bh % H_;
    const u16* qbase = (const u16*)q + ((size_t)b * T_) * E_ + h * D_;
    const u16* kbase = (const u16*)k + ((size_t)b * T_) * E_ + h * D_;
    const u16* vbase = (const u16*)v + ((size_t)b * T_) * E_ + h * D_;
    u16* abase = (u16*)att + ((size_t)b * T_) * E_ + h * D_;
    int q0 = chunk * 64;
    switch (chunk) {
        case 0: attn_body< 64>(qbase, kbase, vbase, abase, q0, Kls, Pls); break;
        case 1: attn_body<128>(qbase, kbase, vbase, abase, q0, Kls, Pls); break;
        case 2: attn_body<192>(qbase, kbase, vbase, abase, q0, Kls, Pls); break;
        default: attn_body<256>(qbase, kbase, vbase, abase, q0, Kls, Pls); break;
    }
}

// ---------------- loss tail ----------------
__global__ __launch_bounds__(256) void rowloss2_k(
        const float* __restrict__ logits, const int* __restrict__ tgt,
        float* __restrict__ accum) {
    __shared__ float part[4];
    int w = threadIdx.x >> 6, lane = threadIdx.x & 63;
    float local = 0.f;
    for (int i = 0; i < 16; i++) {
        int row = blockIdx.x * 64 + w * 16 + i;
        const float* lr = logits + (size_t)row * V_;
        float v0 = lr[lane];
        float v64 = (lane == 0) ? lr[64] : -1e30f;
        float m = fmaxf(v0, v64);
        #pragma unroll
        for (int off = 32; off; off >>= 1) m = fmaxf(m, __shfl_xor(m, off, 64));
        float se = __expf(v0 - m) + ((lane == 0) ? __expf(v64 - m) : 0.f);
        #pragma unroll
        for (int off = 32; off; off >>= 1) se += __shfl_xor(se, off, 64);
        if (lane == 0) local += lr[tgt[row]] - m - __logf(se);
    }
    if (lane == 0) part[w] = local;
    __syncthreads();
    if (threadIdx.x == 0)
        atomicAdd(accum, -(part[0] + part[1] + part[2] + part[3]));
}

__global__ void final_k(const float* __restrict__ accum, const int* __restrict__ flag,
                        void* __restrict__ out) {
    if (threadIdx.x == 0) {
        float v = *accum * (1.f / BT);
        if (*flag) ((float*)out)[(size_t)BT * V_] = v;
        else ((__hip_bfloat16*)out)[(size_t)BT * V_] = __float2bfloat16(v);
    }
}

extern "C" void kernel_launch(void* const* d_in, const int* in_sizes, int n_in,
                              void* d_out, int out_size, void* d_ws, size_t ws_size,
                              hipStream_t stream) {
    const int* idx     = (const int*)d_in[0];
    const int* targets = (const int*)d_in[1];
    const void* tok  = d_in[2];
    const void* pos  = d_in[3];
    const void* Wq   = d_in[4];
    const void* Wk   = d_in[5];
    const void* Wv   = d_in[6];
    const void* Wo   = d_in[7];
    const void* bo   = d_in[8];
    const void* W1   = d_in[9];
    const void* b1   = d_in[10];
    const void* W2   = d_in[11];
    const void* b2   = d_in[12];
    const void* ln1g = d_in[13];
    const void* ln1b = d_in[14];
    const void* ln2g = d_in[15];
    const void* ln2b = d_in[16];
    const void* lnfg = d_in[17];
    const void* lnfb = d_in[18];
    const void* Wlm  = d_in[19];
    const void* blm  = d_in[20];

    // ---- workspace layout (~142 MiB of the 268 MB ws) ----
    // logits f32 | xb f16 (residual) | ab f16 | qb | kb | vb | wt 6*WSLOT f16 | wlm |
    // fold arrays f32 | stats f32 (13 sites x BT x 2) | ffnb f16 [BT][F]
    char* wsb = (char*)d_ws;
    int*   flag    = (int*)wsb;
    float* lossacc = (float*)(wsb + 8);
    float* logits  = (float*)(wsb + 256);
    char* p = wsb + 256 + sizeof(float) * (size_t)BT * V_;
    _Float16* xb = (_Float16*)p;                             // f16 residual stream
    _Float16* ab = (_Float16*)(p + 2 * (size_t)XN);          // attn out
    _Float16* qb = (_Float16*)(p + 4 * (size_t)XN);
    _Float16* kb = (_Float16*)(p + 6 * (size_t)XN);
    _Float16* vb = (_Float16*)(p + 8 * (size_t)XN);
    _Float16* wt = (_Float16*)(p + 10 * (size_t)XN);         // 6*WSLOT f16
    _Float16* wlm = wt + 6 * WSLOT;                          // 128*384 f16
    float* csqkv = (float*)(wlm + (size_t)128 * E_);
    float* bbqkv = csqkv + 6 * 3 * E_;
    float* csw1  = bbqkv + 6 * 3 * E_;
    float* bbw1  = csw1 + 6 * (size_t)F_;
    float* cslm  = bbw1 + 6 * (size_t)F_;
    float* bblm  = cslm + 128;
    float* stats = bblm + 128;                               // 13 * BT * 2 f32
    _Float16* ffnb = (_Float16*)(stats + NSTAT);             // [BT][F]

    dim3 grdEm(3, 128);      // Wo / W2: nwg=384
    dim3 grdQKV(9, 128);     // nwg=1152
    dim3 grdW1(12, 128);     // nwg=1536
    dim3 grdLM(1, 128);      // nwg=128

    init_k<<<1, 64, 0, stream>>>(flag, lossacc);
    zstats_k<<<(NSTAT + 255) / 256, 256, 0, stream>>>(stats);
    detect_k<<<(V_ * E_ + 255) / 256, 256, 0, stream>>>(tok, V_ * E_, flag);
    wtrans_all_k<<<2604, 256, 0, stream>>>(Wq, Wk, Wv, Wo, W1, W2, Wlm,
                                           ln1g, ln2g, lnfg, flag, wt);
    fold_k<<<73, 256, 0, stream>>>(Wq, Wk, Wv, W1, Wlm,
                                   ln1g, ln1b, ln2g, ln2b, lnfg, lnfb,
                                   b1, blm, flag,
                                   csqkv, bbqkv, csw1, bbw1, cslm, bblm);
    embed_k<<<BT / 4, 256, 0, stream>>>(idx, tok, pos, flag, xb, stats);

    for (int l = 0; l < L_; l++) {
        const _Float16* wls = wt + (size_t)l * WSLOT;
        float* st1l = stats + (size_t)l * BT * 2;            // ln1 site l
        float* st2l = stats + (size_t)(6 + l) * BT * 2;      // ln2 site l
        float* stnx = (l < 5) ? stats + (size_t)(l + 1) * BT * 2
                              : stats + (size_t)12 * BT * 2; // lnf
        gemm_qkv_k<<<grdQKV, 256, 0, stream>>>(xb, wls,
                csqkv + (size_t)l * 3 * E_, bbqkv + (size_t)l * 3 * E_, st1l,
                qb, kb, vb);
        attn_mfma_k<<<B_ * H_ * 4, 256, 0, stream>>>(qb, kb, vb, ab);
        gemm_resst_k<<<grdEm, 256, 0, stream>>>(ab, wls + 3 * EE, bo, (long long)l * E_,
                                                flag, xb, st2l, E_, E_);
        gemm_w1_k<<<grdW1, 256, 0, stream>>>(xb, wls + 4 * EE,
                csw1 + (size_t)l * F_, bbw1 + (size_t)l * F_, st2l, ffnb);
        gemm_resst_k<<<grdEm, 256, 0, stream>>>(ffnb, wls + 4 * EE + EF, b2, (long long)l * E_,
                                                flag, xb, stnx, E_, F_);
    }

    gemm_lmh_k<<<grdLM, 256, 0, stream>>>(xb, wlm, cslm, bblm,
                                          stats + (size_t)12 * BT * 2, flag, logits, d_out);
    rowloss2_k<<<BT / 64, 256, 0, stream>>>(logits, targets, lossacc);
    final_k<<<1, 64, 0, stream>>>(lossacc, flag, d_out);
}

// Round 16
// 1006.028 us; speedup vs baseline: 6.2888x; 1.0613x over previous
//
#include <hip/hip_runtime.h>
#include <hip/hip_bf16.h>

typedef unsigned short u16;
typedef unsigned int u32;
typedef _Float16 h16x2 __attribute__((ext_vector_type(2)));
typedef _Float16 f16x8 __attribute__((ext_vector_type(8)));
typedef float f32x4 __attribute__((ext_vector_type(4)));

constexpr int B_ = 64, T_ = 256, V_ = 65, E_ = 384, H_ = 6, L_ = 6, D_ = 64, F_ = 1536;
constexpr int BT = B_ * T_;
constexpr int XN = BT * E_;
constexpr long long EE = (long long)E_ * E_;          // 147456
constexpr long long EF = (long long)E_ * F_;          // 589824
constexpr long long WSLOT = 4 * EE + 2 * EF;          // f16 per layer
constexpr int NSTAT = 13 * BT * 2;                    // stats floats
constexpr int NFOLD = 2 * 6 * 3 * E_ + 2 * 6 * F_ + 256;   // 32512 fold floats
constexpr int ZTOT = NFOLD + NSTAT;                   // contiguous zero region

__device__ __forceinline__ float ldw(const void* p, long long i, int f32) {
    return f32 ? ((const float*)p)[i]
               : __bfloat162float(((const __hip_bfloat16*)p)[i]);
}
__device__ __forceinline__ u16 f2hu(float f) { union { _Float16 h; u16 u; } x; x.h = (_Float16)f; return x.u; }
__device__ __forceinline__ u32 pack_h2(float a, float b) {
    union { h16x2 h; u32 u; } x;
    x.h[0] = (_Float16)a; x.h[1] = (_Float16)b;
    return x.u;
}
__device__ __forceinline__ u32 pk_lo(u32 a, u32 b) { return (a & 0xffffu) | (b << 16); }
__device__ __forceinline__ u32 pk_hi(u32 a, u32 b) { return (a >> 16) | (b & 0xffff0000u); }

__global__ void init_k(int* flag, float* lossacc) {
    if (threadIdx.x == 0) { *flag = 0; *lossacc = 0.f; }
}

__global__ void zstats_k(float* zb, int n) {
    int i = blockIdx.x * blockDim.x + threadIdx.x;
    if (i < n) zb[i] = 0.f;
}

__global__ void detect_k(const void* tok, int n, int* flag) {
    int i = blockIdx.x * blockDim.x + threadIdx.x;
    if (i < n) {
        float v = __bfloat162float(((const __hip_bfloat16*)tok)[i]);
        if (!(fabsf(v) < 1e4f)) *flag = 1;
    }
}

// ---------------- weight transposes, LN-gamma folded: Wt[n][k] = g[k]*W[k][n] ----------
__global__ __launch_bounds__(256) void wtrans_all_k(
        const void* __restrict__ Wq, const void* __restrict__ Wk,
        const void* __restrict__ Wv, const void* __restrict__ Wo,
        const void* __restrict__ W1, const void* __restrict__ W2,
        const void* __restrict__ Wlm,
        const void* __restrict__ ln1g, const void* __restrict__ ln2g,
        const void* __restrict__ lnfg,
        const int* __restrict__ flag, _Float16* __restrict__ wt) {
    int f = *flag;
    int b = blockIdx.x;
    __shared__ _Float16 tile[64][65];
    if (b < 2592) {
        int l = b / 432, r = b % 432;
        const void* src; long long soff; _Float16* dst;
        const void* gp = nullptr; long long go = 0;
        int K, N, kt, nt;
        _Float16* wls = wt + (size_t)l * WSLOT;
        if (r < 144) {
            int m = r / 36, t = r % 36;
            src = (m == 0) ? Wq : (m == 1) ? Wk : (m == 2) ? Wv : Wo;
            soff = (long long)l * EE;
            dst = wls + (size_t)m * EE;
            K = E_; N = E_; kt = t / 6; nt = t % 6;
            if (m < 3) { gp = ln1g; go = (long long)l * E_; }
        } else if (r < 288) {
            int t = r - 144;
            src = W1; soff = (long long)l * EF;
            dst = wls + 4 * EE;
            K = E_; N = F_; kt = t / 24; nt = t % 24;
            gp = ln2g; go = (long long)l * E_;
        } else {
            int t = r - 288;
            src = W2; soff = (long long)l * EF;
            dst = wls + 4 * EE + EF;
            K = F_; N = E_; kt = t / 6; nt = t % 6;
        }
        int k0 = kt * 64, n0 = nt * 64;
        #pragma unroll 4
        for (int p = 0; p < 16; p++) {
            int k = p * 4 + (threadIdx.x >> 6), n = threadIdx.x & 63;
            float v = ldw(src, soff + (long long)(k0 + k) * N + n0 + n, f);
            if (gp) v *= ldw(gp, go + k0 + k, f);
            tile[k][n] = (_Float16)v;
        }
        __syncthreads();
        #pragma unroll 4
        for (int p = 0; p < 16; p++) {
            int n = p * 4 + (threadIdx.x >> 6), k = threadIdx.x & 63;
            dst[(size_t)(n0 + n) * K + k0 + k] = tile[k][n];
        }
    } else {
        int t = b - 2592;            // 0..11
        _Float16* wlm = wt + 6 * WSLOT;
        int kt = t / 2, nt = t % 2;
        int k0 = kt * 64, n0 = nt * 64;
        #pragma unroll 4
        for (int p = 0; p < 16; p++) {
            int k = p * 4 + (threadIdx.x >> 6), n = threadIdx.x & 63;
            float v = 0.f;
            if (n0 + n < V_)
                v = ldw(Wlm, (long long)(k0 + k) * V_ + n0 + n, f) *
                    ldw(lnfg, k0 + k, f);
            tile[k][n] = (_Float16)v;
        }
        __syncthreads();
        #pragma unroll 4
        for (int p = 0; p < 16; p++) {
            int n = p * 4 + (threadIdx.x >> 6), k = threadIdx.x & 63;
            wlm[(size_t)(n0 + n) * E_ + k0 + k] = tile[k][n];
        }
    }
}

// ---------------- fold2_k: k-chunked parallel fold with atomic accumulation ----------
// cs[n]=sum_k g[k]W[k][n], bb[n]=sum_k bln[k]W[k][n] (+bias0[n] by kchunk 0).
// Blocks: 0..215 qkv (l,which,nchunk,kchunk); 216..431 W1 (l,nchunk,kchunk); 432..437 lm.
// Each thread: one n, 64 coalesced k-iterations, 2 atomicAdds. Arrays pre-zeroed.
__global__ __launch_bounds__(256) void fold2_k(
        const void* __restrict__ Wq, const void* __restrict__ Wk,
        const void* __restrict__ Wv, const void* __restrict__ W1,
        const void* __restrict__ Wlm,
        const void* __restrict__ ln1g, const void* __restrict__ ln1b,
        const void* __restrict__ ln2g, const void* __restrict__ ln2b,
        const void* __restrict__ lnfg, const void* __restrict__ lnfb,
        const void* __restrict__ b1, const void* __restrict__ blm,
        const int* __restrict__ flag,
        float* __restrict__ csqkv, float* __restrict__ bbqkv,
        float* __restrict__ csw1, float* __restrict__ bbw1,
        float* __restrict__ cslm, float* __restrict__ bblm) {
    int f = *flag;
    int b = blockIdx.x, tid = threadIdx.x;
    float cs = 0.f, bb = 0.f;
    if (b < 216) {
        int l = b / 36, r = b % 36;
        int which = r / 12, rr = r % 12;
        int nchunk = rr / 6, kchunk = rr % 6;
        int n = nchunk * 256 + tid;
        if (n >= E_) return;
        const void* W = (which == 0) ? Wq : (which == 1) ? Wk : Wv;
        long long wo = (long long)l * EE + (long long)kchunk * 64 * E_ + n;
        long long go = (long long)l * E_ + kchunk * 64;
        #pragma unroll 8
        for (int kk = 0; kk < 64; kk++) {
            float wv = ldw(W, wo + (long long)kk * E_, f);
            cs += ldw(ln1g, go + kk, f) * wv;
            bb += ldw(ln1b, go + kk, f) * wv;
        }
        atomicAdd(&csqkv[((size_t)l * 3 + which) * E_ + n], cs);
        atomicAdd(&bbqkv[((size_t)l * 3 + which) * E_ + n], bb);
    } else if (b < 432) {
        int t = b - 216;
        int l = t / 36, r = t % 36;
        int nchunk = r / 6, kchunk = r % 6;
        int n = nchunk * 256 + tid;
        long long wo = (long long)l * EF + (long long)kchunk * 64 * F_ + n;
        long long go = (long long)l * E_ + kchunk * 64;
        #pragma unroll 8
        for (int kk = 0; kk < 64; kk++) {
            float wv = ldw(W1, wo + (long long)kk * F_, f);
            cs += ldw(ln2g, go + kk, f) * wv;
            bb += ldw(ln2b, go + kk, f) * wv;
        }
        if (kchunk == 0) bb += ldw(b1, (long long)l * F_ + n, f);
        atomicAdd(&csw1[(size_t)l * F_ + n], cs);
        atomicAdd(&bbw1[(size_t)l * F_ + n], bb);
    } else {
        int kchunk = b - 432;        // 0..5
        int n = tid;
        if (n >= V_) return;
        long long wo = (long long)kchunk * 64 * V_ + n;
        long long go = kchunk * 64;
        #pragma unroll 8
        for (int kk = 0; kk < 64; kk++) {
            float wv = ldw(Wlm, wo + (long long)kk * V_, f);
            cs += ldw(lnfg, go + kk, f) * wv;
            bb += ldw(lnfb, go + kk, f) * wv;
        }
        if (kchunk == 0) bb += ldw(blm, n, f);
        atomicAdd(&cslm[n], cs);
        atomicAdd(&bblm[n], bb);
    }
}

// ---------------- embedding: wave per row, f16 residual + direct row stats ----------------
__global__ __launch_bounds__(256) void embed_k(
        const int* __restrict__ idx, const void* __restrict__ tok,
        const void* __restrict__ pos, const int* __restrict__ flag,
        _Float16* __restrict__ x, float* __restrict__ st0) {
    int f = *flag;
    int w = threadIdx.x >> 6, lane = threadIdx.x & 63;
    int row = blockIdx.x * 4 + w;
    int t = row % T_;
    long long tb = (long long)idx[row] * E_;
    long long pb = (long long)t * E_;
    u32* orow = (u32*)(x + (size_t)row * E_);
    float s = 0.f, ss = 0.f;
    #pragma unroll
    for (int i = 0; i < 3; i++) {
        int e = (i * 64 + lane) * 2;
        float r0 = ldw(tok, tb + e, f) + ldw(pos, pb + e, f);
        float r1 = ldw(tok, tb + e + 1, f) + ldw(pos, pb + e + 1, f);
        _Float16 h0 = (_Float16)r0, h1 = (_Float16)r1;
        union { h16x2 h; u32 u; } pk; pk.h[0] = h0; pk.h[1] = h1;
        orow[i * 64 + lane] = pk.u;
        float a = (float)h0, c = (float)h1;
        s += a + c; ss += a * a + c * c;
    }
    #pragma unroll
    for (int off = 32; off; off >>= 1) {
        s  += __shfl_down(s,  off, 64);
        ss += __shfl_down(ss, off, 64);
    }
    if (lane == 0) { st0[2 * row] = s; st0[2 * row + 1] = ss; }
}

// ---------------- XCD-aware bijective block swizzle (nwg % 8 == 0) ----------------
__device__ __forceinline__ void xcd_swz(int nx, int& bx, int& by) {
    int ld = blockIdx.y * gridDim.x + blockIdx.x;
    int nwg = gridDim.x * gridDim.y;
    int cpx = nwg >> 3;
    int t = (ld & 7) * cpx + (ld >> 3);
    bx = t % nx;
    by = t / nx;
}

// ---------------- async stage: 128 rows x 64 k (f16) -> 16KB LDS buffer ----------------
__device__ __forceinline__ void stage_lds(const u16* __restrict__ gsrc, int ldK,
                                          u32* lbuf, int wi, int lane) {
    #pragma unroll
    for (int p = 0; p < 4; p++) {
        int i = (wi << 2) + p;
        int S = (i << 6) + lane;
        int r = S >> 3, cs = S & 7;
        const u16* gp = gsrc + (size_t)r * ldK + ((cs ^ (r & 7)) << 3);
        __builtin_amdgcn_global_load_lds(
            (const __attribute__((address_space(1))) u32*)gp,
            (__attribute__((address_space(3))) u32*)(lbuf + (i << 8)),
            16, 0, 0);
    }
}

// ---------------- MFMA GEMM body: 128x128 tile, BK=64, 2-deep counted-vmcnt pipeline ----
template<int CMODE, bool LNF, bool STATS>
__device__ __forceinline__ void gemm_body(
        const _Float16* __restrict__ A,
        const _Float16* __restrict__ Wt,
        const float* __restrict__ csp, const float* __restrict__ bbp,
        const float* __restrict__ stin,
        const void* __restrict__ bias, long long boff, int has_bias, int f,
        void* __restrict__ Cv, void* __restrict__ dout, float* __restrict__ stout,
        int N, int K, int relu, int bx, int by, u32* Af, u32* Wf) {
    const int tid = threadIdx.x;
    const int lane = tid & 63;
    const int wi = tid >> 6;
    const int wr = wi >> 1, wc = wi & 1;
    const int row0 = by << 7, col0 = bx << 7;
    const int l15 = lane & 15, l4 = lane >> 4;

    f32x4 acc[4][4];
    #pragma unroll
    for (int m = 0; m < 4; m++)
        #pragma unroll
        for (int n = 0; n < 4; n++)
            acc[m][n] = f32x4{0.f, 0.f, 0.f, 0.f};

    const u16* Ab = (const u16*)A + (size_t)row0 * K;
    const u16* Wb = (const u16*)Wt + (size_t)col0 * K;

    const int ntile = K >> 6;
    stage_lds(Ab, K, Af, wi, lane);
    stage_lds(Wb, K, Wf, wi, lane);
    if (ntile > 1) {
        stage_lds(Ab + 64, K, Af + (1 << 12), wi, lane);
        stage_lds(Wb + 64, K, Wf + (1 << 12), wi, lane);
    }

    for (int t = 0; t < ntile; t++) {
        const int buf = t & 1;
        if (t + 1 < ntile) asm volatile("s_waitcnt vmcnt(8)" ::: "memory");
        else               asm volatile("s_waitcnt vmcnt(0)" ::: "memory");
        __builtin_amdgcn_s_barrier();
        __builtin_amdgcn_sched_barrier(0);
        __builtin_amdgcn_s_setprio(1);
        #pragma unroll
        for (int kh = 0; kh < 2; kh++) {
            f16x8 a4[4], w4[4];
            int s = (kh << 2) + l4;
            #pragma unroll
            for (int m = 0; m < 4; m++) {
                int r = (wr << 6) + (m << 4) + l15;
                a4[m] = *(const f16x8*)&Af[(buf << 12) + r * 32 + ((s ^ (r & 7)) << 2)];
            }
            #pragma unroll
            for (int n = 0; n < 4; n++) {
                int c = (wc << 6) + (n << 4) + l15;
                w4[n] = *(const f16x8*)&Wf[(buf << 12) + c * 32 + ((s ^ (c & 7)) << 2)];
            }
            #pragma unroll
            for (int m = 0; m < 4; m++)
                #pragma unroll
                for (int n = 0; n < 4; n++)
                    acc[m][n] = __builtin_amdgcn_mfma_f32_16x16x32_f16(a4[m], w4[n], acc[m][n], 0, 0, 0);
        }
        __builtin_amdgcn_s_setprio(0);
        __builtin_amdgcn_sched_barrier(0);
        __builtin_amdgcn_s_barrier();
        if (t + 2 < ntile) {
            stage_lds(Ab + ((t + 2) << 6), K, Af + (buf << 12), wi, lane);
            stage_lds(Wb + ((t + 2) << 6), K, Wf + (buf << 12), wi, lane);
        }
    }

    // ---- epilogue ----
    float c0[4], c1[4];
    #pragma unroll
    for (int n = 0; n < 4; n++) {
        int col = col0 + (wc << 6) + (n << 4) + l15;
        if (LNF) { c0[n] = csp[col]; c1[n] = bbp[col]; }
        else     { c0[n] = 0.f;
                   c1[n] = (has_bias && (CMODE != 2 || col < N)) ? ldw(bias, boff + col, f) : 0.f; }
    }
    #pragma unroll
    for (int m = 0; m < 4; m++) {
        #pragma unroll
        for (int i = 0; i < 4; i++) {
            int row = row0 + (wr << 6) + (m << 4) + (l4 << 2) + i;
            float mu = 0.f, rs = 1.f;
            if (LNF) {
                float sv = stin[2 * row], ssv = stin[2 * row + 1];
                mu = sv * (1.f / E_);
                rs = rsqrtf(ssv * (1.f / E_) - mu * mu + 1e-5f);
            }
            float ps = 0.f, pss = 0.f;
            #pragma unroll
            for (int n = 0; n < 4; n++) {
                int col = col0 + (wc << 6) + (n << 4) + l15;
                if (CMODE == 2 && col >= N) continue;
                float r = LNF ? rs * (acc[m][n][i] - mu * c0[n]) + c1[n]
                              : acc[m][n][i] + c1[n];
                size_t o = (size_t)row * N + col;
                if (CMODE == 0) {
                    if (relu) r = fmaxf(r, 0.f);
                    ((_Float16*)Cv)[o] = (_Float16)r;
                } else if (CMODE == 1) {
                    _Float16* C = (_Float16*)Cv;
                    r += (float)C[o];
                    _Float16 hv = (_Float16)r;
                    C[o] = hv;
                    if (STATS) { float xv = (float)hv; ps += xv; pss += xv * xv; }
                } else {
                    ((float*)Cv)[o] = r;
                    if (f) ((float*)dout)[o] = r;
                    else ((__hip_bfloat16*)dout)[o] = __float2bfloat16(r);
                }
            }
            if (STATS) {
                #pragma unroll
                for (int off = 1; off < 16; off <<= 1) {
                    ps  += __shfl_xor(ps,  off, 64);
                    pss += __shfl_xor(pss, off, 64);
                }
                if (l15 == 0) {
                    atomicAdd(&stout[2 * row], ps);
                    atomicAdd(&stout[2 * row + 1], pss);
                }
            }
        }
    }
}

// fused Q/K/V with ln1 fold: grid (9, 128)
__global__ __launch_bounds__(256, 2) void gemm_qkv_k(
        const _Float16* __restrict__ A, const _Float16* __restrict__ wls,
        const float* __restrict__ csL, const float* __restrict__ bbL,
        const float* __restrict__ stin,
        _Float16* __restrict__ qb, _Float16* __restrict__ kb, _Float16* __restrict__ vb) {
    __shared__ __align__(16) u32 Af[8192];
    __shared__ __align__(16) u32 Wf[8192];
    int sx, by;
    xcd_swz(9, sx, by);
    int which = sx / 3, bx = sx % 3;
    _Float16* C = (which == 0) ? qb : (which == 1) ? kb : vb;
    gemm_body<0, true, false>(A, wls + (size_t)which * EE,
                              csL + (size_t)which * E_, bbL + (size_t)which * E_, stin,
                              nullptr, 0, 0, 0, C, nullptr, nullptr,
                              E_, E_, 0, bx, by, Af, Wf);
}

// W1 with ln2 fold + relu: grid (12, 128)
__global__ __launch_bounds__(256, 2) void gemm_w1_k(
        const _Float16* __restrict__ A, const _Float16* __restrict__ Wt,
        const float* __restrict__ cs, const float* __restrict__ bb,
        const float* __restrict__ stin, _Float16* __restrict__ C) {
    __shared__ __align__(16) u32 Af[8192];
    __shared__ __align__(16) u32 Wf[8192];
    int bx, by;
    xcd_swz(gridDim.x, bx, by);
    gemm_body<0, true, false>(A, Wt, cs, bb, stin, nullptr, 0, 0, 0,
                              C, nullptr, nullptr, F_, E_, 1, bx, by, Af, Wf);
}

// residual writer (Wo/W2): f16 RMW + row-stats accumulation for the next LN site
__global__ __launch_bounds__(256, 2) void gemm_resst_k(
        const _Float16* __restrict__ A, const _Float16* __restrict__ Wt,
        const void* __restrict__ bias, long long boff, const int* __restrict__ flag,
        _Float16* __restrict__ C, float* __restrict__ stout, int N, int K) {
    __shared__ __align__(16) u32 Af[8192];
    __shared__ __align__(16) u32 Wf[8192];
    int bx, by;
    xcd_swz(gridDim.x, bx, by);
    gemm_body<1, false, true>(A, Wt, nullptr, nullptr, nullptr, bias, boff, 1, *flag,
                              C, nullptr, stout, N, K, 0, bx, by, Af, Wf);
}

// lm head with lnf fold; writes logits f32 AND d_out. grid (1, 128).
__global__ __launch_bounds__(256, 2) void gemm_lmh_k(
        const _Float16* __restrict__ A, const _Float16* __restrict__ Wt,
        const float* __restrict__ cs, const float* __restrict__ bb,
        const float* __restrict__ stin, const int* __restrict__ flag,
        float* __restrict__ logits, void* __restrict__ dout) {
    __shared__ __align__(16) u32 Af[8192];
    __shared__ __align__(16) u32 Wf[8192];
    int bx, by;
    xcd_swz(1, bx, by);
    gemm_body<2, true, false>(A, Wt, cs, bb, stin, nullptr, 0, 0, *flag,
                              logits, dout, nullptr, V_, E_, 0, bx, by, Af, Wf);
}

// ---------------- MFMA attention, f16 I/O (verbatim) ----------------
template<int NK>
__device__ __forceinline__ void attn_body(
        const u16* __restrict__ qbase, const u16* __restrict__ kbase,
        const u16* __restrict__ vbase, u16* __restrict__ abase,
        int q0, u32* Kls, u32* Pls) {
    constexpr int NKF = NK / 16;
    constexpr int NKS = NK / 32;
    const int tid = threadIdx.x;
    const int lane = tid & 63;
    const int w = tid >> 6;
    const int l15 = lane & 15, l4 = lane >> 4;

    {
        int r8 = tid >> 3, slot = tid & 7;
        #pragma unroll
        for (int p = 0; p < NK / 32; p++) {
            int key = r8 + p * 32;
            uint4 a8 = *(const uint4*)(kbase + (size_t)key * E_ + slot * 8);
            *(uint4*)&Kls[key * 32 + ((slot ^ (key & 7)) << 2)] = a8;
        }
    }
    __syncthreads();

    const int qrow = w * 16 + l15;
    const int qi = q0 + qrow;
    f32x4 acc[NKF];
    #pragma unroll
    for (int kf = 0; kf < NKF; kf++) acc[kf] = f32x4{0.f, 0.f, 0.f, 0.f};

    #pragma unroll
    for (int kh = 0; kh < 2; kh++) {
        f16x8 qh = *(const f16x8*)(qbase + (size_t)qi * E_ + ((kh << 2) + l4) * 8);
        #pragma unroll
        for (int kf = 0; kf < NKF; kf++) {
            int krow = kf * 16 + l15;
            f16x8 kf8 = *(const f16x8*)&Kls[krow * 32 + ((((kh << 2) + l4) ^ (krow & 7)) << 2)];
            acc[kf] = __builtin_amdgcn_mfma_f32_16x16x32_f16(kf8, qh, acc[kf], 0, 0, 0);
        }
    }

    float m = -1e30f;
    #pragma unroll
    for (int kf = 0; kf < NKF; kf++)
        #pragma unroll
        for (int r = 0; r < 4; r++) {
            int key = kf * 16 + l4 * 4 + r;
            float s = acc[kf][r] * 0.125f;
            if (key > qi) s = -1e30f;
            acc[kf][r] = s;
            m = fmaxf(m, s);
        }
    m = fmaxf(m, __shfl_xor(m, 16, 64));
    m = fmaxf(m, __shfl_xor(m, 32, 64));
    float sum = 0.f;
    #pragma unroll
    for (int kf = 0; kf < NKF; kf++)
        #pragma unroll
        for (int r = 0; r < 4; r++) {
            float p = __expf(acc[kf][r] - m);
            acc[kf][r] = p;
            sum += p;
        }
    sum += __shfl_xor(sum, 16, 64);
    sum += __shfl_xor(sum, 32, 64);
    float inv = 1.f / sum;

    #pragma unroll
    for (int kf = 0; kf < NKF; kf++) {
        uint2 pw;
        pw.x = pack_h2(acc[kf][0] * inv, acc[kf][1] * inv);
        pw.y = pack_h2(acc[kf][2] * inv, acc[kf][3] * inv);
        int j = kf * 2 + (l4 >> 1);
        *(uint2*)&Pls[qrow * 128 + ((j ^ (qrow & 15)) << 2) + ((l4 & 1) << 1)] = pw;
    }
    __syncthreads();

    for (int kp = lane; kp < NK / 2; kp += 64) {
        #pragma unroll
        for (int dq = 0; dq < 2; dq++) {
            int db = w + dq * 4;
            uint4 v0 = *(const uint4*)(vbase + (size_t)(2 * kp) * E_ + db * 8);
            uint4 v1 = *(const uint4*)(vbase + (size_t)(2 * kp + 1) * E_ + db * 8);
            u32 uu[8];
            uu[0] = pk_lo(v0.x, v1.x); uu[1] = pk_hi(v0.x, v1.x);
            uu[2] = pk_lo(v0.y, v1.y); uu[3] = pk_hi(v0.y, v1.y);
            uu[4] = pk_lo(v0.z, v1.z); uu[5] = pk_hi(v0.z, v1.z);
            uu[6] = pk_lo(v0.w, v1.w); uu[7] = pk_hi(v0.w, v1.w);
            #pragma unroll
            for (int i = 0; i < 8; i++) {
                int d = db * 8 + i;
                Kls[d * 128 + (((kp >> 2) ^ (d & 15)) << 2) + (kp & 3)] = uu[i];
            }
        }
    }
    __syncthreads();

    f32x4 o2[4];
    #pragma unroll
    for (int df = 0; df < 4; df++) o2[df] = f32x4{0.f, 0.f, 0.f, 0.f};
    #pragma unroll
    for (int ks = 0; ks < NKS; ks++) {
        f16x8 pa = *(const f16x8*)&Pls[qrow * 128 + (((ks * 4 + l4) ^ (qrow & 15)) << 2)];
        #pragma unroll
        for (int df = 0; df < 4; df++) {
            int d = df * 16 + l15;
            f16x8 vb8 = *(const f16x8*)&Kls[d * 128 + (((ks * 4 + l4) ^ (d & 15)) << 2)];
            o2[df] = __builtin_amdgcn_mfma_f32_16x16x32_f16(pa, vb8, o2[df], 0, 0, 0);
        }
    }
    #pragma unroll
    for (int df = 0; df < 4; df++)
        #pragma unroll
        for (int r = 0; r < 4; r++) {
            int qg = q0 + w * 16 + l4 * 4 + r;
            abase[(size_t)qg * E_ + df * 16 + l15] = f2hu(o2[df][r]);
        }
}

__global__ __launch_bounds__(256) void attn_mfma_k(
        const _Float16* __restrict__ q, const _Float16* __restrict__ k,
        const _Float16* __restrict__ v, _Float16* __restrict__ att) {
    __shared__ __align__(16) u32 Kls[256 * 32];   // 32 KB
    __shared__ __align__(16) u32 Pls[64 * 128];   // 32 KB
    int chunk = blockIdx.x & 3;
    int bh = blockIdx.x >> 2;
    int b = bh / H_, h = bh % H_;
    const u16* qbase = (const u16*)q + ((size_t)b * T_) * E_ + h * D_;
    const u16* kbase = (const u16*)k + ((size_t)b * T_) * E_ + h * D_;
    const u16* vbase = (const u16*)v + ((size_t)b * T_) * E_ + h * D_;
    u16* abase = (u16*)att + ((size_t)b * T_) * E_ + h * D_;
    int q0 = chunk * 64;
    switch (chunk) {
        case 0: attn_body< 64>(qbase, kbase, vbase, abase, q0, Kls, Pls); break;
        case 1: attn_body<128>(qbase, kbase, vbase, abase, q0, Kls, Pls); break;
        case 2: attn_body<192>(qbase, kbase, vbase, abase, q0, Kls, Pls); break;
        default: attn_body<256>(qbase, kbase, vbase, abase, q0, Kls, Pls); break;
    }
}

// ---------------- loss tail ----------------
__global__ __launch_bounds__(256) void rowloss2_k(
        const float* __restrict__ logits, const int* __restrict__ tgt,
        float* __restrict__ accum) {
    __shared__ float part[4];
    int w = threadIdx.x >> 6, lane = threadIdx.x & 63;
    float local = 0.f;
    for (int i = 0; i < 16; i++) {
        int row = blockIdx.x * 64 + w * 16 + i;
        const float* lr = logits + (size_t)row * V_;
        float v0 = lr[lane];
        float v64 = (lane == 0) ? lr[64] : -1e30f;
        float m = fmaxf(v0, v64);
        #pragma unroll
        for (int off = 32; off; off >>= 1) m = fmaxf(m, __shfl_xor(m, off, 64));
        float se = __expf(v0 - m) + ((lane == 0) ? __expf(v64 - m) : 0.f);
        #pragma unroll
        for (int off = 32; off; off >>= 1) se += __shfl_xor(se, off, 64);
        if (lane == 0) local += lr[tgt[row]] - m - __logf(se);
    }
    if (lane == 0) part[w] = local;
    __syncthreads();
    if (threadIdx.x == 0)
        atomicAdd(accum, -(part[0] + part[1] + part[2] + part[3]));
}

__global__ void final_k(const float* __restrict__ accum, const int* __restrict__ flag,
                        void* __restrict__ out) {
    if (threadIdx.x == 0) {
        float v = *accum * (1.f / BT);
        if (*flag) ((float*)out)[(size_t)BT * V_] = v;
        else ((__hip_bfloat16*)out)[(size_t)BT * V_] = __float2bfloat16(v);
    }
}

extern "C" void kernel_launch(void* const* d_in, const int* in_sizes, int n_in,
                              void* d_out, int out_size, void* d_ws, size_t ws_size,
                              hipStream_t stream) {
    const int* idx     = (const int*)d_in[0];
    const int* targets = (const int*)d_in[1];
    const void* tok  = d_in[2];
    const void* pos  = d_in[3];
    const void* Wq   = d_in[4];
    const void* Wk   = d_in[5];
    const void* Wv   = d_in[6];
    const void* Wo   = d_in[7];
    const void* bo   = d_in[8];
    const void* W1   = d_in[9];
    const void* b1   = d_in[10];
    const void* W2   = d_in[11];
    const void* b2   = d_in[12];
    const void* ln1g = d_in[13];
    const void* ln1b = d_in[14];
    const void* ln2g = d_in[15];
    const void* ln2b = d_in[16];
    const void* lnfg = d_in[17];
    const void* lnfb = d_in[18];
    const void* Wlm  = d_in[19];
    const void* blm  = d_in[20];

    // ---- workspace layout (~142 MiB of the 268 MB ws) ----
    // logits f32 | xb f16 (residual) | ab | qb | kb | vb | wt 6*WSLOT f16 | wlm |
    // fold arrays f32 (contiguous) | stats f32 (13 x BT x 2) | ffnb f16 [BT][F]
    char* wsb = (char*)d_ws;
    int*   flag    = (int*)wsb;
    float* lossacc = (float*)(wsb + 8);
    float* logits  = (float*)(wsb + 256);
    char* p = wsb + 256 + sizeof(float) * (size_t)BT * V_;
    _Float16* xb = (_Float16*)p;                             // f16 residual stream
    _Float16* ab = (_Float16*)(p + 2 * (size_t)XN);          // attn out
    _Float16* qb = (_Float16*)(p + 4 * (size_t)XN);
    _Float16* kb = (_Float16*)(p + 6 * (size_t)XN);
    _Float16* vb = (_Float16*)(p + 8 * (size_t)XN);
    _Float16* wt = (_Float16*)(p + 10 * (size_t)XN);         // 6*WSLOT f16
    _Float16* wlm = wt + 6 * WSLOT;                          // 128*384 f16
    float* csqkv = (float*)(wlm + (size_t)128 * E_);
    float* bbqkv = csqkv + 6 * 3 * E_;
    float* csw1  = bbqkv + 6 * 3 * E_;
    float* bbw1  = csw1 + 6 * (size_t)F_;
    float* cslm  = bbw1 + 6 * (size_t)F_;
    float* bblm  = cslm + 128;
    float* stats = bblm + 128;                               // 13 * BT * 2 f32
    _Float16* ffnb = (_Float16*)(stats + NSTAT);             // [BT][F]

    dim3 grdEm(3, 128);      // Wo / W2: nwg=384
    dim3 grdQKV(9, 128);     // nwg=1152
    dim3 grdW1(12, 128);     // nwg=1536
    dim3 grdLM(1, 128);      // nwg=128

    init_k<<<1, 64, 0, stream>>>(flag, lossacc);
    zstats_k<<<(ZTOT + 255) / 256, 256, 0, stream>>>(csqkv, ZTOT);
    detect_k<<<(V_ * E_ + 255) / 256, 256, 0, stream>>>(tok, V_ * E_, flag);
    wtrans_all_k<<<2604, 256, 0, stream>>>(Wq, Wk, Wv, Wo, W1, W2, Wlm,
                                           ln1g, ln2g, lnfg, flag, wt);
    fold2_k<<<438, 256, 0, stream>>>(Wq, Wk, Wv, W1, Wlm,
                                     ln1g, ln1b, ln2g, ln2b, lnfg, lnfb,
                                     b1, blm, flag,
                                     csqkv, bbqkv, csw1, bbw1, cslm, bblm);
    embed_k<<<BT / 4, 256, 0, stream>>>(idx, tok, pos, flag, xb, stats);

    for (int l = 0; l < L_; l++) {
        const _Float16* wls = wt + (size_t)l * WSLOT;
        float* st1l = stats + (size_t)l * BT * 2;            // ln1 site l
        float* st2l = stats + (size_t)(6 + l) * BT * 2;      // ln2 site l
        float* stnx = (l < 5) ? stats + (size_t)(l + 1) * BT * 2
                              : stats + (size_t)12 * BT * 2; // lnf
        gemm_qkv_k<<<grdQKV, 256, 0, stream>>>(xb, wls,
                csqkv + (size_t)l * 3 * E_, bbqkv + (size_t)l * 3 * E_, st1l,
                qb, kb, vb);
        attn_mfma_k<<<B_ * H_ * 4, 256, 0, stream>>>(qb, kb, vb, ab);
        gemm_resst_k<<<grdEm, 256, 0, stream>>>(ab, wls + 3 * EE, bo, (long long)l * E_,
                                                flag, xb, st2l, E_, E_);
        gemm_w1_k<<<grdW1, 256, 0, stream>>>(xb, wls + 4 * EE,
                csw1 + (size_t)l * F_, bbw1 + (size_t)l * F_, st2l, ffnb);
        gemm_resst_k<<<grdEm, 256, 0, stream>>>(ffnb, wls + 4 * EE + EF, b2, (long long)l * E_,
                                                flag, xb, stnx, E_, F_);
    }

    gemm_lmh_k<<<grdLM, 256, 0, stream>>>(xb, wlm, cslm, bblm,
                                          stats + (size_t)12 * BT * 2, flag, logits, d_out);
    rowloss2_k<<<BT / 64, 256, 0, stream>>>(logits, targets, lossacc);
    final_k<<<1, 64, 0, stream>>>(lossacc, flag, d_out);
}

// Round 18
// 932.529 us; speedup vs baseline: 6.7845x; 1.0788x over previous
//
#include <hip/hip_runtime.h>
#include <hip/hip_bf16.h>

typedef unsigned short u16;
typedef unsigned int u32;
typedef _Float16 h16x2 __attribute__((ext_vector_type(2)));
typedef _Float16 f16x8 __attribute__((ext_vector_type(8)));
typedef float f32x4 __attribute__((ext_vector_type(4)));

constexpr int B_ = 64, T_ = 256, V_ = 65, E_ = 384, H_ = 6, L_ = 6, D_ = 64, F_ = 1536;
constexpr int BT = B_ * T_;
constexpr int XN = BT * E_;
constexpr long long EE = (long long)E_ * E_;          // 147456
constexpr long long EF = (long long)E_ * F_;          // 589824
constexpr long long WSLOT = 4 * EE + 2 * EF;          // f16 per layer
constexpr int NSTAT = 13 * BT * 2;                    // stats floats
constexpr int NFOLD = 2 * 6 * 3 * E_ + 2 * 6 * F_ + 256;   // 32512 fold floats
constexpr int ZTOT = NFOLD + NSTAT;                   // contiguous zero region

__device__ __forceinline__ float ldw(const void* p, long long i, int f32) {
    return f32 ? ((const float*)p)[i]
               : __bfloat162float(((const __hip_bfloat16*)p)[i]);
}
__device__ __forceinline__ u16 f2hu(float f) { union { _Float16 h; u16 u; } x; x.h = (_Float16)f; return x.u; }
__device__ __forceinline__ u32 pack_h2(float a, float b) {
    union { h16x2 h; u32 u; } x;
    x.h[0] = (_Float16)a; x.h[1] = (_Float16)b;
    return x.u;
}
__device__ __forceinline__ u32 pk_lo(u32 a, u32 b) { return (a & 0xffffu) | (b << 16); }
__device__ __forceinline__ u32 pk_hi(u32 a, u32 b) { return (a >> 16) | (b & 0xffff0000u); }

__global__ void init_k(int* flag, float* lossacc) {
    if (threadIdx.x == 0) { *flag = 0; *lossacc = 0.f; }
}

__global__ void zstats_k(float* zb, int n) {
    int i = blockIdx.x * blockDim.x + threadIdx.x;
    if (i < n) zb[i] = 0.f;
}

__global__ void detect_k(const void* tok, int n, int* flag) {
    int i = blockIdx.x * blockDim.x + threadIdx.x;
    if (i < n) {
        float v = __bfloat162float(((const __hip_bfloat16*)tok)[i]);
        if (!(fabsf(v) < 1e4f)) *flag = 1;
    }
}

// ---------------- weight transposes, LN-gamma folded: Wt[n][k] = g[k]*W[k][n] ----------
__global__ __launch_bounds__(256) void wtrans_all_k(
        const void* __restrict__ Wq, const void* __restrict__ Wk,
        const void* __restrict__ Wv, const void* __restrict__ Wo,
        const void* __restrict__ W1, const void* __restrict__ W2,
        const void* __restrict__ Wlm,
        const void* __restrict__ ln1g, const void* __restrict__ ln2g,
        const void* __restrict__ lnfg,
        const int* __restrict__ flag, _Float16* __restrict__ wt) {
    int f = *flag;
    int b = blockIdx.x;
    __shared__ _Float16 tile[64][65];
    if (b < 2592) {
        int l = b / 432, r = b % 432;
        const void* src; long long soff; _Float16* dst;
        const void* gp = nullptr; long long go = 0;
        int K, N, kt, nt;
        _Float16* wls = wt + (size_t)l * WSLOT;
        if (r < 144) {
            int m = r / 36, t = r % 36;
            src = (m == 0) ? Wq : (m == 1) ? Wk : (m == 2) ? Wv : Wo;
            soff = (long long)l * EE;
            dst = wls + (size_t)m * EE;
            K = E_; N = E_; kt = t / 6; nt = t % 6;
            if (m < 3) { gp = ln1g; go = (long long)l * E_; }
        } else if (r < 288) {
            int t = r - 144;
            src = W1; soff = (long long)l * EF;
            dst = wls + 4 * EE;
            K = E_; N = F_; kt = t / 24; nt = t % 24;
            gp = ln2g; go = (long long)l * E_;
        } else {
            int t = r - 288;
            src = W2; soff = (long long)l * EF;
            dst = wls + 4 * EE + EF;
            K = F_; N = E_; kt = t / 6; nt = t % 6;
        }
        int k0 = kt * 64, n0 = nt * 64;
        #pragma unroll 4
        for (int p = 0; p < 16; p++) {
            int k = p * 4 + (threadIdx.x >> 6), n = threadIdx.x & 63;
            float v = ldw(src, soff + (long long)(k0 + k) * N + n0 + n, f);
            if (gp) v *= ldw(gp, go + k0 + k, f);
            tile[k][n] = (_Float16)v;
        }
        __syncthreads();
        #pragma unroll 4
        for (int p = 0; p < 16; p++) {
            int n = p * 4 + (threadIdx.x >> 6), k = threadIdx.x & 63;
            dst[(size_t)(n0 + n) * K + k0 + k] = tile[k][n];
        }
    } else {
        int t = b - 2592;            // 0..11
        _Float16* wlm = wt + 6 * WSLOT;
        int kt = t / 2, nt = t % 2;
        int k0 = kt * 64, n0 = nt * 64;
        #pragma unroll 4
        for (int p = 0; p < 16; p++) {
            int k = p * 4 + (threadIdx.x >> 6), n = threadIdx.x & 63;
            float v = 0.f;
            if (n0 + n < V_)
                v = ldw(Wlm, (long long)(k0 + k) * V_ + n0 + n, f) *
                    ldw(lnfg, k0 + k, f);
            tile[k][n] = (_Float16)v;
        }
        __syncthreads();
        #pragma unroll 4
        for (int p = 0; p < 16; p++) {
            int n = p * 4 + (threadIdx.x >> 6), k = threadIdx.x & 63;
            wlm[(size_t)(n0 + n) * E_ + k0 + k] = tile[k][n];
        }
    }
}

// ---------------- fold2_k: k-chunked parallel fold with atomic accumulation ----------
__global__ __launch_bounds__(256) void fold2_k(
        const void* __restrict__ Wq, const void* __restrict__ Wk,
        const void* __restrict__ Wv, const void* __restrict__ W1,
        const void* __restrict__ Wlm,
        const void* __restrict__ ln1g, const void* __restrict__ ln1b,
        const void* __restrict__ ln2g, const void* __restrict__ ln2b,
        const void* __restrict__ lnfg, const void* __restrict__ lnfb,
        const void* __restrict__ b1, const void* __restrict__ blm,
        const int* __restrict__ flag,
        float* __restrict__ csqkv, float* __restrict__ bbqkv,
        float* __restrict__ csw1, float* __restrict__ bbw1,
        float* __restrict__ cslm, float* __restrict__ bblm) {
    int f = *flag;
    int b = blockIdx.x, tid = threadIdx.x;
    float cs = 0.f, bb = 0.f;
    if (b < 216) {
        int l = b / 36, r = b % 36;
        int which = r / 12, rr = r % 12;
        int nchunk = rr / 6, kchunk = rr % 6;
        int n = nchunk * 256 + tid;
        if (n >= E_) return;
        const void* W = (which == 0) ? Wq : (which == 1) ? Wk : Wv;
        long long wo = (long long)l * EE + (long long)kchunk * 64 * E_ + n;
        long long go = (long long)l * E_ + kchunk * 64;
        #pragma unroll 8
        for (int kk = 0; kk < 64; kk++) {
            float wv = ldw(W, wo + (long long)kk * E_, f);
            cs += ldw(ln1g, go + kk, f) * wv;
            bb += ldw(ln1b, go + kk, f) * wv;
        }
        atomicAdd(&csqkv[((size_t)l * 3 + which) * E_ + n], cs);
        atomicAdd(&bbqkv[((size_t)l * 3 + which) * E_ + n], bb);
    } else if (b < 432) {
        int t = b - 216;
        int l = t / 36, r = t % 36;
        int nchunk = r / 6, kchunk = r % 6;
        int n = nchunk * 256 + tid;
        long long wo = (long long)l * EF + (long long)kchunk * 64 * F_ + n;
        long long go = (long long)l * E_ + kchunk * 64;
        #pragma unroll 8
        for (int kk = 0; kk < 64; kk++) {
            float wv = ldw(W1, wo + (long long)kk * F_, f);
            cs += ldw(ln2g, go + kk, f) * wv;
            bb += ldw(ln2b, go + kk, f) * wv;
        }
        if (kchunk == 0) bb += ldw(b1, (long long)l * F_ + n, f);
        atomicAdd(&csw1[(size_t)l * F_ + n], cs);
        atomicAdd(&bbw1[(size_t)l * F_ + n], bb);
    } else {
        int kchunk = b - 432;        // 0..5
        int n = tid;
        if (n >= V_) return;
        long long wo = (long long)kchunk * 64 * V_ + n;
        long long go = kchunk * 64;
        #pragma unroll 8
        for (int kk = 0; kk < 64; kk++) {
            float wv = ldw(Wlm, wo + (long long)kk * V_, f);
            cs += ldw(lnfg, go + kk, f) * wv;
            bb += ldw(lnfb, go + kk, f) * wv;
        }
        if (kchunk == 0) bb += ldw(blm, n, f);
        atomicAdd(&cslm[n], cs);
        atomicAdd(&bblm[n], bb);
    }
}

// ---------------- embedding: wave per row, f16 residual + direct row stats ----------------
__global__ __launch_bounds__(256) void embed_k(
        const int* __restrict__ idx, const void* __restrict__ tok,
        const void* __restrict__ pos, const int* __restrict__ flag,
        _Float16* __restrict__ x, float* __restrict__ st0) {
    int f = *flag;
    int w = threadIdx.x >> 6, lane = threadIdx.x & 63;
    int row = blockIdx.x * 4 + w;
    int t = row % T_;
    long long tb = (long long)idx[row] * E_;
    long long pb = (long long)t * E_;
    u32* orow = (u32*)(x + (size_t)row * E_);
    float s = 0.f, ss = 0.f;
    #pragma unroll
    for (int i = 0; i < 3; i++) {
        int e = (i * 64 + lane) * 2;
        float r0 = ldw(tok, tb + e, f) + ldw(pos, pb + e, f);
        float r1 = ldw(tok, tb + e + 1, f) + ldw(pos, pb + e + 1, f);
        _Float16 h0 = (_Float16)r0, h1 = (_Float16)r1;
        union { h16x2 h; u32 u; } pk; pk.h[0] = h0; pk.h[1] = h1;
        orow[i * 64 + lane] = pk.u;
        float a = (float)h0, c = (float)h1;
        s += a + c; ss += a * a + c * c;
    }
    #pragma unroll
    for (int off = 32; off; off >>= 1) {
        s  += __shfl_down(s,  off, 64);
        ss += __shfl_down(ss, off, 64);
    }
    if (lane == 0) { st0[2 * row] = s; st0[2 * row + 1] = ss; }
}

// ---------------- XCD-aware bijective block swizzle (nwg % 8 == 0) ----------------
__device__ __forceinline__ void xcd_swz(int nx, int& bx, int& by) {
    int ld = blockIdx.y * gridDim.x + blockIdx.x;
    int nwg = gridDim.x * gridDim.y;
    int cpx = nwg >> 3;
    int t = (ld & 7) * cpx + (ld >> 3);
    bx = t % nx;
    by = t / nx;
}

// ---------------- async stage: NI insts/wave, NI*32 rows x 64 k (f16) -> LDS ----------
template<int NI>
__device__ __forceinline__ void stage_lds(const u16* __restrict__ gsrc, int ldK,
                                          u32* lbuf, int wi, int lane) {
    #pragma unroll
    for (int p = 0; p < NI; p++) {
        int i = wi * NI + p;
        int S = (i << 6) + lane;
        int r = S >> 3, cs = S & 7;
        const u16* gp = gsrc + (size_t)r * ldK + ((cs ^ (r & 7)) << 3);
        __builtin_amdgcn_global_load_lds(
            (const __attribute__((address_space(1))) u32*)gp,
            (__attribute__((address_space(3))) u32*)(lbuf + (i << 8)),
            16, 0, 0);
    }
}

// ---------------- MFMA GEMM body: MTx128 tile, BK=64, 2-deep counted-vmcnt pipeline ----
// MT = 128 (4 waves x 64x64 quadrants) or 64 (4 waves x 32x64 quadrants).
// Steady-state vmcnt = per-tile insts = MT/32 + 4 (oldest tile drained, next in flight).
template<int CMODE, bool LNF, bool STATS, int MT>
__device__ __forceinline__ void gemm_body(
        const _Float16* __restrict__ A,
        const _Float16* __restrict__ Wt,
        const float* __restrict__ csp, const float* __restrict__ bbp,
        const float* __restrict__ stin,
        const void* __restrict__ bias, long long boff, int has_bias, int f,
        void* __restrict__ Cv, void* __restrict__ dout, float* __restrict__ stout,
        int N, int K, int relu, int bx, int by, u32* Af, u32* Wf) {
    constexpr int MFR = MT / 32;          // m-fragments per wave (4 or 2)
    constexpr int ASTR = MT * 32;         // A buffer stride in u32
    const int tid = threadIdx.x;
    const int lane = tid & 63;
    const int wi = tid >> 6;
    const int wr = wi >> 1, wc = wi & 1;
    const int row0 = by * MT, col0 = bx << 7;
    const int l15 = lane & 15, l4 = lane >> 4;

    f32x4 acc[MFR][4];
    #pragma unroll
    for (int m = 0; m < MFR; m++)
        #pragma unroll
        for (int n = 0; n < 4; n++)
            acc[m][n] = f32x4{0.f, 0.f, 0.f, 0.f};

    const u16* Ab = (const u16*)A + (size_t)row0 * K;
    const u16* Wb = (const u16*)Wt + (size_t)col0 * K;

    const int ntile = K >> 6;
    stage_lds<MFR>(Ab, K, Af, wi, lane);
    stage_lds<4>(Wb, K, Wf, wi, lane);
    if (ntile > 1) {
        stage_lds<MFR>(Ab + 64, K, Af + ASTR, wi, lane);
        stage_lds<4>(Wb + 64, K, Wf + (1 << 12), wi, lane);
    }

    for (int t = 0; t < ntile; t++) {
        const int buf = t & 1;
        if (t + 1 < ntile) {
            if constexpr (MT == 128) asm volatile("s_waitcnt vmcnt(8)" ::: "memory");
            else                     asm volatile("s_waitcnt vmcnt(6)" ::: "memory");
        } else {
            asm volatile("s_waitcnt vmcnt(0)" ::: "memory");
        }
        __builtin_amdgcn_s_barrier();
        __builtin_amdgcn_sched_barrier(0);
        __builtin_amdgcn_s_setprio(1);
        #pragma unroll
        for (int kh = 0; kh < 2; kh++) {
            f16x8 a4[MFR], w4[4];
            int s = (kh << 2) + l4;
            #pragma unroll
            for (int m = 0; m < MFR; m++) {
                int r = wr * (MT / 2) + (m << 4) + l15;
                a4[m] = *(const f16x8*)&Af[buf * ASTR + r * 32 + ((s ^ (r & 7)) << 2)];
            }
            #pragma unroll
            for (int n = 0; n < 4; n++) {
                int c = (wc << 6) + (n << 4) + l15;
                w4[n] = *(const f16x8*)&Wf[(buf << 12) + c * 32 + ((s ^ (c & 7)) << 2)];
            }
            #pragma unroll
            for (int m = 0; m < MFR; m++)
                #pragma unroll
                for (int n = 0; n < 4; n++)
                    acc[m][n] = __builtin_amdgcn_mfma_f32_16x16x32_f16(a4[m], w4[n], acc[m][n], 0, 0, 0);
        }
        __builtin_amdgcn_s_setprio(0);
        __builtin_amdgcn_sched_barrier(0);
        __builtin_amdgcn_s_barrier();
        if (t + 2 < ntile) {
            stage_lds<MFR>(Ab + ((t + 2) << 6), K, Af + buf * ASTR, wi, lane);
            stage_lds<4>(Wb + ((t + 2) << 6), K, Wf + (buf << 12), wi, lane);
        }
    }

    // ---- epilogue ----
    float c0[4], c1[4];
    #pragma unroll
    for (int n = 0; n < 4; n++) {
        int col = col0 + (wc << 6) + (n << 4) + l15;
        if (LNF) { c0[n] = csp[col]; c1[n] = bbp[col]; }
        else     { c0[n] = 0.f;
                   c1[n] = (has_bias && (CMODE != 2 || col < N)) ? ldw(bias, boff + col, f) : 0.f; }
    }
    #pragma unroll
    for (int m = 0; m < MFR; m++) {
        #pragma unroll
        for (int i = 0; i < 4; i++) {
            int row = row0 + wr * (MT / 2) + (m << 4) + (l4 << 2) + i;
            float mu = 0.f, rs = 1.f;
            if (LNF) {
                float sv = stin[2 * row], ssv = stin[2 * row + 1];
                mu = sv * (1.f / E_);
                rs = rsqrtf(ssv * (1.f / E_) - mu * mu + 1e-5f);
            }
            float ps = 0.f, pss = 0.f;
            #pragma unroll
            for (int n = 0; n < 4; n++) {
                int col = col0 + (wc << 6) + (n << 4) + l15;
                if (CMODE == 2 && col >= N) continue;
                float r = LNF ? rs * (acc[m][n][i] - mu * c0[n]) + c1[n]
                              : acc[m][n][i] + c1[n];
                size_t o = (size_t)row * N + col;
                if (CMODE == 0) {
                    if (relu) r = fmaxf(r, 0.f);
                    ((_Float16*)Cv)[o] = (_Float16)r;
                } else if (CMODE == 1) {
                    _Float16* C = (_Float16*)Cv;
                    r += (float)C[o];
                    _Float16 hv = (_Float16)r;
                    C[o] = hv;
                    if (STATS) { float xv = (float)hv; ps += xv; pss += xv * xv; }
                } else {
                    ((float*)Cv)[o] = r;
                    if (f) ((float*)dout)[o] = r;
                    else ((__hip_bfloat16*)dout)[o] = __float2bfloat16(r);
                }
            }
            if (STATS) {
                #pragma unroll
                for (int off = 1; off < 16; off <<= 1) {
                    ps  += __shfl_xor(ps,  off, 64);
                    pss += __shfl_xor(pss, off, 64);
                }
                if (l15 == 0) {
                    atomicAdd(&stout[2 * row], ps);
                    atomicAdd(&stout[2 * row + 1], pss);
                }
            }
        }
    }
}

// fused Q/K/V with ln1 fold: grid (9, 128)
__global__ __launch_bounds__(256, 2) void gemm_qkv_k(
        const _Float16* __restrict__ A, const _Float16* __restrict__ wls,
        const float* __restrict__ csL, const float* __restrict__ bbL,
        const float* __restrict__ stin,
        _Float16* __restrict__ qb, _Float16* __restrict__ kb, _Float16* __restrict__ vb) {
    __shared__ __align__(16) u32 Af[8192];
    __shared__ __align__(16) u32 Wf[8192];
    int sx, by;
    xcd_swz(9, sx, by);
    int which = sx / 3, bx = sx % 3;
    _Float16* C = (which == 0) ? qb : (which == 1) ? kb : vb;
    gemm_body<0, true, false, 128>(A, wls + (size_t)which * EE,
                              csL + (size_t)which * E_, bbL + (size_t)which * E_, stin,
                              nullptr, 0, 0, 0, C, nullptr, nullptr,
                              E_, E_, 0, bx, by, Af, Wf);
}

// W1 with ln2 fold + relu: grid (12, 128)
__global__ __launch_bounds__(256, 2) void gemm_w1_k(
        const _Float16* __restrict__ A, const _Float16* __restrict__ Wt,
        const float* __restrict__ cs, const float* __restrict__ bb,
        const float* __restrict__ stin, _Float16* __restrict__ C) {
    __shared__ __align__(16) u32 Af[8192];
    __shared__ __align__(16) u32 Wf[8192];
    int bx, by;
    xcd_swz(gridDim.x, bx, by);
    gemm_body<0, true, false, 128>(A, Wt, cs, bb, stin, nullptr, 0, 0, 0,
                              C, nullptr, nullptr, F_, E_, 1, bx, by, Af, Wf);
}

// residual writer (Wo/W2): MT=64 tiles, grid (3, 256) = 768 wg, 3 blocks/CU (48KB LDS)
__global__ __launch_bounds__(256, 3) void gemm_resst_k(
        const _Float16* __restrict__ A, const _Float16* __restrict__ Wt,
        const void* __restrict__ bias, long long boff, const int* __restrict__ flag,
        _Float16* __restrict__ C, float* __restrict__ stout, int N, int K) {
    __shared__ __align__(16) u32 Af[4096];   // 2 x 64 x 64 f16 = 16 KB
    __shared__ __align__(16) u32 Wf[8192];   // 2 x 128 x 64 f16 = 32 KB
    int bx, by;
    xcd_swz(gridDim.x, bx, by);
    gemm_body<1, false, true, 64>(A, Wt, nullptr, nullptr, nullptr, bias, boff, 1, *flag,
                              C, nullptr, stout, N, K, 0, bx, by, Af, Wf);
}

// lm head with lnf fold; writes logits f32 AND d_out. grid (1, 128).
__global__ __launch_bounds__(256, 2) void gemm_lmh_k(
        const _Float16* __restrict__ A, const _Float16* __restrict__ Wt,
        const float* __restrict__ cs, const float* __restrict__ bb,
        const float* __restrict__ stin, const int* __restrict__ flag,
        float* __restrict__ logits, void* __restrict__ dout) {
    __shared__ __align__(16) u32 Af[8192];
    __shared__ __align__(16) u32 Wf[8192];
    int bx, by;
    xcd_swz(1, bx, by);
    gemm_body<2, true, false, 128>(A, Wt, cs, bb, stin, nullptr, 0, 0, *flag,
                              logits, dout, nullptr, V_, E_, 0, bx, by, Af, Wf);
}

// ---------------- MFMA attention, f16 I/O (verbatim) ----------------
template<int NK>
__device__ __forceinline__ void attn_body(
        const u16* __restrict__ qbase, const u16* __restrict__ kbase,
        const u16* __restrict__ vbase, u16* __restrict__ abase,
        int q0, u32* Kls, u32* Pls) {
    constexpr int NKF = NK / 16;
    constexpr int NKS = NK / 32;
    const int tid = threadIdx.x;
    const int lane = tid & 63;
    const int w = tid >> 6;
    const int l15 = lane & 15, l4 = lane >> 4;

    {
        int r8 = tid >> 3, slot = tid & 7;
        #pragma unroll
        for (int p = 0; p < NK / 32; p++) {
            int key = r8 + p * 32;
            uint4 a8 = *(const uint4*)(kbase + (size_t)key * E_ + slot * 8);
            *(uint4*)&Kls[key * 32 + ((slot ^ (key & 7)) << 2)] = a8;
        }
    }
    __syncthreads();

    const int qrow = w * 16 + l15;
    const int qi = q0 + qrow;
    f32x4 acc[NKF];
    #pragma unroll
    for (int kf = 0; kf < NKF; kf++) acc[kf] = f32x4{0.f, 0.f, 0.f, 0.f};

    #pragma unroll
    for (int kh = 0; kh < 2; kh++) {
        f16x8 qh = *(const f16x8*)(qbase + (size_t)qi * E_ + ((kh << 2) + l4) * 8);
        #pragma unroll
        for (int kf = 0; kf < NKF; kf++) {
            int krow = kf * 16 + l15;
            f16x8 kf8 = *(const f16x8*)&Kls[krow * 32 + ((((kh << 2) + l4) ^ (krow & 7)) << 2)];
            acc[kf] = __builtin_amdgcn_mfma_f32_16x16x32_f16(kf8, qh, acc[kf], 0, 0, 0);
        }
    }

    float m = -1e30f;
    #pragma unroll
    for (int kf = 0; kf < NKF; kf++)
        #pragma unroll
        for (int r = 0; r < 4; r++) {
            int key = kf * 16 + l4 * 4 + r;
            float s = acc[kf][r] * 0.125f;
            if (key > qi) s = -1e30f;
            acc[kf][r] = s;
            m = fmaxf(m, s);
        }
    m = fmaxf(m, __shfl_xor(m, 16, 64));
    m = fmaxf(m, __shfl_xor(m, 32, 64));
    float sum = 0.f;
    #pragma unroll
    for (int kf = 0; kf < NKF; kf++)
        #pragma unroll
        for (int r = 0; r < 4; r++) {
            float p = __expf(acc[kf][r] - m);
            acc[kf][r] = p;
            sum += p;
        }
    sum += __shfl_xor(sum, 16, 64);
    sum += __shfl_xor(sum, 32, 64);
    float inv = 1.f / sum;

    #pragma unroll
    for (int kf = 0; kf < NKF; kf++) {
        uint2 pw;
        pw.x = pack_h2(acc[kf][0] * inv, acc[kf][1] * inv);
        pw.y = pack_h2(acc[kf][2] * inv, acc[kf][3] * inv);
        int j = kf * 2 + (l4 >> 1);
        *(uint2*)&Pls[qrow * 128 + ((j ^ (qrow & 15)) << 2) + ((l4 & 1) << 1)] = pw;
    }
    __syncthreads();

    for (int kp = lane; kp < NK / 2; kp += 64) {
        #pragma unroll
        for (int dq = 0; dq < 2; dq++) {
            int db = w + dq * 4;
            uint4 v0 = *(const uint4*)(vbase + (size_t)(2 * kp) * E_ + db * 8);
            uint4 v1 = *(const uint4*)(vbase + (size_t)(2 * kp + 1) * E_ + db * 8);
            u32 uu[8];
            uu[0] = pk_lo(v0.x, v1.x); uu[1] = pk_hi(v0.x, v1.x);
            uu[2] = pk_lo(v0.y, v1.y); uu[3] = pk_hi(v0.y, v1.y);
            uu[4] = pk_lo(v0.z, v1.z); uu[5] = pk_hi(v0.z, v1.z);
            uu[6] = pk_lo(v0.w, v1.w); uu[7] = pk_hi(v0.w, v1.w);
            #pragma unroll
            for (int i = 0; i < 8; i++) {
                int d = db * 8 + i;
                Kls[d * 128 + (((kp >> 2) ^ (d & 15)) << 2) + (kp & 3)] = uu[i];
            }
        }
    }
    __syncthreads();

    f32x4 o2[4];
    #pragma unroll
    for (int df = 0; df < 4; df++) o2[df] = f32x4{0.f, 0.f, 0.f, 0.f};
    #pragma unroll
    for (int ks = 0; ks < NKS; ks++) {
        f16x8 pa = *(const f16x8*)&Pls[qrow * 128 + (((ks * 4 + l4) ^ (qrow & 15)) << 2)];
        #pragma unroll
        for (int df = 0; df < 4; df++) {
            int d = df * 16 + l15;
            f16x8 vb8 = *(const f16x8*)&Kls[d * 128 + (((ks * 4 + l4) ^ (d & 15)) << 2)];
            o2[df] = __builtin_amdgcn_mfma_f32_16x16x32_f16(pa, vb8, o2[df], 0, 0, 0);
        }
    }
    #pragma unroll
    for (int df = 0; df < 4; df++)
        #pragma unroll
        for (int r = 0; r < 4; r++) {
            int qg = q0 + w * 16 + l4 * 4 + r;
            abase[(size_t)qg * E_ + df * 16 + l15] = f2hu(o2[df][r]);
        }
}

__global__ __launch_bounds__(256) void attn_mfma_k(
        const _Float16* __restrict__ q, const _Float16* __restrict__ k,
        const _Float16* __restrict__ v, _Float16* __restrict__ att) {
    __shared__ __align__(16) u32 Kls[256 * 32];   // 32 KB
    __shared__ __align__(16) u32 Pls[64 * 128];   // 32 KB
    int chunk = blockIdx.x & 3;
    int bh = blockIdx.x >> 2;
    int b = bh / H_, h = bh % H_;
    const u16* qbase = (const u16*)q + ((size_t)b * T_) * E_ + h * D_;
    const u16* kbase = (const u16*)k + ((size_t)b * T_) * E_ + h * D_;
    const u16* vbase = (const u16*)v + ((size_t)b * T_) * E_ + h * D_;
    u16* abase = (u16*)att + ((size_t)b * T_) * E_ + h * D_;
    int q0 = chunk * 64;
    switch (chunk) {
        case 0: attn_body< 64>(qbase, kbase, vbase, abase, q0, Kls, Pls); break;
        case 1: attn_body<128>(qbase, kbase, vbase, abase, q0, Kls, Pls); break;
        case 2: attn_body<192>(qbase, kbase, vbase, abase, q0, Kls, Pls); break;
        default: attn_body<256>(qbase, kbase, vbase, abase, q0, Kls, Pls); break;
    }
}

// ---------------- loss tail ----------------
__global__ __launch_bounds__(256) void rowloss2_k(
        const float* __restrict__ logits, const int* __restrict__ tgt,
        float* __restrict__ accum) {
    __shared__ float part[4];
    int w = threadIdx.x >> 6, lane = threadIdx.x & 63;
    float local = 0.f;
    for (int i = 0; i < 16; i++) {
        int row = blockIdx.x * 64 + w * 16 + i;
        const float* lr = logits + (size_t)row * V_;
        float v0 = lr[lane];
        float v64 = (lane == 0) ? lr[64] : -1e30f;
        float m = fmaxf(v0, v64);
        #pragma unroll
        for (int off = 32; off; off >>= 1) m = fmaxf(m, __shfl_xor(m, off, 64));
        float se = __expf(v0 - m) + ((lane == 0) ? __expf(v64 - m) : 0.f);
        #pragma unroll
        for (int off = 32; off; off >>= 1) se += __shfl_xor(se, off, 64);
        if (lane == 0) local += lr[tgt[row]] - m - __logf(se);
    }
    if (lane == 0) part[w] = local;
    __syncthreads();
    if (threadIdx.x == 0)
        atomicAdd(accum, -(part[0] + part[1] + part[2] + part[3]));
}

__global__ void final_k(const float* __restrict__ accum, const int* __restrict__ flag,
                        void* __restrict__ out) {
    if (threadIdx.x == 0) {
        float v = *accum * (1.f / BT);
        if (*flag) ((float*)out)[(size_t)BT * V_] = v;
        else ((__hip_bfloat16*)out)[(size_t)BT * V_] = __float2bfloat16(v);
    }
}

extern "C" void kernel_launch(void* const* d_in, const int* in_sizes, int n_in,
                              void* d_out, int out_size, void* d_ws, size_t ws_size,
                              hipStream_t stream) {
    const int* idx     = (const int*)d_in[0];
    const int* targets = (const int*)d_in[1];
    const void* tok  = d_in[2];
    const void* pos  = d_in[3];
    const void* Wq   = d_in[4];
    const void* Wk   = d_in[5];
    const void* Wv   = d_in[6];
    const void* Wo   = d_in[7];
    const void* bo   = d_in[8];
    const void* W1   = d_in[9];
    const void* b1   = d_in[10];
    const void* W2   = d_in[11];
    const void* b2   = d_in[12];
    const void* ln1g = d_in[13];
    const void* ln1b = d_in[14];
    const void* ln2g = d_in[15];
    const void* ln2b = d_in[16];
    const void* lnfg = d_in[17];
    const void* lnfb = d_in[18];
    const void* Wlm  = d_in[19];
    const void* blm  = d_in[20];

    // ---- workspace layout (~142 MiB of the 268 MB ws) ----
    char* wsb = (char*)d_ws;
    int*   flag    = (int*)wsb;
    float* lossacc = (float*)(wsb + 8);
    float* logits  = (float*)(wsb + 256);
    char* p = wsb + 256 + sizeof(float) * (size_t)BT * V_;
    _Float16* xb = (_Float16*)p;                             // f16 residual stream
    _Float16* ab = (_Float16*)(p + 2 * (size_t)XN);          // attn out
    _Float16* qb = (_Float16*)(p + 4 * (size_t)XN);
    _Float16* kb = (_Float16*)(p + 6 * (size_t)XN);
    _Float16* vb = (_Float16*)(p + 8 * (size_t)XN);
    _Float16* wt = (_Float16*)(p + 10 * (size_t)XN);         // 6*WSLOT f16
    _Float16* wlm = wt + 6 * WSLOT;                          // 128*384 f16
    float* csqkv = (float*)(wlm + (size_t)128 * E_);
    float* bbqkv = csqkv + 6 * 3 * E_;
    float* csw1  = bbqkv + 6 * 3 * E_;
    float* bbw1  = csw1 + 6 * (size_t)F_;
    float* cslm  = bbw1 + 6 * (size_t)F_;
    float* bblm  = cslm + 128;
    float* stats = bblm + 128;                               // 13 * BT * 2 f32
    _Float16* ffnb = (_Float16*)(stats + NSTAT);             // [BT][F]

    dim3 grdE64(3, 256);     // Wo / W2 (MT=64): nwg=768
    dim3 grdQKV(9, 128);     // nwg=1152
    dim3 grdW1(12, 128);     // nwg=1536
    dim3 grdLM(1, 128);      // nwg=128

    init_k<<<1, 64, 0, stream>>>(flag, lossacc);
    zstats_k<<<(ZTOT + 255) / 256, 256, 0, stream>>>(csqkv, ZTOT);
    detect_k<<<(V_ * E_ + 255) / 256, 256, 0, stream>>>(tok, V_ * E_, flag);
    wtrans_all_k<<<2604, 256, 0, stream>>>(Wq, Wk, Wv, Wo, W1, W2, Wlm,
                                           ln1g, ln2g, lnfg, flag, wt);
    fold2_k<<<438, 256, 0, stream>>>(Wq, Wk, Wv, W1, Wlm,
                                     ln1g, ln1b, ln2g, ln2b, lnfg, lnfb,
                                     b1, blm, flag,
                                     csqkv, bbqkv, csw1, bbw1, cslm, bblm);
    embed_k<<<BT / 4, 256, 0, stream>>>(idx, tok, pos, flag, xb, stats);

    for (int l = 0; l < L_; l++) {
        const _Float16* wls = wt + (size_t)l * WSLOT;
        float* st1l = stats + (size_t)l * BT * 2;            // ln1 site l
        float* st2l = stats + (size_t)(6 + l) * BT * 2;      // ln2 site l
        float* stnx = (l < 5) ? stats + (size_t)(l + 1) * BT * 2
                              : stats + (size_t)12 * BT * 2; // lnf
        gemm_qkv_k<<<grdQKV, 256, 0, stream>>>(xb, wls,
                csqkv + (size_t)l * 3 * E_, bbqkv + (size_t)l * 3 * E_, st1l,
                qb, kb, vb);
        attn_mfma_k<<<B_ * H_ * 4, 256, 0, stream>>>(qb, kb, vb, ab);
        gemm_resst_k<<<grdE64, 256, 0, stream>>>(ab, wls + 3 * EE, bo, (long long)l * E_,
                                                 flag, xb, st2l, E_, E_);
        gemm_w1_k<<<grdW1, 256, 0, stream>>>(xb, wls + 4 * EE,
                csw1 + (size_t)l * F_, bbw1 + (size_t)l * F_, st2l, ffnb);
        gemm_resst_k<<<grdE64, 256, 0, stream>>>(ffnb, wls + 4 * EE + EF, b2, (long long)l * E_,
                                                 flag, xb, stnx, E_, F_);
    }

    gemm_lmh_k<<<grdLM, 256, 0, stream>>>(xb, wlm, cslm, bblm,
                                          stats + (size_t)12 * BT * 2, flag, logits, d_out);
    rowloss2_k<<<BT / 64, 256, 0, stream>>>(logits, targets, lossacc);
    final_k<<<1, 64, 0, stream>>>(lossacc, flag, d_out);
}